// Round 9
// baseline (343.053 us; speedup 1.0000x reference)
//
#include <hip/hip_runtime.h>
#include <math.h>

#define NB 64
#define TC 16
#define HC 32
#define NNODES 16384
#define NEDGES 131072
#define EPG 2048
#define EPSV 1e-15f

static inline int GRID(int n) { return (n + 255) / 256; }

template<int V> struct Log2 { static constexpr int v = 1 + Log2<V/2>::v; };
template<> struct Log2<1> { static constexpr int v = 0; };

// ---------------- GCN front-end ----------------

// block = (b, dtile of 64 d-rows). Edge-built weighted adjacency entirely in LDS.
__global__ void k_zgemm2(const int* __restrict__ esrc, const int* __restrict__ edst,
                         const float* __restrict__ ea, const float* __restrict__ pos,
                         float* __restrict__ z, float* __restrict__ dinv_g,
                         float* __restrict__ mc) {
    __shared__ float dinvs[256];
    __shared__ __align__(16) float as_[64 * 36];
    __shared__ __align__(16) float bs[32 * 48];
    int b = blockIdx.x >> 2;
    int dtile = (blockIdx.x & 3) * 64;
    int tid = threadIdx.x;
    if (blockIdx.x == 0 && tid < 2) mc[tid] = 0.f;
    int ebase = b * EPG;
    int svr[8], dvr[8];
    float evr[8];
#pragma unroll
    for (int j = 0; j < 8; ++j) {
        int e = ebase + tid + j * 256;
        svr[j] = esrc[e] & 255;
        dvr[j] = edst[e] & 255;
        evr[j] = ea[e];
    }
    dinvs[tid] = 1.0f;
    __syncthreads();
#pragma unroll
    for (int j = 0; j < 8; ++j) atomicAdd(&dinvs[dvr[j]], evr[j]);
    __syncthreads();
    float dg = dinvs[tid];
    float dv = (dg > 0.f) ? rsqrtf(dg) : 0.f;
    __syncthreads();
    dinvs[tid] = dv;
    __syncthreads();
    if (dtile == 0) dinv_g[b * 256 + tid] = dinvs[tid];
    int d = tid >> 2, q = tid & 3;
    float acc[12];
#pragma unroll
    for (int j = 0; j < 12; ++j) acc[j] = 0.f;
    const float* pbase = pos + (size_t)b * 256 * 48;
    for (int s0 = 0; s0 < 256; s0 += 32) {
        for (int i = tid; i < 576; i += 256)
            ((float4*)as_)[i] = make_float4(0.f, 0.f, 0.f, 0.f);
        __syncthreads();
#pragma unroll
        for (int j = 0; j < 8; ++j) {
            int dr = dvr[j] - dtile, sc = svr[j] - s0;
            if ((unsigned)dr < 64u && (unsigned)sc < 32u)
                atomicAdd(&as_[dr * 36 + sc], evr[j]);
        }
        for (int i = tid; i < 384; i += 256) {
            int r = i / 12, c = i % 12;
            float4 v = *(const float4*)(pbase + (size_t)(s0 + r) * 48 + c * 4);
            float dd = dinvs[s0 + r];
            v.x *= dd; v.y *= dd; v.z *= dd; v.w *= dd;
            *(float4*)(bs + r * 48 + c * 4) = v;
        }
        __syncthreads();
#pragma unroll 8
        for (int sp = 0; sp < 32; ++sp) {
            float a = as_[d * 36 + sp];
            const float* bp = &bs[sp * 48 + q * 12];
#pragma unroll
            for (int j = 0; j < 12; ++j) acc[j] += a * bp[j];
        }
        __syncthreads();
    }
    float dd = dinvs[dtile + d];
    float* zr = z + (size_t)(b * 256 + dtile + d) * 48 + q * 12;
#pragma unroll
    for (int j = 0; j < 12; ++j) zr[j] = acc[j] * dd;
}

// Fused per-node: y = relu((z + pos*dinv^2)@W1 + b1); mean_t; tanh; softmax -> p1
__global__ __launch_bounds__(512) void k_y2(
        const float* __restrict__ z, const float* __restrict__ pos,
        const float* __restrict__ dinv, const float* __restrict__ W1,
        const float* __restrict__ b1, const float* __restrict__ Wp1,
        const float* __restrict__ bp1, float* __restrict__ y,
        float* __restrict__ p1) {
    __shared__ float ys[16][33];
    __shared__ __align__(16) float wp[32 * 64];
    __shared__ float xmv[32];
    int n = blockIdx.x;
    int tid = threadIdx.x;
    int t = tid >> 5, h = tid & 31;
    ((float4*)wp)[tid] = ((const float4*)Wp1)[tid];
    const float* zr = z + (size_t)n * 48 + t * 3;
    const float* pr = pos + (size_t)n * 48 + t * 3;
    float di = dinv[n], d2 = di * di;
    float a0 = zr[0] + pr[0] * d2;
    float a1 = zr[1] + pr[1] * d2;
    float a2 = zr[2] + pr[2] * d2;
    float v = fmaxf(a0 * W1[h] + a1 * W1[32 + h] + a2 * W1[64 + h] + b1[h], 0.f);
    y[(size_t)n * 512 + tid] = v;
    ys[t][h] = v;
    __syncthreads();
    if (tid < 32) {
        float s = 0.f;
#pragma unroll
        for (int tt = 0; tt < 16; ++tt) s += ys[tt][tid];
        xmv[tid] = s * (1.0f / 16.0f);
    }
    __syncthreads();
    if (tid < 64) {
        float acc = bp1[tid];
#pragma unroll 8
        for (int hh = 0; hh < 32; ++hh) acc += xmv[hh] * wp[hh * 64 + tid];
        float vv = tanhf(acc);
        float m = vv;
        for (int o = 32; o > 0; o >>= 1) m = fmaxf(m, __shfl_xor(m, o));
        float e = expf(vv - m);
        float s = e;
        for (int o = 32; o > 0; o >>= 1) s += __shfl_xor(s, o);
        p1[(size_t)n * 64 + tid] = e / s;
    }
}

// ---------------- L1 kernels ----------------

// out[b,t,k,h] = sum_n p[(b*NC+n)*KC+k] * x[...], register-tiled 4k x 4h
template<int NC, int KC, int NCH, int SB, int STT, int STN>
__global__ void k_pool4(const float* __restrict__ p, const float* __restrict__ x,
                        float* __restrict__ outp) {
    constexpr int TPT = KC * 2;
    constexpr int TPB = 256 / TPT;
    constexpr int NTILE = TC / TPB;
    __shared__ __align__(16) float ps[NCH * KC];
    __shared__ __align__(16) float xs[TPB * NCH * HC];
    int b = blockIdx.x / NTILE;
    int t0 = (blockIdx.x % NTILE) * TPB;
    int tid = threadIdx.x;
    int th = tid / TPT;
    int r = tid % TPT;
    int k0 = (r >> 3) * 4;
    int h0 = (r & 7) * 4;
    float acc[4][4];
#pragma unroll
    for (int rr = 0; rr < 4; ++rr)
#pragma unroll
        for (int cc = 0; cc < 4; ++cc) acc[rr][cc] = 0.f;
    const float* pbase = p + (size_t)b * NC * KC;
    const float* xbase = x + (size_t)b * SB + (size_t)t0 * STT;
    for (int n0 = 0; n0 < NC; n0 += NCH) {
        for (int i = tid; i < NCH * KC / 4; i += 256)
            ((float4*)ps)[i] = ((const float4*)(pbase + (size_t)n0 * KC))[i];
        for (int i = tid; i < TPB * NCH * 8; i += 256) {
            int q = i & 7;
            int n = (i >> 3) % NCH;
            int tt = i / (NCH * 8);
            *(float4*)&xs[(tt * NCH + n) * HC + q * 4] =
                *(const float4*)(xbase + (size_t)tt * STT + (size_t)(n0 + n) * STN + q * 4);
        }
        __syncthreads();
#pragma unroll 4
        for (int n = 0; n < NCH; ++n) {
            float4 kv4 = *(const float4*)&ps[n * KC + k0];
            float4 xv4 = *(const float4*)&xs[(th * NCH + n) * HC + h0];
            float kv[4] = {kv4.x, kv4.y, kv4.z, kv4.w};
            float xv[4] = {xv4.x, xv4.y, xv4.z, xv4.w};
#pragma unroll
            for (int rr = 0; rr < 4; ++rr)
#pragma unroll
                for (int cc = 0; cc < 4; ++cc) acc[rr][cc] += kv[rr] * xv[cc];
        }
        __syncthreads();
    }
    float* ob = outp + (((size_t)(b * TC + t0 + th) * KC + k0) * HC + h0);
#pragma unroll
    for (int rr = 0; rr < 4; ++rr) {
        float4 v = {acc[rr][0], acc[rr][1], acc[rr][2], acc[rr][3]};
        *(float4*)(ob + (size_t)rr * HC) = v;
    }
}

// L1 adjacency-apply with LDS-built count matrix from edges.
__global__ void k_adjp2(const int* __restrict__ esrc, const int* __restrict__ edst,
                        const float* __restrict__ p, float* __restrict__ tmp,
                        float* __restrict__ dflat) {
    __shared__ __align__(16) float as_[32 * 260];
    __shared__ __align__(16) float ps[64 * 64];
    int b = blockIdx.x >> 3;
    int nt0 = (blockIdx.x & 7) * 32;
    int tid = threadIdx.x;
    for (int i = tid; i < 32 * 260 / 4; i += 256)
        ((float4*)as_)[i] = make_float4(0.f, 0.f, 0.f, 0.f);
    __syncthreads();
    int ebase = b * EPG;
#pragma unroll
    for (int j = 0; j < 8; ++j) {
        int e = ebase + tid + j * 256;
        int sv = esrc[e] & 255;
        int nr = sv - nt0;
        if ((unsigned)nr < 32u)
            atomicAdd(&as_[nr * 260 + (edst[e] & 255)], 1.0f);
    }
    __syncthreads();
    int n = tid >> 3, l0 = (tid & 7) * 8;
    float acc[8];
#pragma unroll
    for (int j = 0; j < 8; ++j) acc[j] = 0.f;
    float rs = 0.f;
    for (int m0 = 0; m0 < 256; m0 += 64) {
        for (int i = tid; i < 64 * 64 / 4; i += 256)
            ((float4*)ps)[i] = ((const float4*)(p + ((size_t)b * 256 + m0) * 64))[i];
        __syncthreads();
#pragma unroll 4
        for (int m = 0; m < 64; ++m) {
            float av = as_[n * 260 + m0 + m];
            rs += av;
            float4 p0 = *(const float4*)&ps[m * 64 + l0];
            float4 p1v = *(const float4*)&ps[m * 64 + l0 + 4];
            acc[0] += av * p0.x; acc[1] += av * p0.y; acc[2] += av * p0.z; acc[3] += av * p0.w;
            acc[4] += av * p1v.x; acc[5] += av * p1v.y; acc[6] += av * p1v.z; acc[7] += av * p1v.w;
        }
        __syncthreads();
    }
#pragma unroll
    for (int j = 0; j < 8; ++j)
        tmp[((size_t)b * 256 + nt0 + n) * 64 + l0 + j] = acc[j];
    if ((tid & 7) == 0) dflat[(size_t)b * 256 + nt0 + n] = rs;
}

__device__ inline float blk_sum256(float v, float* rbuf) {
    for (int o = 32; o > 0; o >>= 1) v += __shfl_xor(v, o);
    __syncthreads();
    if ((threadIdx.x & 63) == 0) rbuf[threadIdx.x >> 6] = v;
    __syncthreads();
    return rbuf[0] + rbuf[1] + rbuf[2] + rbuf[3];
}

// Partial GEMM, no atomics: G[split][b] = p_chunk^T @ [p_chunk | tmp_chunk]
template<int NC, int KC, int NSPLIT, int KT, int LT>
__global__ void k_ssgp(const float* __restrict__ p, const float* __restrict__ tmp,
                       const float* __restrict__ dflat, float* __restrict__ G,
                       float* __restrict__ Gden) {
    constexpr int NCH = NC / NSPLIT;
    constexpr int LC = 2 * KC;
    constexpr int KQ = KC / 4;
    __shared__ __align__(16) float ab[NCH * LC];
    __shared__ float rbuf[4];
    int b = blockIdx.x / NSPLIT;
    int split = blockIdx.x % NSPLIT;
    int n0 = split * NCH;
    int tid = threadIdx.x;
    const float* pb = p + ((size_t)b * NC + n0) * KC;
    const float* tb = tmp + ((size_t)b * NC + n0) * KC;
    const float* db = dflat + (size_t)b * NC + n0;
    for (int i = tid; i < NCH * KQ; i += 256) {
        int r = i / KQ, c = i % KQ;
        *(float4*)(ab + r * LC + c * 4) = ((const float4*)pb)[i];
        *(float4*)(ab + r * LC + KC + c * 4) = ((const float4*)tb)[i];
    }
    __syncthreads();
    float den = 0.f;
    for (int i = tid; i < NCH * KQ; i += 256) {
        int r = i / KQ, c = i % KQ;
        float4 v = *(const float4*)(ab + r * LC + c * 4);
        den += (v.x * v.x + v.y * v.y + v.z * v.z + v.w * v.w) * db[r];
    }
    int kt = tid >> 4, lt = tid & 15;
    int k0 = kt * KT, l0 = lt * LT;
    float acc[KT][LT];
#pragma unroll
    for (int r = 0; r < KT; ++r)
#pragma unroll
        for (int c = 0; c < LT; ++c) acc[r][c] = 0.f;
#pragma unroll 4
    for (int n = 0; n < NCH; ++n) {
        float kv[KT], lv[LT];
#pragma unroll
        for (int r = 0; r < KT; ++r) kv[r] = ab[n * LC + k0 + r];
#pragma unroll
        for (int c = 0; c < LT; ++c) lv[c] = ab[n * LC + l0 + c];
#pragma unroll
        for (int r = 0; r < KT; ++r)
#pragma unroll
            for (int c = 0; c < LT; ++c) acc[r][c] += kv[r] * lv[c];
    }
    float* Gb = G + ((size_t)split * NB + b) * (KC * LC);
#pragma unroll
    for (int r = 0; r < KT; ++r)
#pragma unroll
        for (int c = 0; c < LT; ++c)
            Gb[(k0 + r) * LC + l0 + c] = acc[r][c];
    float dt = blk_sum256(den, rbuf);
    if (tid == 0) Gden[(size_t)split * NB + b] = dt;
}

// Per-batch finish (L1): sum partials, losses, zero-diag+normalize, next dflat
template<int KC, int NSPLIT, bool DFN>
__global__ void k_finish(const float* __restrict__ G, const float* __restrict__ Gden,
                         float* __restrict__ oadj_out, float* __restrict__ dfn_out,
                         float* __restrict__ mc_out, float* __restrict__ or_out) {
    constexpr int LK = Log2<KC>::v;
    constexpr int KCP = KC + 1;
    constexpr int LC = 2 * KC;
    __shared__ float sss[KC * KCP];
    __shared__ float oss[KC * KCP];
    __shared__ float dvv[KC];
    __shared__ float rbuf[4];
    int b = blockIdx.x, tid = threadIdx.x;
    for (int i = tid; i < KC * KC; i += 256) {
        int k = i >> LK, l = i & (KC - 1);
        float sv = 0.f, ov = 0.f;
#pragma unroll
        for (int s = 0; s < NSPLIT; ++s) {
            const float* Gb = G + ((size_t)s * NB + b) * KC * LC;
            sv += Gb[k * LC + l];
            ov += Gb[k * LC + KC + l];
        }
        sss[k * KCP + l] = sv;
        oss[k * KCP + l] = ov;
    }
    __syncthreads();
    float ssn2 = 0.f;
    for (int i = tid; i < KC * KC; i += 256) {
        int k = i >> LK, l = i & (KC - 1);
        float v = sss[k * KCP + l];
        ssn2 += v * v;
    }
    float num = 0.f;
    for (int k = tid; k < KC; k += 256) num += oss[k * KCP + k];
    float ssn2_t = blk_sum256(ssn2, rbuf);
    float num_t = blk_sum256(num, rbuf);
    float den_t = 0.f;
#pragma unroll
    for (int s = 0; s < NSPLIT; ++s) den_t += Gden[(size_t)s * NB + b];
    float inv = 1.0f / sqrtf(ssn2_t);
    float dk = rsqrtf((float)KC);
    float o2 = 0.f;
    for (int i = tid; i < KC * KC; i += 256) {
        int k = i >> LK, l = i & (KC - 1);
        float v = sss[k * KCP + l] * inv - ((k == l) ? dk : 0.f);
        o2 += v * v;
    }
    float o2_t = blk_sum256(o2, rbuf);
    if (tid == 0) {
        atomicAdd(mc_out, -(num_t / den_t) * (1.0f / NB));
        atomicAdd(or_out, sqrtf(o2_t) * (1.0f / NB));
    }
    if (tid < KC) {
        float rs = 0.f;
        for (int l = 0; l < KC; ++l) rs += oss[tid * KCP + l];
        rs -= oss[tid * KCP + tid];
        dvv[tid] = sqrtf(rs) + EPSV;
    }
    __syncthreads();
    for (int i = tid; i < KC * KC; i += 256) {
        int k = i >> LK, l = i & (KC - 1);
        float v = (k == l) ? 0.f : oss[k * KCP + l] / (dvv[k] * dvv[l]);
        oadj_out[(size_t)b * KC * KC + i] = v;
    }
    if (DFN && tid < KC) {
        float s = 0.f;
        for (int l = 0; l < KC; ++l)
            if (l != tid) s += oss[tid * KCP + l] / (dvv[tid] * dvv[l]);
        dfn_out[(size_t)b * KC + tid] = s;
    }
}

// Fused dense_graph_conv per (b,t): out = (adjn@x)@Wrel + brel + x@Wroot (L1 only)
template<int NC2, int OC>
__global__ void k_graphconv_t(const float* __restrict__ adjn, const float* __restrict__ x,
                              const float* __restrict__ Wrel, const float* __restrict__ brel,
                              const float* __restrict__ Wroot, float* __restrict__ outp) {
    constexpr int EL1 = NC2 * HC / 256;
    constexpr int EL2 = NC2 * OC / 256;
    constexpr int LOC = Log2<OC>::v;
    __shared__ __align__(16) float xs[NC2 * HC];
    __shared__ __align__(16) float as_[NC2 * NC2];
    __shared__ float c1[NC2 * HC];
    int bt = blockIdx.x;
    int b = bt >> 4;
    int tid = threadIdx.x;
    for (int i = tid; i < NC2 * HC / 4; i += 256)
        ((float4*)xs)[i] = ((const float4*)(x + (size_t)bt * NC2 * HC))[i];
    for (int i = tid; i < NC2 * NC2 / 4; i += 256)
        ((float4*)as_)[i] = ((const float4*)(adjn + (size_t)b * NC2 * NC2))[i];
    __syncthreads();
#pragma unroll
    for (int e = 0; e < EL1; ++e) {
        int idx = tid + e * 256;
        int hh = idx & 31, n = idx >> 5;
        float acc = 0.f;
#pragma unroll 8
        for (int m = 0; m < NC2; ++m) acc += as_[n * NC2 + m] * xs[m * HC + hh];
        c1[idx] = acc;
    }
    __syncthreads();
#pragma unroll
    for (int e = 0; e < EL2; ++e) {
        int idx = tid + e * 256;
        int o = idx & (OC - 1), n = idx >> LOC;
        float acc = brel[o];
#pragma unroll 8
        for (int hh = 0; hh < HC; ++hh)
            acc += c1[n * HC + hh] * Wrel[hh * OC + o] + xs[n * HC + hh] * Wroot[hh * OC + o];
        outp[(size_t)bt * NC2 * OC + idx] = acc;
    }
}

// ---------------- fused tail: L2 + L3 + agg, one block per batch ----------------

__global__ __launch_bounds__(256) void k_tail(
        const float* __restrict__ x1b,    // [B][16][64][32]
        const float* __restrict__ oadj1,  // [B][64][64]
        const float* __restrict__ dflat2, // [B][64]
        const float* __restrict__ p1,     // [B][256][64]
        const float* __restrict__ Wp2, const float* __restrict__ bp2,
        const float* __restrict__ Wrel3, const float* __restrict__ brel3,
        const float* __restrict__ Wroot3,
        const float* __restrict__ Wp3, const float* __restrict__ bp3,
        const float* __restrict__ Wrel4, const float* __restrict__ brel4,
        const float* __restrict__ Wroot4,
        float* __restrict__ x2a_g,        // scratch [B][16][32][32]
        float* __restrict__ x2b_g,        // scratch [B][16][32][32]
        float* __restrict__ outx,         // [B][16][8][64]
        float* __restrict__ outagg,       // [B][256][8]
        float* __restrict__ mc_out, float* __restrict__ or_out) {
    __shared__ float lds[14848];          // 58 KB arena
    float* P2     = lds;                  // 2048 (persist)
    float* P3     = lds + 2048;           // 256  (persist)
    float* OADJ2s = lds + 2304;           // 1024 (persist)
    float* DF3    = lds + 3328;           // 32   (persist)
    float* XSUM3  = lds + 3360;           // 1024 (persist)
    float* OADJ3s = lds + 4384;           // 64   (persist)
    float* DVV    = lds + 4448;           // 64
    float* RBUF   = lds + 4512;           // 4
    float* X3A    = lds + 4608;           // 4096 (persist from phase 7)
    float* S      = lds + 8704;           // 6144 scratch

    int b = blockIdx.x, tid = threadIdx.x;
    const float* x1bb = x1b + (size_t)b * 32768;

    // ---- Phase 1: ms2 (mean over t, tanh linear, softmax -> P2[64][32])
    {
        float* XM2 = S;            // 2048
        float* WP2s = S + 2048;    // 1024
        float* S2 = S + 3072;      // 2048
        for (int i = tid; i < 2048; i += 256) {
            float s = 0.f;
            for (int t = 0; t < 16; ++t) s += x1bb[t * 2048 + i];
            XM2[i] = s * (1.0f / 16.0f);
        }
        for (int i = tid; i < 1024; i += 256) WP2s[i] = Wp2[i];
        __syncthreads();
        for (int i = tid; i < 2048; i += 256) {
            int n = i >> 5, k = i & 31;
            float acc = bp2[k];
            for (int h = 0; h < 32; ++h) acc += XM2[n * 32 + h] * WP2s[h * 32 + k];
            S2[i] = tanhf(acc);
        }
        __syncthreads();
        {
            int lane = tid & 31;
            int rr = tid >> 5;
            for (int r0 = 0; r0 < 64; r0 += 8) {
                int row = r0 + rr;
                float v = S2[row * 32 + lane];
                float m = v;
                for (int o = 16; o > 0; o >>= 1) m = fmaxf(m, __shfl_xor(m, o, 32));
                float e = expf(v - m);
                float s = e;
                for (int o = 16; o > 0; o >>= 1) s += __shfl_xor(s, o, 32);
                P2[row * 32 + lane] = e / s;
            }
        }
        __syncthreads();
    }

    // ---- Phase 2: pool2 -> x2a_g[b][t][32][32]
    {
        float* XT = S;
        for (int t = 0; t < 16; ++t) {
            for (int i = tid; i < 2048; i += 256) XT[i] = x1bb[t * 2048 + i];
            __syncthreads();
            for (int i = tid; i < 1024; i += 256) {
                int k = i >> 5, h = i & 31;
                float acc = 0.f;
                for (int n = 0; n < 64; ++n) acc += P2[n * 32 + k] * XT[n * 32 + h];
                x2a_g[(size_t)(b * 16 + t) * 1024 + i] = acc;
            }
            __syncthreads();
        }
    }

    // ---- Phase 3: adjp2: TMP2 = oadj1[b] @ P2
    float* TMP2 = S;               // 2048, persists into phase 4
    {
        float* OADJ1s = S + 2048;  // 4096
        for (int i = tid; i < 4096; i += 256) OADJ1s[i] = oadj1[(size_t)b * 4096 + i];
        __syncthreads();
        for (int i = tid; i < 2048; i += 256) {
            int n = i >> 5, l = i & 31;
            float acc = 0.f;
            for (int m = 0; m < 64; ++m) acc += OADJ1s[n * 64 + m] * P2[m * 32 + l];
            TMP2[i] = acc;
        }
        __syncthreads();
    }

    // ---- Phase 4: ss2 + finish2 (losses L2, OADJ2s normalize, DF3)
    {
        float* GS = S + 2048;      // 32x33 = 1056
        float* GO = S + 3104;      // 1056
        for (int i = tid; i < 1024; i += 256) {
            int k = i >> 5, l = i & 31;
            float accs = 0.f, acco = 0.f;
            for (int n = 0; n < 64; ++n) {
                float pv = P2[n * 32 + k];
                accs += pv * P2[n * 32 + l];
                acco += pv * TMP2[n * 32 + l];
            }
            GS[k * 33 + l] = accs;
            GO[k * 33 + l] = acco;
        }
        __syncthreads();
        const float* df2 = dflat2 + (size_t)b * 64;
        float den = 0.f;
        for (int i = tid; i < 2048; i += 256) {
            float pv = P2[i];
            den += pv * pv * df2[i >> 5];
        }
        float ssn2 = 0.f;
        for (int i = tid; i < 1024; i += 256) {
            int k = i >> 5, l = i & 31;
            float v = GS[k * 33 + l];
            ssn2 += v * v;
        }
        float num = 0.f;
        for (int k = tid; k < 32; k += 256) num += GO[k * 33 + k];
        float den_t = blk_sum256(den, RBUF);
        float ssn2_t = blk_sum256(ssn2, RBUF);
        float num_t = blk_sum256(num, RBUF);
        float inv = 1.0f / sqrtf(ssn2_t);
        float dk = rsqrtf(32.0f);
        float o2 = 0.f;
        for (int i = tid; i < 1024; i += 256) {
            int k = i >> 5, l = i & 31;
            float v = GS[k * 33 + l] * inv - ((k == l) ? dk : 0.f);
            o2 += v * v;
        }
        float o2_t = blk_sum256(o2, RBUF);
        if (tid == 0) {
            atomicAdd(mc_out, -(num_t / den_t) * (1.0f / NB));
            atomicAdd(or_out, sqrtf(o2_t) * (1.0f / NB));
        }
        if (tid < 32) {
            float rs = 0.f;
            for (int l = 0; l < 32; ++l) rs += GO[tid * 33 + l];
            rs -= GO[tid * 33 + tid];
            DVV[tid] = sqrtf(rs) + EPSV;
        }
        __syncthreads();
        for (int i = tid; i < 1024; i += 256) {
            int k = i >> 5, l = i & 31;
            OADJ2s[i] = (k == l) ? 0.f : GO[k * 33 + l] / (DVV[k] * DVV[l]);
        }
        __syncthreads();
        if (tid < 32) {
            float s = 0.f;
            for (int l = 0; l < 32; ++l) s += OADJ2s[tid * 32 + l];
            DF3[tid] = s;
        }
        __syncthreads();
    }

    // ---- Phase 5: graphconv2 -> x2b_g; accumulate XSUM3 = sum_t x2b_t
    {
        float* WREL3s = S;          // 1024
        float* WROOT3s = S + 1024;  // 1024
        float* X2AT = S + 2048;     // 1024
        float* C1 = S + 3072;       // 1024
        for (int i = tid; i < 1024; i += 256) {
            WREL3s[i] = Wrel3[i];
            WROOT3s[i] = Wroot3[i];
        }
        for (int i = tid; i < 1024; i += 256) XSUM3[i] = 0.f;
        __syncthreads();
        for (int t = 0; t < 16; ++t) {
            for (int i = tid; i < 1024; i += 256)
                X2AT[i] = x2a_g[(size_t)(b * 16 + t) * 1024 + i];
            __syncthreads();
            for (int i = tid; i < 1024; i += 256) {
                int n = i >> 5, h = i & 31;
                float acc = 0.f;
                for (int m = 0; m < 32; ++m) acc += OADJ2s[n * 32 + m] * X2AT[m * 32 + h];
                C1[i] = acc;
            }
            __syncthreads();
            for (int i = tid; i < 1024; i += 256) {
                int n = i >> 5, o = i & 31;
                float acc = brel3[o];
                for (int h = 0; h < 32; ++h)
                    acc += C1[n * 32 + h] * WREL3s[h * 32 + o] + X2AT[n * 32 + h] * WROOT3s[h * 32 + o];
                x2b_g[(size_t)(b * 16 + t) * 1024 + i] = acc;
                XSUM3[i] += acc;
            }
            __syncthreads();
        }
    }

    // ---- Phase 6: ms3 -> P3[32][8]
    {
        float* WP3s = S;            // 256
        float* S3 = S + 256;        // 256
        for (int i = tid; i < 256; i += 256) WP3s[i] = Wp3[i];
        __syncthreads();
        for (int i = tid; i < 256; i += 256) {
            int n = i >> 3, k = i & 7;
            float acc = bp3[k];
            for (int h = 0; h < 32; ++h)
                acc += (XSUM3[n * 32 + h] * (1.0f / 16.0f)) * WP3s[h * 8 + k];
            S3[i] = tanhf(acc);
        }
        __syncthreads();
        for (int n = tid; n < 32; n += 256) {
            float m = -1e30f;
            for (int k = 0; k < 8; ++k) m = fmaxf(m, S3[n * 8 + k]);
            float s = 0.f;
            float ev[8];
            for (int k = 0; k < 8; ++k) { ev[k] = expf(S3[n * 8 + k] - m); s += ev[k]; }
            for (int k = 0; k < 8; ++k) P3[n * 8 + k] = ev[k] / s;
        }
        __syncthreads();
    }

    // ---- Phase 7: pool3 (X3A in LDS) + adjp3 + post3 (losses L3, OADJ3s)
    {
        float* X2BT = S;            // 1024
        for (int t = 0; t < 16; ++t) {
            for (int i = tid; i < 1024; i += 256)
                X2BT[i] = x2b_g[(size_t)(b * 16 + t) * 1024 + i];
            __syncthreads();
            for (int i = tid; i < 256; i += 256) {
                int k = i >> 5, h = i & 31;
                float acc = 0.f;
                for (int n = 0; n < 32; ++n) acc += P3[n * 8 + k] * X2BT[n * 32 + h];
                X3A[t * 256 + i] = acc;
            }
            __syncthreads();
        }
        float* TMP3 = S + 1024;     // 256
        float* GS3 = S + 1280;      // 8x9 = 72
        float* GO3 = S + 1360;      // 72
        for (int i = tid; i < 256; i += 256) {
            int n = i >> 3, l = i & 7;
            float acc = 0.f;
            for (int m = 0; m < 32; ++m) acc += OADJ2s[n * 32 + m] * P3[m * 8 + l];
            TMP3[i] = acc;
        }
        __syncthreads();
        for (int i = tid; i < 64; i += 256) {
            int k = i >> 3, l = i & 7;
            float accs = 0.f, acco = 0.f;
            for (int n = 0; n < 32; ++n) {
                float pv = P3[n * 8 + k];
                accs += pv * P3[n * 8 + l];
                acco += pv * TMP3[n * 8 + l];
            }
            GS3[k * 9 + l] = accs;
            GO3[k * 9 + l] = acco;
        }
        __syncthreads();
        float den = 0.f;
        for (int i = tid; i < 256; i += 256) {
            float pv = P3[i];
            den += pv * pv * DF3[i >> 3];
        }
        float ssn2 = 0.f;
        for (int i = tid; i < 64; i += 256) {
            int k = i >> 3, l = i & 7;
            float v = GS3[k * 9 + l];
            ssn2 += v * v;
        }
        float num = 0.f;
        for (int k = tid; k < 8; k += 256) num += GO3[k * 9 + k];
        float den_t = blk_sum256(den, RBUF);
        float ssn2_t = blk_sum256(ssn2, RBUF);
        float num_t = blk_sum256(num, RBUF);
        float inv = 1.0f / sqrtf(ssn2_t);
        float dk = rsqrtf(8.0f);
        float o2 = 0.f;
        for (int i = tid; i < 64; i += 256) {
            int k = i >> 3, l = i & 7;
            float v = GS3[k * 9 + l] * inv - ((k == l) ? dk : 0.f);
            o2 += v * v;
        }
        float o2_t = blk_sum256(o2, RBUF);
        if (tid == 0) {
            atomicAdd(mc_out, -(num_t / den_t) * (1.0f / NB));
            atomicAdd(or_out, sqrtf(o2_t) * (1.0f / NB));
        }
        if (tid < 8) {
            float rs = 0.f;
            for (int l = 0; l < 8; ++l) rs += GO3[tid * 9 + l];
            rs -= GO3[tid * 9 + tid];
            DVV[32 + tid] = sqrtf(rs) + EPSV;
        }
        __syncthreads();
        for (int i = tid; i < 64; i += 256) {
            int k = i >> 3, l = i & 7;
            OADJ3s[i] = (k == l) ? 0.f : GO3[k * 9 + l] / (DVV[32 + k] * DVV[32 + l]);
        }
        __syncthreads();
    }

    // ---- Phase 8: graphconv3 -> outx
    {
        float* WREL4s = S;           // 2048
        float* WROOT4s = S + 2048;   // 2048
        float* C1 = S + 4096;        // 256 (8x32)
        for (int i = tid; i < 2048; i += 256) {
            WREL4s[i] = Wrel4[i];
            WROOT4s[i] = Wroot4[i];
        }
        __syncthreads();
        for (int t = 0; t < 16; ++t) {
            for (int i = tid; i < 256; i += 256) {
                int n = i >> 5, h = i & 31;
                float acc = 0.f;
                for (int m = 0; m < 8; ++m) acc += OADJ3s[n * 8 + m] * X3A[t * 256 + m * 32 + h];
                C1[i] = acc;
            }
            __syncthreads();
            for (int i = tid; i < 512; i += 256) {
                int n = i >> 6, o = i & 63;
                float acc = brel4[o];
                for (int h = 0; h < 32; ++h)
                    acc += C1[n * 32 + h] * WREL4s[h * 64 + o] +
                           X3A[t * 256 + n * 32 + h] * WROOT4s[h * 64 + o];
                outx[((size_t)(b * 16 + t) * 8 + n) * 64 + o] = acc;
            }
            __syncthreads();
        }
    }

    // ---- Phase 9: agg = p1 @ (P2 @ P3)
    {
        float* Q = S;                // 512 (64x8)
        for (int i = tid; i < 512; i += 256) {
            int k = i >> 3, m = i & 7;
            float acc = 0.f;
            for (int l = 0; l < 32; ++l) acc += P2[k * 32 + l] * P3[l * 8 + m];
            Q[i] = acc;
        }
        __syncthreads();
        const float* p1r = p1 + ((size_t)b * 256 + tid) * 64;
        float acc[8];
#pragma unroll
        for (int m = 0; m < 8; ++m) acc[m] = 0.f;
        for (int k = 0; k < 64; ++k) {
            float pv = p1r[k];
#pragma unroll
            for (int m = 0; m < 8; ++m) acc[m] += pv * Q[k * 8 + m];
        }
#pragma unroll
        for (int m = 0; m < 8; ++m)
            outagg[((size_t)b * 256 + tid) * 8 + m] = acc[m];
    }
}

// ---------------- host launch ----------------

extern "C" void kernel_launch(void* const* d_in, const int* in_sizes, int n_in,
                              void* d_out, int out_size, void* d_ws, size_t ws_size,
                              hipStream_t stream) {
    const float* pos    = (const float*)d_in[0];
    const float* ea     = (const float*)d_in[1];
    const int*   esrc   = (const int*)d_in[2];
    const int*   edst   = (const int*)d_in[3];
    const float* W1     = (const float*)d_in[4];
    const float* b1     = (const float*)d_in[5];
    const float* Wp1    = (const float*)d_in[6];
    const float* bp1    = (const float*)d_in[7];
    const float* Wrel2  = (const float*)d_in[8];
    const float* brel2  = (const float*)d_in[9];
    const float* Wroot2 = (const float*)d_in[10];
    const float* Wp2    = (const float*)d_in[11];
    const float* bp2    = (const float*)d_in[12];
    const float* Wrel3  = (const float*)d_in[13];
    const float* brel3  = (const float*)d_in[14];
    const float* Wroot3 = (const float*)d_in[15];
    const float* Wp3    = (const float*)d_in[16];
    const float* bp3    = (const float*)d_in[17];
    const float* Wrel4  = (const float*)d_in[18];
    const float* brel4  = (const float*)d_in[19];
    const float* Wroot4 = (const float*)d_in[20];
    float* out = (float*)d_out;

    char* w = (char*)d_ws;
    float* X    = (float*)(w + 33554432);      // 33.5 MB : y -> TMP
    char* sp    = w + 67108864;
    float* DINV   = (float*)(sp);
    float* DFLAT2 = (float*)(sp + 1114112);
    float* GDEN1  = (float*)(sp + 1146880);
    float* P1     = (float*)(sp + 2162688);
    float* X1A    = (float*)(sp + 6356992);    // Z overlay (Z dead before X1A write)
    float* OADJ1  = (float*)(sp + 14745600);
    float* DFLAT  = (float*)(sp + 17727488);
    float* Z      = X1A;
    float* GBUF1 = (float*)(w + 16777216);     // 8 MB (dead before X1B write)
    float* X1B   = (float*)(w + 16777216);     // [B][16][64][32] = 8 MB
    float* X2A   = (float*)(w + 25165824);     // [B][16][32][32] = 4 MB
    float* X2B   = (float*)(w + 29360128);     // [B][16][32][32] = 4 MB
    float* TMP   = X;
    float* MC    = out + 524288;

    // GCN: edge-built LDS adjacency -> z -> fused y/mean/softmax (MC zeroed in zgemm2)
    k_zgemm2<<<NB * 4, 256, 0, stream>>>(esrc, edst, ea, pos, Z, DINV, MC);
    k_y2<<<NNODES, 512, 0, stream>>>(Z, pos, DINV, W1, b1, Wp1, bp1, X, P1);

    // ---- Level 1
    k_pool4<256, 64, 64, 131072, 32, 512><<<NB * 8, 256, 0, stream>>>(P1, X, X1A);
    k_adjp2<<<NB * 8, 256, 0, stream>>>(esrc, edst, P1, TMP, DFLAT);
    k_ssgp<256, 64, 4, 4, 8><<<NB * 4, 256, 0, stream>>>(P1, TMP, DFLAT, GBUF1, GDEN1);
    k_finish<64, 4, true><<<NB, 256, 0, stream>>>(GBUF1, GDEN1, OADJ1, DFLAT2, MC, MC + 1);
    k_graphconv_t<64, 32><<<NB * TC, 256, 0, stream>>>(OADJ1, X1A, Wrel2, brel2, Wroot2, X1B);

    // ---- Levels 2+3+agg fused, one block per batch
    k_tail<<<NB, 256, 0, stream>>>(X1B, OADJ1, DFLAT2, P1,
                                   Wp2, bp2, Wrel3, brel3, Wroot3,
                                   Wp3, bp3, Wrel4, brel4, Wroot4,
                                   X2A, X2B, out, out + 524290, MC, MC + 1);
}

// Round 10
// 207.149 us; speedup vs baseline: 1.6561x; 1.6561x over previous
//
#include <hip/hip_runtime.h>
#include <math.h>

#define NB 64
#define TC 16
#define HC 32
#define NNODES 16384
#define NEDGES 131072
#define EPG 2048
#define EPSV 1e-15f

static inline int GRID(int n) { return (n + 255) / 256; }

template<int V> struct Log2 { static constexpr int v = 1 + Log2<V/2>::v; };
template<> struct Log2<1> { static constexpr int v = 0; };

// ---------------- GCN front-end ----------------

__global__ void k_zgemm2(const int* __restrict__ esrc, const int* __restrict__ edst,
                         const float* __restrict__ ea, const float* __restrict__ pos,
                         float* __restrict__ z, float* __restrict__ dinv_g,
                         float* __restrict__ mc) {
    __shared__ float dinvs[256];
    __shared__ __align__(16) float as_[64 * 36];
    __shared__ __align__(16) float bs[32 * 48];
    int b = blockIdx.x >> 2;
    int dtile = (blockIdx.x & 3) * 64;
    int tid = threadIdx.x;
    if (blockIdx.x == 0 && tid < 2) mc[tid] = 0.f;
    int ebase = b * EPG;
    int svr[8], dvr[8];
    float evr[8];
#pragma unroll
    for (int j = 0; j < 8; ++j) {
        int e = ebase + tid + j * 256;
        svr[j] = esrc[e] & 255;
        dvr[j] = edst[e] & 255;
        evr[j] = ea[e];
    }
    dinvs[tid] = 1.0f;
    __syncthreads();
#pragma unroll
    for (int j = 0; j < 8; ++j) atomicAdd(&dinvs[dvr[j]], evr[j]);
    __syncthreads();
    float dg = dinvs[tid];
    float dv = (dg > 0.f) ? rsqrtf(dg) : 0.f;
    __syncthreads();
    dinvs[tid] = dv;
    __syncthreads();
    if (dtile == 0) dinv_g[b * 256 + tid] = dinvs[tid];
    int d = tid >> 2, q = tid & 3;
    float acc[12];
#pragma unroll
    for (int j = 0; j < 12; ++j) acc[j] = 0.f;
    const float* pbase = pos + (size_t)b * 256 * 48;
    for (int s0 = 0; s0 < 256; s0 += 32) {
        for (int i = tid; i < 576; i += 256)
            ((float4*)as_)[i] = make_float4(0.f, 0.f, 0.f, 0.f);
        __syncthreads();
#pragma unroll
        for (int j = 0; j < 8; ++j) {
            int dr = dvr[j] - dtile, sc = svr[j] - s0;
            if ((unsigned)dr < 64u && (unsigned)sc < 32u)
                atomicAdd(&as_[dr * 36 + sc], evr[j]);
        }
        for (int i = tid; i < 384; i += 256) {
            int r = i / 12, c = i % 12;
            float4 v = *(const float4*)(pbase + (size_t)(s0 + r) * 48 + c * 4);
            float dd = dinvs[s0 + r];
            v.x *= dd; v.y *= dd; v.z *= dd; v.w *= dd;
            *(float4*)(bs + r * 48 + c * 4) = v;
        }
        __syncthreads();
#pragma unroll 8
        for (int sp = 0; sp < 32; ++sp) {
            float a = as_[d * 36 + sp];
            const float* bp = &bs[sp * 48 + q * 12];
#pragma unroll
            for (int j = 0; j < 12; ++j) acc[j] += a * bp[j];
        }
        __syncthreads();
    }
    float dd = dinvs[dtile + d];
    float* zr = z + (size_t)(b * 256 + dtile + d) * 48 + q * 12;
#pragma unroll
    for (int j = 0; j < 12; ++j) zr[j] = acc[j] * dd;
}

__global__ __launch_bounds__(512) void k_y2(
        const float* __restrict__ z, const float* __restrict__ pos,
        const float* __restrict__ dinv, const float* __restrict__ W1,
        const float* __restrict__ b1, const float* __restrict__ Wp1,
        const float* __restrict__ bp1, float* __restrict__ y,
        float* __restrict__ p1) {
    __shared__ float ys[16][33];
    __shared__ __align__(16) float wp[32 * 64];
    __shared__ float xmv[32];
    int n = blockIdx.x;
    int tid = threadIdx.x;
    int t = tid >> 5, h = tid & 31;
    ((float4*)wp)[tid] = ((const float4*)Wp1)[tid];
    const float* zr = z + (size_t)n * 48 + t * 3;
    const float* pr = pos + (size_t)n * 48 + t * 3;
    float di = dinv[n], d2 = di * di;
    float a0 = zr[0] + pr[0] * d2;
    float a1 = zr[1] + pr[1] * d2;
    float a2 = zr[2] + pr[2] * d2;
    float v = fmaxf(a0 * W1[h] + a1 * W1[32 + h] + a2 * W1[64 + h] + b1[h], 0.f);
    y[(size_t)n * 512 + tid] = v;
    ys[t][h] = v;
    __syncthreads();
    if (tid < 32) {
        float s = 0.f;
#pragma unroll
        for (int tt = 0; tt < 16; ++tt) s += ys[tt][tid];
        xmv[tid] = s * (1.0f / 16.0f);
    }
    __syncthreads();
    if (tid < 64) {
        float acc = bp1[tid];
#pragma unroll 8
        for (int hh = 0; hh < 32; ++hh) acc += xmv[hh] * wp[hh * 64 + tid];
        float vv = tanhf(acc);
        float m = vv;
        for (int o = 32; o > 0; o >>= 1) m = fmaxf(m, __shfl_xor(m, o));
        float e = expf(vv - m);
        float s = e;
        for (int o = 32; o > 0; o >>= 1) s += __shfl_xor(s, o);
        p1[(size_t)n * 64 + tid] = e / s;
    }
}

// ---------------- L1 kernels ----------------

template<int NC, int KC, int NCH, int SB, int STT, int STN>
__global__ void k_pool4(const float* __restrict__ p, const float* __restrict__ x,
                        float* __restrict__ outp) {
    constexpr int TPT = KC * 2;
    constexpr int TPB = 256 / TPT;
    constexpr int NTILE = TC / TPB;
    __shared__ __align__(16) float ps[NCH * KC];
    __shared__ __align__(16) float xs[TPB * NCH * HC];
    int b = blockIdx.x / NTILE;
    int t0 = (blockIdx.x % NTILE) * TPB;
    int tid = threadIdx.x;
    int th = tid / TPT;
    int r = tid % TPT;
    int k0 = (r >> 3) * 4;
    int h0 = (r & 7) * 4;
    float acc[4][4];
#pragma unroll
    for (int rr = 0; rr < 4; ++rr)
#pragma unroll
        for (int cc = 0; cc < 4; ++cc) acc[rr][cc] = 0.f;
    const float* pbase = p + (size_t)b * NC * KC;
    const float* xbase = x + (size_t)b * SB + (size_t)t0 * STT;
    for (int n0 = 0; n0 < NC; n0 += NCH) {
        for (int i = tid; i < NCH * KC / 4; i += 256)
            ((float4*)ps)[i] = ((const float4*)(pbase + (size_t)n0 * KC))[i];
        for (int i = tid; i < TPB * NCH * 8; i += 256) {
            int q = i & 7;
            int n = (i >> 3) % NCH;
            int tt = i / (NCH * 8);
            *(float4*)&xs[(tt * NCH + n) * HC + q * 4] =
                *(const float4*)(xbase + (size_t)tt * STT + (size_t)(n0 + n) * STN + q * 4);
        }
        __syncthreads();
#pragma unroll 4
        for (int n = 0; n < NCH; ++n) {
            float4 kv4 = *(const float4*)&ps[n * KC + k0];
            float4 xv4 = *(const float4*)&xs[(th * NCH + n) * HC + h0];
            float kv[4] = {kv4.x, kv4.y, kv4.z, kv4.w};
            float xv[4] = {xv4.x, xv4.y, xv4.z, xv4.w};
#pragma unroll
            for (int rr = 0; rr < 4; ++rr)
#pragma unroll
                for (int cc = 0; cc < 4; ++cc) acc[rr][cc] += kv[rr] * xv[cc];
        }
        __syncthreads();
    }
    float* ob = outp + (((size_t)(b * TC + t0 + th) * KC + k0) * HC + h0);
#pragma unroll
    for (int rr = 0; rr < 4; ++rr) {
        float4 v = {acc[rr][0], acc[rr][1], acc[rr][2], acc[rr][3]};
        *(float4*)(ob + (size_t)rr * HC) = v;
    }
}

__global__ void k_adjp2(const int* __restrict__ esrc, const int* __restrict__ edst,
                        const float* __restrict__ p, float* __restrict__ tmp,
                        float* __restrict__ dflat) {
    __shared__ __align__(16) float as_[32 * 260];
    __shared__ __align__(16) float ps[64 * 64];
    int b = blockIdx.x >> 3;
    int nt0 = (blockIdx.x & 7) * 32;
    int tid = threadIdx.x;
    for (int i = tid; i < 32 * 260 / 4; i += 256)
        ((float4*)as_)[i] = make_float4(0.f, 0.f, 0.f, 0.f);
    __syncthreads();
    int ebase = b * EPG;
#pragma unroll
    for (int j = 0; j < 8; ++j) {
        int e = ebase + tid + j * 256;
        int sv = esrc[e] & 255;
        int nr = sv - nt0;
        if ((unsigned)nr < 32u)
            atomicAdd(&as_[nr * 260 + (edst[e] & 255)], 1.0f);
    }
    __syncthreads();
    int n = tid >> 3, l0 = (tid & 7) * 8;
    float acc[8];
#pragma unroll
    for (int j = 0; j < 8; ++j) acc[j] = 0.f;
    float rs = 0.f;
    for (int m0 = 0; m0 < 256; m0 += 64) {
        for (int i = tid; i < 64 * 64 / 4; i += 256)
            ((float4*)ps)[i] = ((const float4*)(p + ((size_t)b * 256 + m0) * 64))[i];
        __syncthreads();
#pragma unroll 4
        for (int m = 0; m < 64; ++m) {
            float av = as_[n * 260 + m0 + m];
            rs += av;
            float4 p0 = *(const float4*)&ps[m * 64 + l0];
            float4 p1v = *(const float4*)&ps[m * 64 + l0 + 4];
            acc[0] += av * p0.x; acc[1] += av * p0.y; acc[2] += av * p0.z; acc[3] += av * p0.w;
            acc[4] += av * p1v.x; acc[5] += av * p1v.y; acc[6] += av * p1v.z; acc[7] += av * p1v.w;
        }
        __syncthreads();
    }
#pragma unroll
    for (int j = 0; j < 8; ++j)
        tmp[((size_t)b * 256 + nt0 + n) * 64 + l0 + j] = acc[j];
    if ((tid & 7) == 0) dflat[(size_t)b * 256 + nt0 + n] = rs;
}

__device__ inline float blk_sum256(float v, float* rbuf) {
    for (int o = 32; o > 0; o >>= 1) v += __shfl_xor(v, o);
    __syncthreads();
    if ((threadIdx.x & 63) == 0) rbuf[threadIdx.x >> 6] = v;
    __syncthreads();
    return rbuf[0] + rbuf[1] + rbuf[2] + rbuf[3];
}

template<int NC, int KC, int NSPLIT, int KT, int LT>
__global__ void k_ssgp(const float* __restrict__ p, const float* __restrict__ tmp,
                       const float* __restrict__ dflat, float* __restrict__ G,
                       float* __restrict__ Gden) {
    constexpr int NCH = NC / NSPLIT;
    constexpr int LC = 2 * KC;
    constexpr int KQ = KC / 4;
    __shared__ __align__(16) float ab[NCH * LC];
    __shared__ float rbuf[4];
    int b = blockIdx.x / NSPLIT;
    int split = blockIdx.x % NSPLIT;
    int n0 = split * NCH;
    int tid = threadIdx.x;
    const float* pb = p + ((size_t)b * NC + n0) * KC;
    const float* tb = tmp + ((size_t)b * NC + n0) * KC;
    const float* db = dflat + (size_t)b * NC + n0;
    for (int i = tid; i < NCH * KQ; i += 256) {
        int r = i / KQ, c = i % KQ;
        *(float4*)(ab + r * LC + c * 4) = ((const float4*)pb)[i];
        *(float4*)(ab + r * LC + KC + c * 4) = ((const float4*)tb)[i];
    }
    __syncthreads();
    float den = 0.f;
    for (int i = tid; i < NCH * KQ; i += 256) {
        int r = i / KQ, c = i % KQ;
        float4 v = *(const float4*)(ab + r * LC + c * 4);
        den += (v.x * v.x + v.y * v.y + v.z * v.z + v.w * v.w) * db[r];
    }
    int kt = tid >> 4, lt = tid & 15;
    int k0 = kt * KT, l0 = lt * LT;
    float acc[KT][LT];
#pragma unroll
    for (int r = 0; r < KT; ++r)
#pragma unroll
        for (int c = 0; c < LT; ++c) acc[r][c] = 0.f;
#pragma unroll 4
    for (int n = 0; n < NCH; ++n) {
        float kv[KT], lv[LT];
#pragma unroll
        for (int r = 0; r < KT; ++r) kv[r] = ab[n * LC + k0 + r];
#pragma unroll
        for (int c = 0; c < LT; ++c) lv[c] = ab[n * LC + l0 + c];
#pragma unroll
        for (int r = 0; r < KT; ++r)
#pragma unroll
            for (int c = 0; c < LT; ++c) acc[r][c] += kv[r] * lv[c];
    }
    float* Gb = G + ((size_t)split * NB + b) * (KC * LC);
#pragma unroll
    for (int r = 0; r < KT; ++r)
#pragma unroll
        for (int c = 0; c < LT; ++c)
            Gb[(k0 + r) * LC + l0 + c] = acc[r][c];
    float dt = blk_sum256(den, rbuf);
    if (tid == 0) Gden[(size_t)split * NB + b] = dt;
}

template<int KC, int NSPLIT, bool DFN>
__global__ void k_finish(const float* __restrict__ G, const float* __restrict__ Gden,
                         float* __restrict__ oadj_out, float* __restrict__ dfn_out,
                         float* __restrict__ mc_out, float* __restrict__ or_out) {
    constexpr int LK = Log2<KC>::v;
    constexpr int KCP = KC + 1;
    constexpr int LC = 2 * KC;
    __shared__ float sss[KC * KCP];
    __shared__ float oss[KC * KCP];
    __shared__ float dvv[KC];
    __shared__ float rbuf[4];
    int b = blockIdx.x, tid = threadIdx.x;
    for (int i = tid; i < KC * KC; i += 256) {
        int k = i >> LK, l = i & (KC - 1);
        float sv = 0.f, ov = 0.f;
#pragma unroll
        for (int s = 0; s < NSPLIT; ++s) {
            const float* Gb = G + ((size_t)s * NB + b) * KC * LC;
            sv += Gb[k * LC + l];
            ov += Gb[k * LC + KC + l];
        }
        sss[k * KCP + l] = sv;
        oss[k * KCP + l] = ov;
    }
    __syncthreads();
    float ssn2 = 0.f;
    for (int i = tid; i < KC * KC; i += 256) {
        int k = i >> LK, l = i & (KC - 1);
        float v = sss[k * KCP + l];
        ssn2 += v * v;
    }
    float num = 0.f;
    for (int k = tid; k < KC; k += 256) num += oss[k * KCP + k];
    float ssn2_t = blk_sum256(ssn2, rbuf);
    float num_t = blk_sum256(num, rbuf);
    float den_t = 0.f;
#pragma unroll
    for (int s = 0; s < NSPLIT; ++s) den_t += Gden[(size_t)s * NB + b];
    float inv = 1.0f / sqrtf(ssn2_t);
    float dk = rsqrtf((float)KC);
    float o2 = 0.f;
    for (int i = tid; i < KC * KC; i += 256) {
        int k = i >> LK, l = i & (KC - 1);
        float v = sss[k * KCP + l] * inv - ((k == l) ? dk : 0.f);
        o2 += v * v;
    }
    float o2_t = blk_sum256(o2, rbuf);
    if (tid == 0) {
        atomicAdd(mc_out, -(num_t / den_t) * (1.0f / NB));
        atomicAdd(or_out, sqrtf(o2_t) * (1.0f / NB));
    }
    if (tid < KC) {
        float rs = 0.f;
        for (int l = 0; l < KC; ++l) rs += oss[tid * KCP + l];
        rs -= oss[tid * KCP + tid];
        dvv[tid] = sqrtf(rs) + EPSV;
    }
    __syncthreads();
    for (int i = tid; i < KC * KC; i += 256) {
        int k = i >> LK, l = i & (KC - 1);
        float v = (k == l) ? 0.f : oss[k * KCP + l] / (dvv[k] * dvv[l]);
        oadj_out[(size_t)b * KC * KC + i] = v;
    }
    if (DFN && tid < KC) {
        float s = 0.f;
        for (int l = 0; l < KC; ++l)
            if (l != tid) s += oss[tid * KCP + l] / (dvv[tid] * dvv[l]);
        dfn_out[(size_t)b * KC + tid] = s;
    }
}

template<int NC2, int OC>
__global__ void k_graphconv_t(const float* __restrict__ adjn, const float* __restrict__ x,
                              const float* __restrict__ Wrel, const float* __restrict__ brel,
                              const float* __restrict__ Wroot, float* __restrict__ outp) {
    constexpr int EL1 = NC2 * HC / 256;
    constexpr int EL2 = NC2 * OC / 256;
    constexpr int LOC = Log2<OC>::v;
    __shared__ __align__(16) float xs[NC2 * HC];
    __shared__ __align__(16) float as_[NC2 * NC2];
    __shared__ float c1[NC2 * HC];
    int bt = blockIdx.x;
    int b = bt >> 4;
    int tid = threadIdx.x;
    for (int i = tid; i < NC2 * HC / 4; i += 256)
        ((float4*)xs)[i] = ((const float4*)(x + (size_t)bt * NC2 * HC))[i];
    for (int i = tid; i < NC2 * NC2 / 4; i += 256)
        ((float4*)as_)[i] = ((const float4*)(adjn + (size_t)b * NC2 * NC2))[i];
    __syncthreads();
#pragma unroll
    for (int e = 0; e < EL1; ++e) {
        int idx = tid + e * 256;
        int hh = idx & 31, n = idx >> 5;
        float acc = 0.f;
#pragma unroll 8
        for (int m = 0; m < NC2; ++m) acc += as_[n * NC2 + m] * xs[m * HC + hh];
        c1[idx] = acc;
    }
    __syncthreads();
#pragma unroll
    for (int e = 0; e < EL2; ++e) {
        int idx = tid + e * 256;
        int o = idx & (OC - 1), n = idx >> LOC;
        float acc = brel[o];
#pragma unroll 8
        for (int hh = 0; hh < HC; ++hh)
            acc += c1[n * HC + hh] * Wrel[hh * OC + o] + xs[n * HC + hh] * Wroot[hh * OC + o];
        outp[(size_t)bt * NC2 * OC + idx] = acc;
    }
}

// ---------------- tail A: per-batch planning (P2, losses2, OADJ2, P3, losses3, OADJ3, agg) ----------------

__global__ __launch_bounds__(256) void k_tail_a(
        const float* __restrict__ x1b, const float* __restrict__ oadj1,
        const float* __restrict__ dflat2, const float* __restrict__ p1,
        const float* __restrict__ Wp2, const float* __restrict__ bp2,
        const float* __restrict__ Wrel3, const float* __restrict__ brel3,
        const float* __restrict__ Wroot3,
        const float* __restrict__ Wp3, const float* __restrict__ bp3,
        float* __restrict__ P2G, float* __restrict__ OADJ2G,
        float* __restrict__ P3G, float* __restrict__ OADJ3G,
        float* __restrict__ outagg,
        float* __restrict__ mc_out, float* __restrict__ or_out) {
    __shared__ float lds[13072];
    float* XM2    = lds;            // 64x36
    float* P2     = lds + 2304;     // 64x36
    float* OADJ2L = lds + 4608;     // 32x36
    float* P3L    = lds + 5760;     // 32x8
    float* OADJ3L = lds + 6016;     // 8x8
    float* DF3    = lds + 6080;     // 32
    float* DVV    = lds + 6112;     // 40
    float* RBUF   = lds + 6152;     // 4
    float* S      = lds + 6160;     // 6912 scratch

    int b = blockIdx.x, tid = threadIdx.x;
    const float* x1bb = x1b + (size_t)b * 32768;

    // Phase 1: XM2 = mean_t x1b
    for (int i = tid; i < 2048; i += 256) {
        float s = 0.f;
        for (int t = 0; t < 16; ++t) s += x1bb[t * 2048 + i];
        XM2[(i >> 5) * 36 + (i & 31)] = s * (1.0f / 16.0f);
    }
    // Phase 2: P2 = softmax(tanh(XM2@Wp2+bp2))
    {
        float* S2 = S;             // 2048 (stride 32)
        float* WP2s = S + 2048;    // 1024
        for (int i = tid; i < 1024; i += 256) WP2s[i] = Wp2[i];
        __syncthreads();
        for (int i = tid; i < 2048; i += 256) {
            int n = i >> 5, k = i & 31;
            float acc = bp2[k];
            for (int h = 0; h < 32; ++h) acc += XM2[n * 36 + h] * WP2s[h * 32 + k];
            S2[i] = tanhf(acc);
        }
        __syncthreads();
        int lane = tid & 31, rr = tid >> 5;
        for (int r0 = 0; r0 < 64; r0 += 8) {
            int row = r0 + rr;
            float v = S2[row * 32 + lane];
            float m = v;
            for (int o = 16; o > 0; o >>= 1) m = fmaxf(m, __shfl_xor(m, o, 32));
            float e = expf(v - m);
            float s = e;
            for (int o = 16; o > 0; o >>= 1) s += __shfl_xor(s, o, 32);
            P2[row * 36 + lane] = e / s;
        }
        __syncthreads();
        for (int i = tid; i < 2048; i += 256)
            P2G[(size_t)b * 2048 + i] = P2[(i >> 5) * 36 + (i & 31)];
    }
    // Phase 3: TMP2 = OADJ1 @ P2
    float* TMP2 = S + 4352;        // 64x36 = 2304
    {
        float* OADJ1s = S;         // 64x68 = 4352
        for (int i = tid; i < 4096; i += 256)
            OADJ1s[(i >> 6) * 68 + (i & 63)] = oadj1[(size_t)b * 4096 + i];
        __syncthreads();
        int n = tid >> 2, l0 = (tid & 3) * 8;
        float acc[8];
#pragma unroll
        for (int j = 0; j < 8; ++j) acc[j] = 0.f;
        for (int m = 0; m < 64; ++m) {
            float av = OADJ1s[n * 68 + m];
            float4 pa = *(const float4*)&P2[m * 36 + l0];
            float4 pb = *(const float4*)&P2[m * 36 + l0 + 4];
            acc[0] += av * pa.x; acc[1] += av * pa.y; acc[2] += av * pa.z; acc[3] += av * pa.w;
            acc[4] += av * pb.x; acc[5] += av * pb.y; acc[6] += av * pb.z; acc[7] += av * pb.w;
        }
        __syncthreads();
#pragma unroll
        for (int j = 0; j < 8; ++j) TMP2[n * 36 + l0 + j] = acc[j];
        __syncthreads();
    }
    // Phase 4: GS/GO, losses L2, OADJ2L, DF3
    {
        float* GS = S;             // 32x33
        float* GO = S + 1056;      // 32x33
        int k = tid >> 3, l0 = (tid & 7) * 4;
        float as4[4] = {0, 0, 0, 0}, ao4[4] = {0, 0, 0, 0};
        for (int n = 0; n < 64; ++n) {
            float pv = P2[n * 36 + k];
            float4 lp = *(const float4*)&P2[n * 36 + l0];
            float4 lt = *(const float4*)&TMP2[n * 36 + l0];
            as4[0] += pv * lp.x; as4[1] += pv * lp.y; as4[2] += pv * lp.z; as4[3] += pv * lp.w;
            ao4[0] += pv * lt.x; ao4[1] += pv * lt.y; ao4[2] += pv * lt.z; ao4[3] += pv * lt.w;
        }
#pragma unroll
        for (int j = 0; j < 4; ++j) {
            GS[k * 33 + l0 + j] = as4[j];
            GO[k * 33 + l0 + j] = ao4[j];
        }
        __syncthreads();
        const float* df2 = dflat2 + (size_t)b * 64;
        float den = 0.f;
        for (int i = tid; i < 2048; i += 256) {
            float pv = P2[(i >> 5) * 36 + (i & 31)];
            den += pv * pv * df2[i >> 5];
        }
        float ssn2 = 0.f;
        for (int i = tid; i < 1024; i += 256) {
            float v = GS[(i >> 5) * 33 + (i & 31)];
            ssn2 += v * v;
        }
        float num = 0.f;
        for (int kk = tid; kk < 32; kk += 256) num += GO[kk * 33 + kk];
        float den_t = blk_sum256(den, RBUF);
        float ssn2_t = blk_sum256(ssn2, RBUF);
        float num_t = blk_sum256(num, RBUF);
        float inv = 1.0f / sqrtf(ssn2_t);
        float dk = rsqrtf(32.0f);
        float o2 = 0.f;
        for (int i = tid; i < 1024; i += 256) {
            int kk = i >> 5, ll = i & 31;
            float v = GS[kk * 33 + ll] * inv - ((kk == ll) ? dk : 0.f);
            o2 += v * v;
        }
        float o2_t = blk_sum256(o2, RBUF);
        if (tid == 0) {
            atomicAdd(mc_out, -(num_t / den_t) * (1.0f / NB));
            atomicAdd(or_out, sqrtf(o2_t) * (1.0f / NB));
        }
        if (tid < 32) {
            float rs = 0.f;
            for (int l = 0; l < 32; ++l) rs += GO[tid * 33 + l];
            rs -= GO[tid * 33 + tid];
            DVV[tid] = sqrtf(rs) + EPSV;
        }
        __syncthreads();
        for (int i = tid; i < 1024; i += 256) {
            int kk = i >> 5, ll = i & 31;
            float v = (kk == ll) ? 0.f : GO[kk * 33 + ll] / (DVV[kk] * DVV[ll]);
            OADJ2L[kk * 36 + ll] = v;
            OADJ2G[(size_t)b * 1024 + i] = v;
        }
        __syncthreads();
        if (tid < 32) {
            float s = 0.f;
            for (int l = 0; l < 32; ++l) s += OADJ2L[tid * 36 + l];
            DF3[tid] = s;
        }
        __syncthreads();
    }
    // Phase 5: XM2A = P2^T @ XM2   [32x36]
    float* XM2A = S;               // 1152
    {
        int k = tid >> 3, h0 = (tid & 7) * 4;
        float a4[4] = {0, 0, 0, 0};
        for (int n = 0; n < 64; ++n) {
            float pv = P2[n * 36 + k];
            float4 xv = *(const float4*)&XM2[n * 36 + h0];
            a4[0] += pv * xv.x; a4[1] += pv * xv.y; a4[2] += pv * xv.z; a4[3] += pv * xv.w;
        }
        __syncthreads();
        *(float4*)&XM2A[k * 36 + h0] = make_float4(a4[0], a4[1], a4[2], a4[3]);
        __syncthreads();
    }
    // Phase 6: XM2B = graphconv2(XM2A) = (OADJ2@XM2A)@Wrel3 + brel3 + XM2A@Wroot3
    float* XM2B = S + 4352;        // 1152
    {
        float* WREL3s = S + 1152;  // 1024
        float* WROOT3s = S + 2176; // 1024
        float* C1 = S + 3200;      // 1152
        for (int i = tid; i < 1024; i += 256) {
            WREL3s[i] = Wrel3[i];
            WROOT3s[i] = Wroot3[i];
        }
        __syncthreads();
        int n = tid >> 3, j0 = (tid & 7) * 4;
        float a4[4] = {0, 0, 0, 0};
        for (int m = 0; m < 32; ++m) {
            float av = OADJ2L[n * 36 + m];
            float4 xv = *(const float4*)&XM2A[m * 36 + j0];
            a4[0] += av * xv.x; a4[1] += av * xv.y; a4[2] += av * xv.z; a4[3] += av * xv.w;
        }
        __syncthreads();
        *(float4*)&C1[n * 36 + j0] = make_float4(a4[0], a4[1], a4[2], a4[3]);
        __syncthreads();
        float o4[4];
#pragma unroll
        for (int j = 0; j < 4; ++j) o4[j] = brel3[j0 + j];
        for (int h = 0; h < 32; ++h) {
            float c1v = C1[n * 36 + h];
            float xav = XM2A[n * 36 + h];
            float4 wr = *(const float4*)&WREL3s[h * 32 + j0];
            float4 wo = *(const float4*)&WROOT3s[h * 32 + j0];
            o4[0] += c1v * wr.x + xav * wo.x;
            o4[1] += c1v * wr.y + xav * wo.y;
            o4[2] += c1v * wr.z + xav * wo.z;
            o4[3] += c1v * wr.w + xav * wo.w;
        }
        __syncthreads();
        *(float4*)&XM2B[n * 36 + j0] = make_float4(o4[0], o4[1], o4[2], o4[3]);
        __syncthreads();
    }
    // Phase 7: P3 = softmax(tanh(XM2B@Wp3+bp3))
    {
        float* WP3s = S;           // 256 (XM2A dead)
        for (int i = tid; i < 256; i += 256) WP3s[i] = Wp3[i];
        __syncthreads();
        int n = tid >> 3, kk = tid & 7;
        float acc = bp3[kk];
        for (int h = 0; h < 32; ++h) acc += XM2B[n * 36 + h] * WP3s[h * 8 + kk];
        float v = tanhf(acc);
        float m = v;
        for (int o = 4; o > 0; o >>= 1) m = fmaxf(m, __shfl_xor(m, o, 8));
        float e = expf(v - m);
        float s = e;
        for (int o = 4; o > 0; o >>= 1) s += __shfl_xor(s, o, 8);
        P3L[n * 8 + kk] = e / s;
        __syncthreads();
        if (tid < 256) P3G[(size_t)b * 256 + tid] = P3L[tid];
        __syncthreads();
    }
    // Phase 8: L3 losses + OADJ3
    {
        float* TMP3 = S;           // 256
        float* GS3 = S + 256;      // 72
        float* GO3 = S + 336;      // 72
        int n = tid >> 3, l = tid & 7;
        float acc = 0.f;
        for (int m = 0; m < 32; ++m) acc += OADJ2L[n * 36 + m] * P3L[m * 8 + l];
        TMP3[n * 8 + l] = acc;
        __syncthreads();
        if (tid < 64) {
            int k = tid >> 3, ll = tid & 7;
            float accs = 0.f, acco = 0.f;
            for (int nn = 0; nn < 32; ++nn) {
                float pv = P3L[nn * 8 + k];
                accs += pv * P3L[nn * 8 + ll];
                acco += pv * TMP3[nn * 8 + ll];
            }
            GS3[k * 9 + ll] = accs;
            GO3[k * 9 + ll] = acco;
        }
        __syncthreads();
        float den = 0.f;
        {
            float pv = P3L[tid];
            den = pv * pv * DF3[tid >> 3];
        }
        float ssn2 = 0.f;
        if (tid < 64) {
            float v = GS3[(tid >> 3) * 9 + (tid & 7)];
            ssn2 = v * v;
        }
        float num = 0.f;
        if (tid < 8) num = GO3[tid * 9 + tid];
        float den_t = blk_sum256(den, RBUF);
        float ssn2_t = blk_sum256(ssn2, RBUF);
        float num_t = blk_sum256(num, RBUF);
        float inv = 1.0f / sqrtf(ssn2_t);
        float dk = rsqrtf(8.0f);
        float o2 = 0.f;
        if (tid < 64) {
            int k = tid >> 3, ll = tid & 7;
            float v = GS3[k * 9 + ll] * inv - ((k == ll) ? dk : 0.f);
            o2 = v * v;
        }
        float o2_t = blk_sum256(o2, RBUF);
        if (tid == 0) {
            atomicAdd(mc_out, -(num_t / den_t) * (1.0f / NB));
            atomicAdd(or_out, sqrtf(o2_t) * (1.0f / NB));
        }
        if (tid < 8) {
            float rs = 0.f;
            for (int ll = 0; ll < 8; ++ll) rs += GO3[tid * 9 + ll];
            rs -= GO3[tid * 9 + tid];
            DVV[32 + tid] = sqrtf(rs) + EPSV;
        }
        __syncthreads();
        if (tid < 64) {
            int k = tid >> 3, ll = tid & 7;
            float v = (k == ll) ? 0.f : GO3[k * 9 + ll] / (DVV[32 + k] * DVV[32 + ll]);
            OADJ3L[tid] = v;
            OADJ3G[(size_t)b * 64 + tid] = v;
        }
        __syncthreads();
    }
    // Phase 9: agg = p1 @ (P2 @ P3)
    {
        float* Q = S;              // 512
        for (int i = tid; i < 512; i += 256) {
            int k = i >> 3, m = i & 7;
            float acc = 0.f;
            for (int l = 0; l < 32; ++l) acc += P2[k * 36 + l] * P3L[l * 8 + m];
            Q[i] = acc;
        }
        __syncthreads();
        const float* p1r = p1 + ((size_t)b * 256 + tid) * 64;
        float acc[8];
#pragma unroll
        for (int m = 0; m < 8; ++m) acc[m] = 0.f;
        for (int k = 0; k < 64; ++k) {
            float pv = p1r[k];
#pragma unroll
            for (int m = 0; m < 8; ++m) acc[m] += pv * Q[k * 8 + m];
        }
#pragma unroll
        for (int m = 0; m < 8; ++m)
            outagg[((size_t)b * 256 + tid) * 8 + m] = acc[m];
    }
}

// ---------------- tail B: per-(b,t) heavy path, fully LDS-resident ----------------

__global__ __launch_bounds__(256) void k_tail_b(
        const float* __restrict__ x1b, const float* __restrict__ P2G,
        const float* __restrict__ OADJ2G, const float* __restrict__ P3G,
        const float* __restrict__ OADJ3G,
        const float* __restrict__ Wrel3, const float* __restrict__ brel3,
        const float* __restrict__ Wroot3,
        const float* __restrict__ Wrel4, const float* __restrict__ brel4,
        const float* __restrict__ Wroot4,
        float* __restrict__ outx) {
    __shared__ float A[6912];
    int bt = blockIdx.x;
    int b = bt >> 4;
    int tid = threadIdx.x;

    // Phase 1: X2A = P2^T @ x1b_t
    float* X2A = A + 4608;         // 32x36, persists
    {
        float* X1BT = A;           // 64x36
        float* P2s = A + 2304;     // 64x36
        for (int i = tid; i < 2048; i += 256) {
            X1BT[(i >> 5) * 36 + (i & 31)] = x1b[(size_t)bt * 2048 + i];
            P2s[(i >> 5) * 36 + (i & 31)] = P2G[(size_t)b * 2048 + i];
        }
        __syncthreads();
        int k = tid >> 3, h0 = (tid & 7) * 4;
        float a4[4] = {0, 0, 0, 0};
        for (int n = 0; n < 64; ++n) {
            float pv = P2s[n * 36 + k];
            float4 xv = *(const float4*)&X1BT[n * 36 + h0];
            a4[0] += pv * xv.x; a4[1] += pv * xv.y; a4[2] += pv * xv.z; a4[3] += pv * xv.w;
        }
        __syncthreads();
        *(float4*)&X2A[k * 36 + h0] = make_float4(a4[0], a4[1], a4[2], a4[3]);
        __syncthreads();
    }
    // Phase 2: X2B = graphconv2(X2A)
    float* X2B = A + 5760;         // 32x36
    {
        float* OADJ2s = A;         // 32x36
        float* WREL3s = A + 1152;  // 1024
        float* WROOT3s = A + 2176; // 1024
        float* C1 = A + 3200;      // 32x36
        for (int i = tid; i < 1024; i += 256) {
            OADJ2s[(i >> 5) * 36 + (i & 31)] = OADJ2G[(size_t)b * 1024 + i];
            WREL3s[i] = Wrel3[i];
            WROOT3s[i] = Wroot3[i];
        }
        __syncthreads();
        int n = tid >> 3, j0 = (tid & 7) * 4;
        float a4[4] = {0, 0, 0, 0};
        for (int m = 0; m < 32; ++m) {
            float av = OADJ2s[n * 36 + m];
            float4 xv = *(const float4*)&X2A[m * 36 + j0];
            a4[0] += av * xv.x; a4[1] += av * xv.y; a4[2] += av * xv.z; a4[3] += av * xv.w;
        }
        __syncthreads();
        *(float4*)&C1[n * 36 + j0] = make_float4(a4[0], a4[1], a4[2], a4[3]);
        __syncthreads();
        float o4[4];
#pragma unroll
        for (int j = 0; j < 4; ++j) o4[j] = brel3[j0 + j];
        for (int h = 0; h < 32; ++h) {
            float c1v = C1[n * 36 + h];
            float xav = X2A[n * 36 + h];
            float4 wr = *(const float4*)&WREL3s[h * 32 + j0];
            float4 wo = *(const float4*)&WROOT3s[h * 32 + j0];
            o4[0] += c1v * wr.x + xav * wo.x;
            o4[1] += c1v * wr.y + xav * wo.y;
            o4[2] += c1v * wr.z + xav * wo.z;
            o4[3] += c1v * wr.w + xav * wo.w;
        }
        __syncthreads();
        *(float4*)&X2B[n * 36 + j0] = make_float4(o4[0], o4[1], o4[2], o4[3]);
        __syncthreads();
    }
    // Phase 3: X3A = P3^T @ X2B
    float* X3A = A + 288;          // 8x36
    {
        float* P3s = A;            // 256
        if (tid < 256) P3s[tid] = P3G[(size_t)b * 256 + tid];
        __syncthreads();
        int k = tid >> 5, h = tid & 31;
        float acc = 0.f;
        for (int n = 0; n < 32; ++n) acc += P3s[n * 8 + k] * X2B[n * 36 + h];
        __syncthreads();
        X3A[k * 36 + h] = acc;
        __syncthreads();
    }
    // Phase 4: out_t = graphconv3(X3A)
    {
        float* OADJ3s = A + 576;   // 64
        float* WREL4s = A + 640;   // 2048
        float* WROOT4s = A + 2688; // 2048
        float* C3 = A + 4736;      // 8x36
        if (tid < 64) OADJ3s[tid] = OADJ3G[(size_t)b * 64 + tid];
        for (int i = tid; i < 2048; i += 256) {
            WREL4s[i] = Wrel4[i];
            WROOT4s[i] = Wroot4[i];
        }
        __syncthreads();
        int n = tid >> 5, h = tid & 31;
        float acc = 0.f;
#pragma unroll
        for (int m = 0; m < 8; ++m) acc += OADJ3s[n * 8 + m] * X3A[m * 36 + h];
        C3[n * 36 + h] = acc;
        __syncthreads();
        int o0 = (tid & 31) * 2;
        float a0 = brel4[o0], a1 = brel4[o0 + 1];
        for (int hh = 0; hh < 32; ++hh) {
            float c3v = C3[n * 36 + hh];
            float x3v = X3A[n * 36 + hh];
            a0 += c3v * WREL4s[hh * 64 + o0] + x3v * WROOT4s[hh * 64 + o0];
            a1 += c3v * WREL4s[hh * 64 + o0 + 1] + x3v * WROOT4s[hh * 64 + o0 + 1];
        }
        float* ob = outx + ((size_t)bt * 8 + n) * 64 + o0;
        ob[0] = a0;
        ob[1] = a1;
    }
}

// ---------------- host launch ----------------

extern "C" void kernel_launch(void* const* d_in, const int* in_sizes, int n_in,
                              void* d_out, int out_size, void* d_ws, size_t ws_size,
                              hipStream_t stream) {
    const float* pos    = (const float*)d_in[0];
    const float* ea     = (const float*)d_in[1];
    const int*   esrc   = (const int*)d_in[2];
    const int*   edst   = (const int*)d_in[3];
    const float* W1     = (const float*)d_in[4];
    const float* b1     = (const float*)d_in[5];
    const float* Wp1    = (const float*)d_in[6];
    const float* bp1    = (const float*)d_in[7];
    const float* Wrel2  = (const float*)d_in[8];
    const float* brel2  = (const float*)d_in[9];
    const float* Wroot2 = (const float*)d_in[10];
    const float* Wp2    = (const float*)d_in[11];
    const float* bp2    = (const float*)d_in[12];
    const float* Wrel3  = (const float*)d_in[13];
    const float* brel3  = (const float*)d_in[14];
    const float* Wroot3 = (const float*)d_in[15];
    const float* Wp3    = (const float*)d_in[16];
    const float* bp3    = (const float*)d_in[17];
    const float* Wrel4  = (const float*)d_in[18];
    const float* brel4  = (const float*)d_in[19];
    const float* Wroot4 = (const float*)d_in[20];
    float* out = (float*)d_out;

    char* w = (char*)d_ws;
    float* X    = (float*)(w + 33554432);      // 33.5 MB : y -> TMP
    char* sp    = w + 67108864;
    float* DINV   = (float*)(sp);
    float* DFLAT2 = (float*)(sp + 1114112);
    float* GDEN1  = (float*)(sp + 1146880);
    float* P1     = (float*)(sp + 2162688);
    float* X1A    = (float*)(sp + 6356992);    // Z overlay
    float* OADJ1  = (float*)(sp + 14745600);
    float* DFLAT  = (float*)(sp + 17727488);
    float* P2G    = (float*)(sp + 18874368);   // 512 KB
    float* OADJ2G = (float*)(sp + 19398656);   // 256 KB
    float* P3G    = (float*)(sp + 19660800);   // 64 KB
    float* OADJ3G = (float*)(sp + 19726336);   // 16 KB
    float* Z      = X1A;
    float* GBUF1 = (float*)(w + 16777216);     // 8 MB (dead before X1B write)
    float* X1B   = (float*)(w + 16777216);     // [B][16][64][32] = 8 MB
    float* TMP   = X;
    float* MC    = out + 524288;

    // GCN front-end
    k_zgemm2<<<NB * 4, 256, 0, stream>>>(esrc, edst, ea, pos, Z, DINV, MC);
    k_y2<<<NNODES, 512, 0, stream>>>(Z, pos, DINV, W1, b1, Wp1, bp1, X, P1);

    // ---- Level 1
    k_pool4<256, 64, 64, 131072, 32, 512><<<NB * 8, 256, 0, stream>>>(P1, X, X1A);
    k_adjp2<<<NB * 8, 256, 0, stream>>>(esrc, edst, P1, TMP, DFLAT);
    k_ssgp<256, 64, 4, 4, 8><<<NB * 4, 256, 0, stream>>>(P1, TMP, DFLAT, GBUF1, GDEN1);
    k_finish<64, 4, true><<<NB, 256, 0, stream>>>(GBUF1, GDEN1, OADJ1, DFLAT2, MC, MC + 1);
    k_graphconv_t<64, 32><<<NB * TC, 256, 0, stream>>>(OADJ1, X1A, Wrel2, brel2, Wroot2, X1B);

    // ---- Tail: per-batch planning + per-(b,t) heavy path
    k_tail_a<<<NB, 256, 0, stream>>>(X1B, OADJ1, DFLAT2, P1,
                                     Wp2, bp2, Wrel3, brel3, Wroot3, Wp3, bp3,
                                     P2G, OADJ2G, P3G, OADJ3G,
                                     out + 524290, MC, MC + 1);
    k_tail_b<<<NB * TC, 256, 0, stream>>>(X1B, P2G, OADJ2G, P3G, OADJ3G,
                                          Wrel3, brel3, Wroot3,
                                          Wrel4, brel4, Wroot4, out);
}

// Round 11
// 196.114 us; speedup vs baseline: 1.7493x; 1.0563x over previous
//
#include <hip/hip_runtime.h>
#include <math.h>

#define NB 64
#define TC 16
#define HC 32
#define NNODES 16384
#define NEDGES 131072
#define EPG 2048
#define EPSV 1e-15f

static inline int GRID(int n) { return (n + 255) / 256; }

template<int V> struct Log2 { static constexpr int v = 1 + Log2<V/2>::v; };
template<> struct Log2<1> { static constexpr int v = 0; };

__device__ inline float blk_sum256(float v, float* rbuf) {
    for (int o = 32; o > 0; o >>= 1) v += __shfl_xor(v, o);
    __syncthreads();
    if ((threadIdx.x & 63) == 0) rbuf[threadIdx.x >> 6] = v;
    __syncthreads();
    return rbuf[0] + rbuf[1] + rbuf[2] + rbuf[3];
}

// ---------------- front: edge-LDS adjacency GEMM + fused xm/p1 ----------------
// block = (b, dtile of 64 d-rows). Produces z (global, for pool1f), dinv, p1 rows.
__global__ __launch_bounds__(256) void k_front(
        const int* __restrict__ esrc, const int* __restrict__ edst,
        const float* __restrict__ ea, const float* __restrict__ pos,
        const float* __restrict__ W1, const float* __restrict__ b1,
        const float* __restrict__ Wp1, const float* __restrict__ bp1,
        float* __restrict__ z, float* __restrict__ dinv_g,
        float* __restrict__ p1, float* __restrict__ mc) {
    __shared__ float L[14784];
    float* dinvs = L;             // 256
    float* as_   = L + 256;       // 64x36
    float* bs    = L + 2560;      // 32x48
    float* s1    = L + 256;       // 64x64 (reuse as_+bs after GEMM)
    float* zs    = L + 4352;      // 64x48
    float* poss  = L + 7424;      // 64x48 -> a3 in place
    float* xm    = L + 10496;     // 64x32
    float* wp    = L + 12544;     // 32x64
    float* W1s   = L + 14592;     // 96
    float* b1s   = L + 14688;     // 32
    float* bp1s  = L + 14720;     // 64
    int b = blockIdx.x >> 2;
    int dtile = (blockIdx.x & 3) * 64;
    int tid = threadIdx.x;
    if (blockIdx.x == 0 && tid < 2) mc[tid] = 0.f;
    // stage weights (regions disjoint from GEMM scratch)
    for (int i = tid; i < 512; i += 256) ((float4*)wp)[i] = ((const float4*)Wp1)[i];
    if (tid < 96) W1s[tid] = W1[tid];
    if (tid < 32) b1s[tid] = b1[tid];
    if (tid < 64) bp1s[tid] = bp1[tid];
    // stage pos slice for this node tile (64 nodes x 48)
    for (int i = tid; i < 768; i += 256)
        ((float4*)poss)[i] = ((const float4*)(pos + ((size_t)b * 256 + dtile) * 48))[i];
    // edges -> registers
    int ebase = b * EPG;
    int svr[8], dvr[8];
    float evr[8];
#pragma unroll
    for (int j = 0; j < 8; ++j) {
        int e = ebase + tid + j * 256;
        svr[j] = esrc[e] & 255;
        dvr[j] = edst[e] & 255;
        evr[j] = ea[e];
    }
    dinvs[tid] = 1.0f;
    __syncthreads();
#pragma unroll
    for (int j = 0; j < 8; ++j) atomicAdd(&dinvs[dvr[j]], evr[j]);
    __syncthreads();
    float dg = dinvs[tid];
    float dvv = (dg > 0.f) ? rsqrtf(dg) : 0.f;
    __syncthreads();
    dinvs[tid] = dvv;
    __syncthreads();
    if (dtile == 0) dinv_g[b * 256 + tid] = dinvs[tid];
    int d = tid >> 2, q = tid & 3;
    float acc[12];
#pragma unroll
    for (int j = 0; j < 12; ++j) acc[j] = 0.f;
    const float* pbase = pos + (size_t)b * 256 * 48;
    for (int s0 = 0; s0 < 256; s0 += 32) {
        for (int i = tid; i < 576; i += 256)
            ((float4*)as_)[i] = make_float4(0.f, 0.f, 0.f, 0.f);
        __syncthreads();
#pragma unroll
        for (int j = 0; j < 8; ++j) {
            int dr = dvr[j] - dtile, sc = svr[j] - s0;
            if ((unsigned)dr < 64u && (unsigned)sc < 32u)
                atomicAdd(&as_[dr * 36 + sc], evr[j]);
        }
        for (int i = tid; i < 384; i += 256) {
            int r = i / 12, c = i % 12;
            float4 v = *(const float4*)(pbase + (size_t)(s0 + r) * 48 + c * 4);
            float dd = dinvs[s0 + r];
            v.x *= dd; v.y *= dd; v.z *= dd; v.w *= dd;
            *(float4*)(bs + r * 48 + c * 4) = v;
        }
        __syncthreads();
#pragma unroll 8
        for (int sp = 0; sp < 32; ++sp) {
            float a = as_[d * 36 + sp];
            const float* bp = &bs[sp * 48 + q * 12];
#pragma unroll
            for (int j = 0; j < 12; ++j) acc[j] += a * bp[j];
        }
        __syncthreads();
    }
    float dd = dinvs[dtile + d];
    float* zr = z + (size_t)(b * 256 + dtile + d) * 48 + q * 12;
#pragma unroll
    for (int j = 0; j < 12; ++j) {
        float v = acc[j] * dd;
        zr[j] = v;
        zs[d * 48 + q * 12 + j] = v;
    }
    __syncthreads();
    // a3 = zs + poss*dinv^2 (in place into poss)
    for (int i = tid; i < 3072; i += 256) {
        int nn = i / 48;
        float d2 = dinvs[dtile + nn];
        d2 *= d2;
        poss[i] = zs[i] + poss[i] * d2;
    }
    __syncthreads();
    // xm = mean_t relu(a3 @ W1 + b1)
    {
        int h = tid & 31, ng = tid >> 5;
        float w0 = W1s[h], w1 = W1s[32 + h], w2 = W1s[64 + h], bb = b1s[h];
#pragma unroll
        for (int j = 0; j < 8; ++j) {
            int nn = ng + 8 * j;
            float a = 0.f;
#pragma unroll
            for (int t = 0; t < 16; ++t) {
                const float* ap = &poss[nn * 48 + t * 3];
                float y = fmaxf(ap[0] * w0 + ap[1] * w1 + ap[2] * w2 + bb, 0.f);
                a += y;
            }
            xm[nn * 32 + h] = a * (1.0f / 16.0f);
        }
    }
    __syncthreads();
    // s1 = tanh(xm @ Wp1 + bp1)
    for (int i = tid; i < 4096; i += 256) {
        int n = i >> 6, k = i & 63;
        float a = bp1s[k];
#pragma unroll 8
        for (int h2 = 0; h2 < 32; ++h2) a += xm[n * 32 + h2] * wp[h2 * 64 + k];
        s1[i] = tanhf(a);
    }
    __syncthreads();
    // softmax rows of 64, wave per row
    {
        int wid = tid >> 6, lane = tid & 63;
        for (int r0 = wid; r0 < 64; r0 += 4) {
            float v = s1[r0 * 64 + lane];
            float m = v;
            for (int o = 32; o > 0; o >>= 1) m = fmaxf(m, __shfl_xor(m, o));
            float e = expf(v - m);
            float s = e;
            for (int o = 32; o > 0; o >>= 1) s += __shfl_xor(s, o);
            p1[((size_t)b * 256 + dtile + r0) * 64 + lane] = e / s;
        }
    }
}

// ---------------- pool1 fused: recompute y from z, pool in LDS ----------------
// block = (b, tp): t0 = tp*2, covers 2 t's. X1A[b,t,k,h] = sum_n p1[n,k]*y[n,t,h]
__global__ __launch_bounds__(256) void k_pool1f(
        const float* __restrict__ z, const float* __restrict__ pos,
        const float* __restrict__ dinv, const float* __restrict__ p1,
        const float* __restrict__ W1, const float* __restrict__ b1,
        float* __restrict__ X1A) {
    __shared__ __align__(16) float ps[4096];
    __shared__ __align__(16) float ys[4096];
    __shared__ float zc[384];
    __shared__ float pc[384];
    __shared__ float dv[64];
    __shared__ float W1s[96];
    __shared__ float b1s[32];
    int b = blockIdx.x >> 3;
    int t0 = (blockIdx.x & 7) * 2;
    int tid = threadIdx.x;
    if (tid < 96) W1s[tid] = W1[tid];
    if (tid < 32) b1s[tid] = b1[tid];
    __syncthreads();
    int hh = tid & 31;
    float w0 = W1s[hh], w1 = W1s[32 + hh], w2 = W1s[64 + hh], bb = b1s[hh];
    int th = tid >> 7, r = tid & 127;
    int k0 = (r >> 3) * 4, h0 = (r & 7) * 4;
    float acc[4][4];
#pragma unroll
    for (int a = 0; a < 4; ++a)
#pragma unroll
        for (int c = 0; c < 4; ++c) acc[a][c] = 0.f;
    for (int n0 = 0; n0 < 256; n0 += 64) {
        for (int i = tid; i < 1024; i += 256)
            ((float4*)ps)[i] = ((const float4*)(p1 + ((size_t)b * 256 + n0) * 64))[i];
        if (tid < 192) {
            int n = tid / 3, c = tid % 3;
            size_t off = ((size_t)(b * 256 + n0 + n)) * 48 + t0 * 3 + c * 2;
            *(float2*)&zc[n * 6 + c * 2] = *(const float2*)(z + off);
            *(float2*)&pc[n * 6 + c * 2] = *(const float2*)(pos + off);
        }
        if (tid < 64) dv[tid] = dinv[b * 256 + n0 + tid];
        __syncthreads();
        int g = tid >> 5;
#pragma unroll
        for (int j = 0; j < 16; ++j) {
            int pidx = g * 16 + j;
            int t = pidx >> 6, nn = pidx & 63;
            float d2 = dv[nn] * dv[nn];
            const float* zp = &zc[nn * 6 + t * 3];
            const float* pp = &pc[nn * 6 + t * 3];
            float a0 = zp[0] + pp[0] * d2;
            float a1 = zp[1] + pp[1] * d2;
            float a2 = zp[2] + pp[2] * d2;
            ys[t * 2048 + nn * 32 + hh] = fmaxf(a0 * w0 + a1 * w1 + a2 * w2 + bb, 0.f);
        }
        __syncthreads();
#pragma unroll 4
        for (int n = 0; n < 64; ++n) {
            float4 kv4 = *(const float4*)&ps[n * 64 + k0];
            float4 xv4 = *(const float4*)&ys[th * 2048 + n * 32 + h0];
            float kv[4] = {kv4.x, kv4.y, kv4.z, kv4.w};
            float xv[4] = {xv4.x, xv4.y, xv4.z, xv4.w};
#pragma unroll
            for (int a = 0; a < 4; ++a)
#pragma unroll
                for (int c = 0; c < 4; ++c) acc[a][c] += kv[a] * xv[c];
        }
        __syncthreads();
    }
    float* ob = X1A + (((size_t)(b * 16 + t0 + th) * 64 + k0) * 32 + h0);
#pragma unroll
    for (int a = 0; a < 4; ++a) {
        float4 v = {acc[a][0], acc[a][1], acc[a][2], acc[a][3]};
        *(float4*)(ob + (size_t)a * 32) = v;
    }
}

// ---------------- L1: adjacency-apply + dflat (edge-built counts in LDS) ----------------
__global__ void k_adjp2(const int* __restrict__ esrc, const int* __restrict__ edst,
                        const float* __restrict__ p, float* __restrict__ tmp,
                        float* __restrict__ dflat) {
    __shared__ __align__(16) float as_[32 * 260];
    __shared__ __align__(16) float ps[64 * 64];
    int b = blockIdx.x >> 3;
    int nt0 = (blockIdx.x & 7) * 32;
    int tid = threadIdx.x;
    for (int i = tid; i < 32 * 260 / 4; i += 256)
        ((float4*)as_)[i] = make_float4(0.f, 0.f, 0.f, 0.f);
    __syncthreads();
    int ebase = b * EPG;
#pragma unroll
    for (int j = 0; j < 8; ++j) {
        int e = ebase + tid + j * 256;
        int sv = esrc[e] & 255;
        int nr = sv - nt0;
        if ((unsigned)nr < 32u)
            atomicAdd(&as_[nr * 260 + (edst[e] & 255)], 1.0f);
    }
    __syncthreads();
    int n = tid >> 3, l0 = (tid & 7) * 8;
    float acc[8];
#pragma unroll
    for (int j = 0; j < 8; ++j) acc[j] = 0.f;
    float rs = 0.f;
    for (int m0 = 0; m0 < 256; m0 += 64) {
        for (int i = tid; i < 64 * 64 / 4; i += 256)
            ((float4*)ps)[i] = ((const float4*)(p + ((size_t)b * 256 + m0) * 64))[i];
        __syncthreads();
#pragma unroll 4
        for (int m = 0; m < 64; ++m) {
            float av = as_[n * 260 + m0 + m];
            rs += av;
            float4 p0 = *(const float4*)&ps[m * 64 + l0];
            float4 p1v = *(const float4*)&ps[m * 64 + l0 + 4];
            acc[0] += av * p0.x; acc[1] += av * p0.y; acc[2] += av * p0.z; acc[3] += av * p0.w;
            acc[4] += av * p1v.x; acc[5] += av * p1v.y; acc[6] += av * p1v.z; acc[7] += av * p1v.w;
        }
        __syncthreads();
    }
#pragma unroll
    for (int j = 0; j < 8; ++j)
        tmp[((size_t)b * 256 + nt0 + n) * 64 + l0 + j] = acc[j];
    if ((tid & 7) == 0) dflat[(size_t)b * 256 + nt0 + n] = rs;
}

template<int NC, int KC, int NSPLIT, int KT, int LT>
__global__ void k_ssgp(const float* __restrict__ p, const float* __restrict__ tmp,
                       const float* __restrict__ dflat, float* __restrict__ G,
                       float* __restrict__ Gden) {
    constexpr int NCH = NC / NSPLIT;
    constexpr int LC = 2 * KC;
    constexpr int KQ = KC / 4;
    __shared__ __align__(16) float ab[NCH * LC];
    __shared__ float rbuf[4];
    int b = blockIdx.x / NSPLIT;
    int split = blockIdx.x % NSPLIT;
    int n0 = split * NCH;
    int tid = threadIdx.x;
    const float* pb = p + ((size_t)b * NC + n0) * KC;
    const float* tb = tmp + ((size_t)b * NC + n0) * KC;
    const float* db = dflat + (size_t)b * NC + n0;
    for (int i = tid; i < NCH * KQ; i += 256) {
        int r = i / KQ, c = i % KQ;
        *(float4*)(ab + r * LC + c * 4) = ((const float4*)pb)[i];
        *(float4*)(ab + r * LC + KC + c * 4) = ((const float4*)tb)[i];
    }
    __syncthreads();
    float den = 0.f;
    for (int i = tid; i < NCH * KQ; i += 256) {
        int r = i / KQ, c = i % KQ;
        float4 v = *(const float4*)(ab + r * LC + c * 4);
        den += (v.x * v.x + v.y * v.y + v.z * v.z + v.w * v.w) * db[r];
    }
    int kt = tid >> 4, lt = tid & 15;
    int k0 = kt * KT, l0 = lt * LT;
    float acc[KT][LT];
#pragma unroll
    for (int r = 0; r < KT; ++r)
#pragma unroll
        for (int c = 0; c < LT; ++c) acc[r][c] = 0.f;
#pragma unroll 4
    for (int n = 0; n < NCH; ++n) {
        float kv[KT], lv[LT];
#pragma unroll
        for (int r = 0; r < KT; ++r) kv[r] = ab[n * LC + k0 + r];
#pragma unroll
        for (int c = 0; c < LT; ++c) lv[c] = ab[n * LC + l0 + c];
#pragma unroll
        for (int r = 0; r < KT; ++r)
#pragma unroll
            for (int c = 0; c < LT; ++c) acc[r][c] += kv[r] * lv[c];
    }
    float* Gb = G + ((size_t)split * NB + b) * (KC * LC);
#pragma unroll
    for (int r = 0; r < KT; ++r)
#pragma unroll
        for (int c = 0; c < LT; ++c)
            Gb[(k0 + r) * LC + l0 + c] = acc[r][c];
    float dt = blk_sum256(den, rbuf);
    if (tid == 0) Gden[(size_t)split * NB + b] = dt;
}

template<int KC, int NSPLIT, bool DFN>
__global__ void k_finish(const float* __restrict__ G, const float* __restrict__ Gden,
                         float* __restrict__ oadj_out, float* __restrict__ dfn_out,
                         float* __restrict__ mc_out, float* __restrict__ or_out) {
    constexpr int LK = Log2<KC>::v;
    constexpr int KCP = KC + 1;
    constexpr int LC = 2 * KC;
    __shared__ float sss[KC * KCP];
    __shared__ float oss[KC * KCP];
    __shared__ float dvv[KC];
    __shared__ float rbuf[4];
    int b = blockIdx.x, tid = threadIdx.x;
    for (int i = tid; i < KC * KC; i += 256) {
        int k = i >> LK, l = i & (KC - 1);
        float sv = 0.f, ov = 0.f;
#pragma unroll
        for (int s = 0; s < NSPLIT; ++s) {
            const float* Gb = G + ((size_t)s * NB + b) * KC * LC;
            sv += Gb[k * LC + l];
            ov += Gb[k * LC + KC + l];
        }
        sss[k * KCP + l] = sv;
        oss[k * KCP + l] = ov;
    }
    __syncthreads();
    float ssn2 = 0.f;
    for (int i = tid; i < KC * KC; i += 256) {
        int k = i >> LK, l = i & (KC - 1);
        float v = sss[k * KCP + l];
        ssn2 += v * v;
    }
    float num = 0.f;
    for (int k = tid; k < KC; k += 256) num += oss[k * KCP + k];
    float ssn2_t = blk_sum256(ssn2, rbuf);
    float num_t = blk_sum256(num, rbuf);
    float den_t = 0.f;
#pragma unroll
    for (int s = 0; s < NSPLIT; ++s) den_t += Gden[(size_t)s * NB + b];
    float inv = 1.0f / sqrtf(ssn2_t);
    float dk = rsqrtf((float)KC);
    float o2 = 0.f;
    for (int i = tid; i < KC * KC; i += 256) {
        int k = i >> LK, l = i & (KC - 1);
        float v = sss[k * KCP + l] * inv - ((k == l) ? dk : 0.f);
        o2 += v * v;
    }
    float o2_t = blk_sum256(o2, rbuf);
    if (tid == 0) {
        atomicAdd(mc_out, -(num_t / den_t) * (1.0f / NB));
        atomicAdd(or_out, sqrtf(o2_t) * (1.0f / NB));
    }
    if (tid < KC) {
        float rs = 0.f;
        for (int l = 0; l < KC; ++l) rs += oss[tid * KCP + l];
        rs -= oss[tid * KCP + tid];
        dvv[tid] = sqrtf(rs) + EPSV;
    }
    __syncthreads();
    for (int i = tid; i < KC * KC; i += 256) {
        int k = i >> LK, l = i & (KC - 1);
        float v = (k == l) ? 0.f : oss[k * KCP + l] / (dvv[k] * dvv[l]);
        oadj_out[(size_t)b * KC * KC + i] = v;
    }
    if (DFN && tid < KC) {
        float s = 0.f;
        for (int l = 0; l < KC; ++l)
            if (l != tid) s += oss[tid * KCP + l] / (dvv[tid] * dvv[l]);
        dfn_out[(size_t)b * KC + tid] = s;
    }
}

// ---------------- tail A: per-batch planning ----------------
__global__ __launch_bounds__(256) void k_tail_a(
        const float* __restrict__ X1A, const float* __restrict__ oadj1,
        const float* __restrict__ dflat2, const float* __restrict__ p1,
        const float* __restrict__ Wrel2, const float* __restrict__ brel2,
        const float* __restrict__ Wroot2,
        const float* __restrict__ Wp2, const float* __restrict__ bp2,
        const float* __restrict__ Wrel3, const float* __restrict__ brel3,
        const float* __restrict__ Wroot3,
        const float* __restrict__ Wp3, const float* __restrict__ bp3,
        float* __restrict__ P2G, float* __restrict__ OADJ2G,
        float* __restrict__ P3G, float* __restrict__ OADJ3G,
        float* __restrict__ outagg,
        float* __restrict__ mc_out, float* __restrict__ or_out) {
    __shared__ float lds[16160];
    float* P2     = lds;            // 64x36 (phase1c temp: Wrel2s/Wroot2s)
    float* XM2    = lds + 2304;     // 64x36
    float* OADJ2L = lds + 4608;     // 32x36
    float* P3L    = lds + 5760;     // 32x8
    float* OADJ3L = lds + 6016;     // 8x8
    float* DF3    = lds + 6080;     // 32
    float* DVV    = lds + 6112;     // 40
    float* RBUF   = lds + 6152;     // 8
    float* OADJ1s = lds + 6160;     // 64x68
    float* S      = lds + 10512;    // 5648 scratch

    int b = blockIdx.x, tid = threadIdx.x;

    // Phase 0: XM1A = mean_t X1A  (at S, stride 36)
    float* XM1A = S;
    for (int i = tid; i < 2048; i += 256) {
        float s = 0.f;
        for (int t = 0; t < 16; ++t) s += X1A[((size_t)b * 16 + t) * 2048 + i];
        XM1A[(i >> 5) * 36 + (i & 31)] = s * (1.0f / 16.0f);
    }
    for (int i = tid; i < 4096; i += 256)
        OADJ1s[(i >> 6) * 68 + (i & 63)] = oadj1[(size_t)b * 4096 + i];
    {
        float* WR = P2;          // temp
        float* WO = P2 + 1024;
        for (int i = tid; i < 1024; i += 256) { WR[i] = Wrel2[i]; WO[i] = Wroot2[i]; }
        __syncthreads();
        // C1 = OADJ1 @ XM1A
        float* C1 = S + 2304;
        int n = tid >> 2, j0 = (tid & 3) * 8;
        float a8[8];
#pragma unroll
        for (int j = 0; j < 8; ++j) a8[j] = 0.f;
        for (int m = 0; m < 64; ++m) {
            float av = OADJ1s[n * 68 + m];
            float4 x1 = *(const float4*)&XM1A[m * 36 + j0];
            float4 x2 = *(const float4*)&XM1A[m * 36 + j0 + 4];
            a8[0] += av * x1.x; a8[1] += av * x1.y; a8[2] += av * x1.z; a8[3] += av * x1.w;
            a8[4] += av * x2.x; a8[5] += av * x2.y; a8[6] += av * x2.z; a8[7] += av * x2.w;
        }
        __syncthreads();
#pragma unroll
        for (int j = 0; j < 8; ++j) C1[n * 36 + j0 + j] = a8[j];
        __syncthreads();
        // XM2 = C1@Wrel2 + brel2 + XM1A@Wroot2
        float o8[8];
#pragma unroll
        for (int j = 0; j < 8; ++j) o8[j] = brel2[j0 + j];
        for (int h = 0; h < 32; ++h) {
            float c1v = C1[n * 36 + h];
            float xav = XM1A[n * 36 + h];
            float4 wr1 = *(const float4*)&WR[h * 32 + j0];
            float4 wr2 = *(const float4*)&WR[h * 32 + j0 + 4];
            float4 wo1 = *(const float4*)&WO[h * 32 + j0];
            float4 wo2 = *(const float4*)&WO[h * 32 + j0 + 4];
            o8[0] += c1v * wr1.x + xav * wo1.x; o8[1] += c1v * wr1.y + xav * wo1.y;
            o8[2] += c1v * wr1.z + xav * wo1.z; o8[3] += c1v * wr1.w + xav * wo1.w;
            o8[4] += c1v * wr2.x + xav * wo2.x; o8[5] += c1v * wr2.y + xav * wo2.y;
            o8[6] += c1v * wr2.z + xav * wo2.z; o8[7] += c1v * wr2.w + xav * wo2.w;
        }
#pragma unroll
        for (int j = 0; j < 8; ++j) XM2[n * 36 + j0 + j] = o8[j];
        __syncthreads();
    }
    // Phase 2: P2 = softmax(tanh(XM2@Wp2+bp2))
    {
        float* S2 = S;             // 2048 (stride 32)
        float* WP2s = S + 2048;    // 1024
        for (int i = tid; i < 1024; i += 256) WP2s[i] = Wp2[i];
        __syncthreads();
        for (int i = tid; i < 2048; i += 256) {
            int n = i >> 5, k = i & 31;
            float a = bp2[k];
            for (int h = 0; h < 32; ++h) a += XM2[n * 36 + h] * WP2s[h * 32 + k];
            S2[i] = tanhf(a);
        }
        __syncthreads();
        int lane = tid & 31, rr = tid >> 5;
        for (int r0 = 0; r0 < 64; r0 += 8) {
            int row = r0 + rr;
            float v = S2[row * 32 + lane];
            float m = v;
            for (int o = 16; o > 0; o >>= 1) m = fmaxf(m, __shfl_xor(m, o, 32));
            float e = expf(v - m);
            float s = e;
            for (int o = 16; o > 0; o >>= 1) s += __shfl_xor(s, o, 32);
            P2[row * 36 + lane] = e / s;
        }
        __syncthreads();
        for (int i = tid; i < 2048; i += 256)
            P2G[(size_t)b * 2048 + i] = P2[(i >> 5) * 36 + (i & 31)];
    }
    // Phase 3: TMP2 = OADJ1 @ P2
    float* TMP2 = S;
    {
        int n = tid >> 2, l0 = (tid & 3) * 8;
        float a8[8];
#pragma unroll
        for (int j = 0; j < 8; ++j) a8[j] = 0.f;
        for (int m = 0; m < 64; ++m) {
            float av = OADJ1s[n * 68 + m];
            float4 pa = *(const float4*)&P2[m * 36 + l0];
            float4 pb = *(const float4*)&P2[m * 36 + l0 + 4];
            a8[0] += av * pa.x; a8[1] += av * pa.y; a8[2] += av * pa.z; a8[3] += av * pa.w;
            a8[4] += av * pb.x; a8[5] += av * pb.y; a8[6] += av * pb.z; a8[7] += av * pb.w;
        }
        __syncthreads();
#pragma unroll
        for (int j = 0; j < 8; ++j) TMP2[n * 36 + l0 + j] = a8[j];
        __syncthreads();
    }
    // Phase 4: GS/GO, losses L2, OADJ2L, DF3
    {
        float* GS = S + 2304;
        float* GO = S + 3360;
        int k = tid >> 3, l0 = (tid & 7) * 4;
        float as4[4] = {0, 0, 0, 0}, ao4[4] = {0, 0, 0, 0};
        for (int n = 0; n < 64; ++n) {
            float pv = P2[n * 36 + k];
            float4 lp = *(const float4*)&P2[n * 36 + l0];
            float4 lt = *(const float4*)&TMP2[n * 36 + l0];
            as4[0] += pv * lp.x; as4[1] += pv * lp.y; as4[2] += pv * lp.z; as4[3] += pv * lp.w;
            ao4[0] += pv * lt.x; ao4[1] += pv * lt.y; ao4[2] += pv * lt.z; ao4[3] += pv * lt.w;
        }
#pragma unroll
        for (int j = 0; j < 4; ++j) {
            GS[k * 33 + l0 + j] = as4[j];
            GO[k * 33 + l0 + j] = ao4[j];
        }
        __syncthreads();
        const float* df2 = dflat2 + (size_t)b * 64;
        float den = 0.f;
        for (int i = tid; i < 2048; i += 256) {
            float pv = P2[(i >> 5) * 36 + (i & 31)];
            den += pv * pv * df2[i >> 5];
        }
        float ssn2 = 0.f;
        for (int i = tid; i < 1024; i += 256) {
            float v = GS[(i >> 5) * 33 + (i & 31)];
            ssn2 += v * v;
        }
        float num = 0.f;
        for (int kk = tid; kk < 32; kk += 256) num += GO[kk * 33 + kk];
        float den_t = blk_sum256(den, RBUF);
        float ssn2_t = blk_sum256(ssn2, RBUF);
        float num_t = blk_sum256(num, RBUF);
        float inv = 1.0f / sqrtf(ssn2_t);
        float dk = rsqrtf(32.0f);
        float o2 = 0.f;
        for (int i = tid; i < 1024; i += 256) {
            int kk = i >> 5, ll = i & 31;
            float v = GS[kk * 33 + ll] * inv - ((kk == ll) ? dk : 0.f);
            o2 += v * v;
        }
        float o2_t = blk_sum256(o2, RBUF);
        if (tid == 0) {
            atomicAdd(mc_out, -(num_t / den_t) * (1.0f / NB));
            atomicAdd(or_out, sqrtf(o2_t) * (1.0f / NB));
        }
        if (tid < 32) {
            float rs = 0.f;
            for (int l = 0; l < 32; ++l) rs += GO[tid * 33 + l];
            rs -= GO[tid * 33 + tid];
            DVV[tid] = sqrtf(rs) + EPSV;
        }
        __syncthreads();
        for (int i = tid; i < 1024; i += 256) {
            int kk = i >> 5, ll = i & 31;
            float v = (kk == ll) ? 0.f : GO[kk * 33 + ll] / (DVV[kk] * DVV[ll]);
            OADJ2L[kk * 36 + ll] = v;
            OADJ2G[(size_t)b * 1024 + i] = v;
        }
        __syncthreads();
        if (tid < 32) {
            float s = 0.f;
            for (int l = 0; l < 32; ++l) s += OADJ2L[tid * 36 + l];
            DF3[tid] = s;
        }
        __syncthreads();
    }
    // Phase 5: XM2A = P2^T @ XM2
    float* XM2A = S;
    {
        int k = tid >> 3, h0 = (tid & 7) * 4;
        float a4[4] = {0, 0, 0, 0};
        for (int n = 0; n < 64; ++n) {
            float pv = P2[n * 36 + k];
            float4 xv = *(const float4*)&XM2[n * 36 + h0];
            a4[0] += pv * xv.x; a4[1] += pv * xv.y; a4[2] += pv * xv.z; a4[3] += pv * xv.w;
        }
        __syncthreads();
        *(float4*)&XM2A[k * 36 + h0] = make_float4(a4[0], a4[1], a4[2], a4[3]);
        __syncthreads();
    }
    // Phase 6: XM2B = graphconv3(XM2A)
    float* XM2B = S + 4352;
    {
        float* WREL3s = S + 1152;
        float* WROOT3s = S + 2176;
        float* C1 = S + 3200;
        for (int i = tid; i < 1024; i += 256) {
            WREL3s[i] = Wrel3[i];
            WROOT3s[i] = Wroot3[i];
        }
        __syncthreads();
        int n = tid >> 3, j0 = (tid & 7) * 4;
        float a4[4] = {0, 0, 0, 0};
        for (int m = 0; m < 32; ++m) {
            float av = OADJ2L[n * 36 + m];
            float4 xv = *(const float4*)&XM2A[m * 36 + j0];
            a4[0] += av * xv.x; a4[1] += av * xv.y; a4[2] += av * xv.z; a4[3] += av * xv.w;
        }
        __syncthreads();
        *(float4*)&C1[n * 36 + j0] = make_float4(a4[0], a4[1], a4[2], a4[3]);
        __syncthreads();
        float o4[4];
#pragma unroll
        for (int j = 0; j < 4; ++j) o4[j] = brel3[j0 + j];
        for (int h = 0; h < 32; ++h) {
            float c1v = C1[n * 36 + h];
            float xav = XM2A[n * 36 + h];
            float4 wr = *(const float4*)&WREL3s[h * 32 + j0];
            float4 wo = *(const float4*)&WROOT3s[h * 32 + j0];
            o4[0] += c1v * wr.x + xav * wo.x;
            o4[1] += c1v * wr.y + xav * wo.y;
            o4[2] += c1v * wr.z + xav * wo.z;
            o4[3] += c1v * wr.w + xav * wo.w;
        }
        __syncthreads();
        *(float4*)&XM2B[n * 36 + j0] = make_float4(o4[0], o4[1], o4[2], o4[3]);
        __syncthreads();
    }
    // Phase 7: P3 = softmax(tanh(XM2B@Wp3+bp3))
    {
        float* WP3s = S;
        for (int i = tid; i < 256; i += 256) WP3s[i] = Wp3[i];
        __syncthreads();
        int n = tid >> 3, kk = tid & 7;
        float a = bp3[kk];
        for (int h = 0; h < 32; ++h) a += XM2B[n * 36 + h] * WP3s[h * 8 + kk];
        float v = tanhf(a);
        float m = v;
        for (int o = 4; o > 0; o >>= 1) m = fmaxf(m, __shfl_xor(m, o, 8));
        float e = expf(v - m);
        float s = e;
        for (int o = 4; o > 0; o >>= 1) s += __shfl_xor(s, o, 8);
        P3L[n * 8 + kk] = e / s;
        __syncthreads();
        P3G[(size_t)b * 256 + tid] = P3L[tid];
        __syncthreads();
    }
    // Phase 8: L3 losses + OADJ3
    {
        float* TMP3 = S;
        float* GS3 = S + 256;
        float* GO3 = S + 336;
        int n = tid >> 3, l = tid & 7;
        float a = 0.f;
        for (int m = 0; m < 32; ++m) a += OADJ2L[n * 36 + m] * P3L[m * 8 + l];
        TMP3[n * 8 + l] = a;
        __syncthreads();
        if (tid < 64) {
            int k = tid >> 3, ll = tid & 7;
            float accs = 0.f, acco = 0.f;
            for (int nn = 0; nn < 32; ++nn) {
                float pv = P3L[nn * 8 + k];
                accs += pv * P3L[nn * 8 + ll];
                acco += pv * TMP3[nn * 8 + ll];
            }
            GS3[k * 9 + ll] = accs;
            GO3[k * 9 + ll] = acco;
        }
        __syncthreads();
        float den;
        {
            float pv = P3L[tid];
            den = pv * pv * DF3[tid >> 3];
        }
        float ssn2 = 0.f;
        if (tid < 64) {
            float v = GS3[(tid >> 3) * 9 + (tid & 7)];
            ssn2 = v * v;
        }
        float num = 0.f;
        if (tid < 8) num = GO3[tid * 9 + tid];
        float den_t = blk_sum256(den, RBUF);
        float ssn2_t = blk_sum256(ssn2, RBUF);
        float num_t = blk_sum256(num, RBUF);
        float inv = 1.0f / sqrtf(ssn2_t);
        float dk = rsqrtf(8.0f);
        float o2 = 0.f;
        if (tid < 64) {
            int k = tid >> 3, ll = tid & 7;
            float v = GS3[k * 9 + ll] * inv - ((k == ll) ? dk : 0.f);
            o2 = v * v;
        }
        float o2_t = blk_sum256(o2, RBUF);
        if (tid == 0) {
            atomicAdd(mc_out, -(num_t / den_t) * (1.0f / NB));
            atomicAdd(or_out, sqrtf(o2_t) * (1.0f / NB));
        }
        if (tid < 8) {
            float rs = 0.f;
            for (int ll = 0; ll < 8; ++ll) rs += GO3[tid * 9 + ll];
            rs -= GO3[tid * 9 + tid];
            DVV[32 + tid] = sqrtf(rs) + EPSV;
        }
        __syncthreads();
        if (tid < 64) {
            int k = tid >> 3, ll = tid & 7;
            float v = (k == ll) ? 0.f : GO3[k * 9 + ll] / (DVV[32 + k] * DVV[32 + ll]);
            OADJ3L[tid] = v;
            OADJ3G[(size_t)b * 64 + tid] = v;
        }
        __syncthreads();
    }
    // Phase 9: agg = p1 @ (P2 @ P3)
    {
        float* Q = S;
        for (int i = tid; i < 512; i += 256) {
            int k = i >> 3, m = i & 7;
            float a = 0.f;
            for (int l = 0; l < 32; ++l) a += P2[k * 36 + l] * P3L[l * 8 + m];
            Q[i] = a;
        }
        __syncthreads();
        const float* p1r = p1 + ((size_t)b * 256 + tid) * 64;
        float a8[8];
#pragma unroll
        for (int m = 0; m < 8; ++m) a8[m] = 0.f;
        for (int k = 0; k < 64; ++k) {
            float pv = p1r[k];
#pragma unroll
            for (int m = 0; m < 8; ++m) a8[m] += pv * Q[k * 8 + m];
        }
#pragma unroll
        for (int m = 0; m < 8; ++m)
            outagg[((size_t)b * 256 + tid) * 8 + m] = a8[m];
    }
}

// ---------------- tail B: per-(b,t) heavy path, gc2 fused, fully LDS-resident ----------------
__global__ __launch_bounds__(256) void k_tail_b(
        const float* __restrict__ X1A, const float* __restrict__ oadj1,
        const float* __restrict__ P2G, const float* __restrict__ OADJ2G,
        const float* __restrict__ P3G, const float* __restrict__ OADJ3G,
        const float* __restrict__ Wrel2, const float* __restrict__ brel2,
        const float* __restrict__ Wroot2,
        const float* __restrict__ Wrel3, const float* __restrict__ brel3,
        const float* __restrict__ Wroot3,
        const float* __restrict__ Wrel4, const float* __restrict__ brel4,
        const float* __restrict__ Wroot4,
        float* __restrict__ outx) {
    __shared__ float A[13408];
    float* X1AT = A;               // 64x36
    float* OADJ1s = A + 2304;      // 64x68
    float* WrelS = A + 6656;       // 1024
    float* WrootS = A + 7680;      // 1024
    float* C1a = A + 8704;         // 64x36
    float* X1B = A + 11008;        // 64x36
    int bt = blockIdx.x;
    int b = bt >> 4;
    int tid = threadIdx.x;
    // Phase 0: X1B = graphconv2(X1A_t)
    for (int i = tid; i < 2048; i += 256)
        X1AT[(i >> 5) * 36 + (i & 31)] = X1A[(size_t)bt * 2048 + i];
    for (int i = tid; i < 4096; i += 256)
        OADJ1s[(i >> 6) * 68 + (i & 63)] = oadj1[(size_t)b * 4096 + i];
    for (int i = tid; i < 1024; i += 256) {
        WrelS[i] = Wrel2[i];
        WrootS[i] = Wroot2[i];
    }
    __syncthreads();
    {
        int n = tid >> 2, j0 = (tid & 3) * 8;
        float a8[8];
#pragma unroll
        for (int j = 0; j < 8; ++j) a8[j] = 0.f;
        for (int m = 0; m < 64; ++m) {
            float av = OADJ1s[n * 68 + m];
            float4 x1 = *(const float4*)&X1AT[m * 36 + j0];
            float4 x2 = *(const float4*)&X1AT[m * 36 + j0 + 4];
            a8[0] += av * x1.x; a8[1] += av * x1.y; a8[2] += av * x1.z; a8[3] += av * x1.w;
            a8[4] += av * x2.x; a8[5] += av * x2.y; a8[6] += av * x2.z; a8[7] += av * x2.w;
        }
        __syncthreads();
#pragma unroll
        for (int j = 0; j < 8; ++j) C1a[n * 36 + j0 + j] = a8[j];
        __syncthreads();
        float o8[8];
#pragma unroll
        for (int j = 0; j < 8; ++j) o8[j] = brel2[j0 + j];
        for (int h = 0; h < 32; ++h) {
            float c1v = C1a[n * 36 + h];
            float xav = X1AT[n * 36 + h];
            float4 wr1 = *(const float4*)&WrelS[h * 32 + j0];
            float4 wr2 = *(const float4*)&WrelS[h * 32 + j0 + 4];
            float4 wo1 = *(const float4*)&WrootS[h * 32 + j0];
            float4 wo2 = *(const float4*)&WrootS[h * 32 + j0 + 4];
            o8[0] += c1v * wr1.x + xav * wo1.x; o8[1] += c1v * wr1.y + xav * wo1.y;
            o8[2] += c1v * wr1.z + xav * wo1.z; o8[3] += c1v * wr1.w + xav * wo1.w;
            o8[4] += c1v * wr2.x + xav * wo2.x; o8[5] += c1v * wr2.y + xav * wo2.y;
            o8[6] += c1v * wr2.z + xav * wo2.z; o8[7] += c1v * wr2.w + xav * wo2.w;
        }
        __syncthreads();
#pragma unroll
        for (int j = 0; j < 8; ++j) X1B[n * 36 + j0 + j] = o8[j];
        __syncthreads();
    }
    // Phase 1: X2A = P2^T @ X1B
    float* P2s = A;                // 64x36
    float* X2A = A + 2304;         // 32x36
    for (int i = tid; i < 2048; i += 256)
        P2s[(i >> 5) * 36 + (i & 31)] = P2G[(size_t)b * 2048 + i];
    __syncthreads();
    {
        int k = tid >> 3, h0 = (tid & 7) * 4;
        float a4[4] = {0, 0, 0, 0};
        for (int n = 0; n < 64; ++n) {
            float pv = P2s[n * 36 + k];
            float4 xv = *(const float4*)&X1B[n * 36 + h0];
            a4[0] += pv * xv.x; a4[1] += pv * xv.y; a4[2] += pv * xv.z; a4[3] += pv * xv.w;
        }
        __syncthreads();
        *(float4*)&X2A[k * 36 + h0] = make_float4(a4[0], a4[1], a4[2], a4[3]);
        __syncthreads();
    }
    // Phase 2: X2B = graphconv3(X2A)
    float* OADJ2s = A + 3456;      // 32x36
    float* Wrel3s = A + 4608;      // 1024
    float* Wroot3s = A + 5632;     // 1024
    float* C1b = A + 6656;         // 32x36
    float* X2B = A + 7808;         // 32x36
    for (int i = tid; i < 1024; i += 256) {
        OADJ2s[(i >> 5) * 36 + (i & 31)] = OADJ2G[(size_t)b * 1024 + i];
        Wrel3s[i] = Wrel3[i];
        Wroot3s[i] = Wroot3[i];
    }
    __syncthreads();
    {
        int n = tid >> 3, j0 = (tid & 7) * 4;
        float a4[4] = {0, 0, 0, 0};
        for (int m = 0; m < 32; ++m) {
            float av = OADJ2s[n * 36 + m];
            float4 xv = *(const float4*)&X2A[m * 36 + j0];
            a4[0] += av * xv.x; a4[1] += av * xv.y; a4[2] += av * xv.z; a4[3] += av * xv.w;
        }
        __syncthreads();
        *(float4*)&C1b[n * 36 + j0] = make_float4(a4[0], a4[1], a4[2], a4[3]);
        __syncthreads();
        float o4[4];
#pragma unroll
        for (int j = 0; j < 4; ++j) o4[j] = brel3[j0 + j];
        for (int h = 0; h < 32; ++h) {
            float c1v = C1b[n * 36 + h];
            float xav = X2A[n * 36 + h];
            float4 wr = *(const float4*)&Wrel3s[h * 32 + j0];
            float4 wo = *(const float4*)&Wroot3s[h * 32 + j0];
            o4[0] += c1v * wr.x + xav * wo.x;
            o4[1] += c1v * wr.y + xav * wo.y;
            o4[2] += c1v * wr.z + xav * wo.z;
            o4[3] += c1v * wr.w + xav * wo.w;
        }
        __syncthreads();
        *(float4*)&X2B[n * 36 + j0] = make_float4(o4[0], o4[1], o4[2], o4[3]);
        __syncthreads();
    }
    // Phase 3: X3A = P3^T @ X2B
    float* P3s = A;                // 256
    float* X3A = A + 8960;         // 8x36
    P3s[tid] = P3G[(size_t)b * 256 + tid];
    __syncthreads();
    {
        int k = tid >> 5, h = tid & 31;
        float a = 0.f;
        for (int n = 0; n < 32; ++n) a += P3s[n * 8 + k] * X2B[n * 36 + h];
        __syncthreads();
        X3A[k * 36 + h] = a;
        __syncthreads();
    }
    // Phase 4: out_t = graphconv4(X3A)
    {
        float* OADJ3s = A + 256;   // 64
        float* C3 = A + 320;       // 8x36
        float* Wrel4s = A + 9248;  // 2048
        float* Wroot4s = A + 11296;// 2048
        if (tid < 64) OADJ3s[tid] = OADJ3G[(size_t)b * 64 + tid];
        for (int i = tid; i < 2048; i += 256) {
            Wrel4s[i] = Wrel4[i];
            Wroot4s[i] = Wroot4[i];
        }
        __syncthreads();
        int n = tid >> 5, h = tid & 31;
        float a = 0.f;
#pragma unroll
        for (int m = 0; m < 8; ++m) a += OADJ3s[n * 8 + m] * X3A[m * 36 + h];
        C3[n * 36 + h] = a;
        __syncthreads();
        int o0 = (tid & 31) * 2;
        float a0 = brel4[o0], a1 = brel4[o0 + 1];
        for (int hh = 0; hh < 32; ++hh) {
            float c3v = C3[n * 36 + hh];
            float x3v = X3A[n * 36 + hh];
            a0 += c3v * Wrel4s[hh * 64 + o0] + x3v * Wroot4s[hh * 64 + o0];
            a1 += c3v * Wrel4s[hh * 64 + o0 + 1] + x3v * Wroot4s[hh * 64 + o0 + 1];
        }
        float* ob = outx + ((size_t)bt * 8 + n) * 64 + o0;
        ob[0] = a0;
        ob[1] = a1;
    }
}

// ---------------- host launch ----------------

extern "C" void kernel_launch(void* const* d_in, const int* in_sizes, int n_in,
                              void* d_out, int out_size, void* d_ws, size_t ws_size,
                              hipStream_t stream) {
    const float* pos    = (const float*)d_in[0];
    const float* ea     = (const float*)d_in[1];
    const int*   esrc   = (const int*)d_in[2];
    const int*   edst   = (const int*)d_in[3];
    const float* W1     = (const float*)d_in[4];
    const float* b1     = (const float*)d_in[5];
    const float* Wp1    = (const float*)d_in[6];
    const float* bp1    = (const float*)d_in[7];
    const float* Wrel2  = (const float*)d_in[8];
    const float* brel2  = (const float*)d_in[9];
    const float* Wroot2 = (const float*)d_in[10];
    const float* Wp2    = (const float*)d_in[11];
    const float* bp2    = (const float*)d_in[12];
    const float* Wrel3  = (const float*)d_in[13];
    const float* brel3  = (const float*)d_in[14];
    const float* Wroot3 = (const float*)d_in[15];
    const float* Wp3    = (const float*)d_in[16];
    const float* bp3    = (const float*)d_in[17];
    const float* Wrel4  = (const float*)d_in[18];
    const float* brel4  = (const float*)d_in[19];
    const float* Wroot4 = (const float*)d_in[20];
    float* out = (float*)d_out;

    char* w = (char*)d_ws;
    float* TMP    = (float*)(w);                        // 4 MB
    float* GBUF1  = (float*)(w + 4194304);              // 8 MB
    float* X1A    = (float*)(w + 12582912);             // 8 MB
    float* Z      = (float*)(w + 20971520);             // 3 MB
    float* P1     = (float*)(w + 25165824);             // 4 MB
    float* DINV   = (float*)(w + 29360128);             // 64 KB
    float* DFLAT  = (float*)(w + 29425664);             // 64 KB
    float* DFLAT2 = (float*)(w + 29491200);             // 16 KB
    float* GDEN1  = (float*)(w + 29507584);             // 1 KB
    float* OADJ1  = (float*)(w + 29622272);             // 1 MB
    float* P2G    = (float*)(w + 30670848);             // 512 KB
    float* OADJ2G = (float*)(w + 31195136);             // 256 KB
    float* P3G    = (float*)(w + 31457280);             // 64 KB
    float* OADJ3G = (float*)(w + 31522816);             // 16 KB
    float* MC     = out + 524288;                       // [mincut, ortho]

    // 1. front: z, dinv, p1 (MC zeroed inside)
    k_front<<<NB * 4, 256, 0, stream>>>(esrc, edst, ea, pos, W1, b1, Wp1, bp1,
                                        Z, DINV, P1, MC);
    // 2. pool L1 (y recomputed in LDS, never materialized)
    k_pool1f<<<NB * 8, 256, 0, stream>>>(Z, pos, DINV, P1, W1, b1, X1A);
    // 3-5. L1 mincut chain
    k_adjp2<<<NB * 8, 256, 0, stream>>>(esrc, edst, P1, TMP, DFLAT);
    k_ssgp<256, 64, 4, 4, 8><<<NB * 4, 256, 0, stream>>>(P1, TMP, DFLAT, GBUF1, GDEN1);
    k_finish<64, 4, true><<<NB, 256, 0, stream>>>(GBUF1, GDEN1, OADJ1, DFLAT2, MC, MC + 1);
    // 6. per-batch planning (gc2 on mean via linearity)
    k_tail_a<<<NB, 256, 0, stream>>>(X1A, OADJ1, DFLAT2, P1,
                                     Wrel2, brel2, Wroot2, Wp2, bp2,
                                     Wrel3, brel3, Wroot3, Wp3, bp3,
                                     P2G, OADJ2G, P3G, OADJ3G,
                                     out + 524290, MC, MC + 1);
    // 7. per-(b,t) heavy path with gc2 fused
    k_tail_b<<<NB * TC, 256, 0, stream>>>(X1A, OADJ1, P2G, OADJ2G, P3G, OADJ3G,
                                          Wrel2, brel2, Wroot2,
                                          Wrel3, brel3, Wroot3,
                                          Wrel4, brel4, Wroot4, out);
}

// Round 12
// 194.294 us; speedup vs baseline: 1.7656x; 1.0094x over previous
//
#include <hip/hip_runtime.h>
#include <math.h>

#define NB 64
#define TC 16
#define HC 32
#define NNODES 16384
#define NEDGES 131072
#define EPG 2048
#define EPSV 1e-15f

static inline int GRID(int n) { return (n + 255) / 256; }

template<int V> struct Log2 { static constexpr int v = 1 + Log2<V/2>::v; };
template<> struct Log2<1> { static constexpr int v = 0; };

__device__ inline float blk_sum256(float v, float* rbuf) {
    for (int o = 32; o > 0; o >>= 1) v += __shfl_xor(v, o);
    __syncthreads();
    if ((threadIdx.x & 63) == 0) rbuf[threadIdx.x >> 6] = v;
    __syncthreads();
    return rbuf[0] + rbuf[1] + rbuf[2] + rbuf[3];
}

// ---------------- front: edge-LDS adjacency GEMM + fused xm/p1 ----------------
// block = (b, dtile of 32 d-rows), grid NB*8 (2 blocks/CU). ~37 KB LDS.
__global__ __launch_bounds__(256) void k_front(
        const int* __restrict__ esrc, const int* __restrict__ edst,
        const float* __restrict__ ea, const float* __restrict__ pos,
        const float* __restrict__ W1, const float* __restrict__ b1,
        const float* __restrict__ Wp1, const float* __restrict__ bp1,
        float* __restrict__ z, float* __restrict__ dinv_g,
        float* __restrict__ p1, float* __restrict__ mc) {
    __shared__ float L[9280];
    float* dinvs = L;             // 256
    float* as_   = L + 256;       // 32x36 = 1152
    float* bs    = L + 1408;      // 32x48 = 1536
    float* s1    = L + 256;       // 32x64 = 2048 (reuse as_+bs after GEMM)
    float* zs    = L + 2944;      // 32x48
    float* poss  = L + 4480;      // 32x48 -> a3 in place
    float* xm    = L + 6016;      // 32x32
    float* wp    = L + 7040;      // 32x64
    float* W1s   = L + 9088;      // 96
    float* b1s   = L + 9184;      // 32
    float* bp1s  = L + 9216;      // 64
    int b = blockIdx.x >> 3;
    int dtile = (blockIdx.x & 7) * 32;
    int tid = threadIdx.x;
    if (blockIdx.x == 0 && tid < 2) mc[tid] = 0.f;
    // stage weights (disjoint from GEMM scratch)
    for (int i = tid; i < 512; i += 256) ((float4*)wp)[i] = ((const float4*)Wp1)[i];
    if (tid < 96) W1s[tid] = W1[tid];
    if (tid < 32) b1s[tid] = b1[tid];
    if (tid < 64) bp1s[tid] = bp1[tid];
    // stage pos slice for this 32-node tile
    for (int i = tid; i < 384; i += 256)
        ((float4*)poss)[i] = ((const float4*)(pos + ((size_t)b * 256 + dtile) * 48))[i];
    // edges -> registers
    int ebase = b * EPG;
    int svr[8], dvr[8];
    float evr[8];
#pragma unroll
    for (int j = 0; j < 8; ++j) {
        int e = ebase + tid + j * 256;
        svr[j] = esrc[e] & 255;
        dvr[j] = edst[e] & 255;
        evr[j] = ea[e];
    }
    dinvs[tid] = 1.0f;
    __syncthreads();
#pragma unroll
    for (int j = 0; j < 8; ++j) atomicAdd(&dinvs[dvr[j]], evr[j]);
    __syncthreads();
    float dg = dinvs[tid];
    float dvv = (dg > 0.f) ? rsqrtf(dg) : 0.f;
    __syncthreads();
    dinvs[tid] = dvv;
    __syncthreads();
    if (dtile == 0) dinv_g[b * 256 + tid] = dinvs[tid];
    int d = tid >> 3, q = tid & 7;        // d in [0,32), q*6 floats of 48
    float acc[6];
#pragma unroll
    for (int j = 0; j < 6; ++j) acc[j] = 0.f;
    const float* pbase = pos + (size_t)b * 256 * 48;
    for (int s0 = 0; s0 < 256; s0 += 32) {
        for (int i = tid; i < 288; i += 256)
            ((float4*)as_)[i] = make_float4(0.f, 0.f, 0.f, 0.f);
        __syncthreads();
#pragma unroll
        for (int j = 0; j < 8; ++j) {
            int dr = dvr[j] - dtile, sc = svr[j] - s0;
            if ((unsigned)dr < 32u && (unsigned)sc < 32u)
                atomicAdd(&as_[dr * 36 + sc], evr[j]);
        }
        for (int i = tid; i < 384; i += 256) {
            int r = i / 12, c = i % 12;
            float4 v = *(const float4*)(pbase + (size_t)(s0 + r) * 48 + c * 4);
            float dd = dinvs[s0 + r];
            v.x *= dd; v.y *= dd; v.z *= dd; v.w *= dd;
            *(float4*)(bs + r * 48 + c * 4) = v;
        }
        __syncthreads();
#pragma unroll 8
        for (int sp = 0; sp < 32; ++sp) {
            float a = as_[d * 36 + sp];
            const float* bp = &bs[sp * 48 + q * 6];
#pragma unroll
            for (int j = 0; j < 6; ++j) acc[j] += a * bp[j];
        }
        __syncthreads();
    }
    float dd = dinvs[dtile + d];
    float* zr = z + (size_t)(b * 256 + dtile + d) * 48 + q * 6;
#pragma unroll
    for (int j = 0; j < 6; ++j) {
        float v = acc[j] * dd;
        zr[j] = v;
        zs[d * 48 + q * 6 + j] = v;
    }
    __syncthreads();
    // a3 = zs + poss*dinv^2 (in place into poss)
    for (int i = tid; i < 1536; i += 256) {
        int nn = i / 48;
        float d2 = dinvs[dtile + nn];
        d2 *= d2;
        poss[i] = zs[i] + poss[i] * d2;
    }
    __syncthreads();
    // xm = mean_t relu(a3 @ W1 + b1)  (32 nodes x 32 h; 4 nodes/thread)
    {
        int h = tid & 31, ng = tid >> 5;
        float w0 = W1s[h], w1 = W1s[32 + h], w2 = W1s[64 + h], bb = b1s[h];
#pragma unroll
        for (int j = 0; j < 4; ++j) {
            int nn = ng + 8 * j;
            float a = 0.f;
#pragma unroll
            for (int t = 0; t < 16; ++t) {
                const float* ap = &poss[nn * 48 + t * 3];
                float y = fmaxf(ap[0] * w0 + ap[1] * w1 + ap[2] * w2 + bb, 0.f);
                a += y;
            }
            xm[nn * 32 + h] = a * (1.0f / 16.0f);
        }
    }
    __syncthreads();
    // s1 = tanh(xm @ Wp1 + bp1)  (32x64)
    for (int i = tid; i < 2048; i += 256) {
        int n = i >> 6, k = i & 63;
        float a = bp1s[k];
#pragma unroll 8
        for (int h2 = 0; h2 < 32; ++h2) a += xm[n * 32 + h2] * wp[h2 * 64 + k];
        s1[i] = tanhf(a);
    }
    __syncthreads();
    // softmax rows of 64, wave per row (32 rows, 4 waves)
    {
        int wid = tid >> 6, lane = tid & 63;
        for (int r0 = wid; r0 < 32; r0 += 4) {
            float v = s1[r0 * 64 + lane];
            float m = v;
            for (int o = 32; o > 0; o >>= 1) m = fmaxf(m, __shfl_xor(m, o));
            float e = expf(v - m);
            float s = e;
            for (int o = 32; o > 0; o >>= 1) s += __shfl_xor(s, o);
            p1[((size_t)b * 256 + dtile + r0) * 64 + lane] = e / s;
        }
    }
}

// ---------------- pool1 fused: recompute y from z, pool in LDS ----------------
__global__ __launch_bounds__(256) void k_pool1f(
        const float* __restrict__ z, const float* __restrict__ pos,
        const float* __restrict__ dinv, const float* __restrict__ p1,
        const float* __restrict__ W1, const float* __restrict__ b1,
        float* __restrict__ X1A) {
    __shared__ __align__(16) float ps[4096];
    __shared__ __align__(16) float ys[4096];
    __shared__ float zc[384];
    __shared__ float pc[384];
    __shared__ float dv[64];
    __shared__ float W1s[96];
    __shared__ float b1s[32];
    int b = blockIdx.x >> 3;
    int t0 = (blockIdx.x & 7) * 2;
    int tid = threadIdx.x;
    if (tid < 96) W1s[tid] = W1[tid];
    if (tid < 32) b1s[tid] = b1[tid];
    __syncthreads();
    int hh = tid & 31;
    float w0 = W1s[hh], w1 = W1s[32 + hh], w2 = W1s[64 + hh], bb = b1s[hh];
    int th = tid >> 7, r = tid & 127;
    int k0 = (r >> 3) * 4, h0 = (r & 7) * 4;
    float acc[4][4];
#pragma unroll
    for (int a = 0; a < 4; ++a)
#pragma unroll
        for (int c = 0; c < 4; ++c) acc[a][c] = 0.f;
    for (int n0 = 0; n0 < 256; n0 += 64) {
        for (int i = tid; i < 1024; i += 256)
            ((float4*)ps)[i] = ((const float4*)(p1 + ((size_t)b * 256 + n0) * 64))[i];
        if (tid < 192) {
            int n = tid / 3, c = tid % 3;
            size_t off = ((size_t)(b * 256 + n0 + n)) * 48 + t0 * 3 + c * 2;
            *(float2*)&zc[n * 6 + c * 2] = *(const float2*)(z + off);
            *(float2*)&pc[n * 6 + c * 2] = *(const float2*)(pos + off);
        }
        if (tid < 64) dv[tid] = dinv[b * 256 + n0 + tid];
        __syncthreads();
        int g = tid >> 5;
#pragma unroll
        for (int j = 0; j < 16; ++j) {
            int pidx = g * 16 + j;
            int t = pidx >> 6, nn = pidx & 63;
            float d2 = dv[nn] * dv[nn];
            const float* zp = &zc[nn * 6 + t * 3];
            const float* pp = &pc[nn * 6 + t * 3];
            float a0 = zp[0] + pp[0] * d2;
            float a1 = zp[1] + pp[1] * d2;
            float a2 = zp[2] + pp[2] * d2;
            ys[t * 2048 + nn * 32 + hh] = fmaxf(a0 * w0 + a1 * w1 + a2 * w2 + bb, 0.f);
        }
        __syncthreads();
#pragma unroll 4
        for (int n = 0; n < 64; ++n) {
            float4 kv4 = *(const float4*)&ps[n * 64 + k0];
            float4 xv4 = *(const float4*)&ys[th * 2048 + n * 32 + h0];
            float kv[4] = {kv4.x, kv4.y, kv4.z, kv4.w};
            float xv[4] = {xv4.x, xv4.y, xv4.z, xv4.w};
#pragma unroll
            for (int a = 0; a < 4; ++a)
#pragma unroll
                for (int c = 0; c < 4; ++c) acc[a][c] += kv[a] * xv[c];
        }
        __syncthreads();
    }
    float* ob = X1A + (((size_t)(b * 16 + t0 + th) * 64 + k0) * 32 + h0);
#pragma unroll
    for (int a = 0; a < 4; ++a) {
        float4 v = {acc[a][0], acc[a][1], acc[a][2], acc[a][3]};
        *(float4*)(ob + (size_t)a * 32) = v;
    }
}

// ---------------- L1: adjacency-apply + dflat ----------------
__global__ void k_adjp2(const int* __restrict__ esrc, const int* __restrict__ edst,
                        const float* __restrict__ p, float* __restrict__ tmp,
                        float* __restrict__ dflat) {
    __shared__ __align__(16) float as_[32 * 260];
    __shared__ __align__(16) float ps[64 * 64];
    int b = blockIdx.x >> 3;
    int nt0 = (blockIdx.x & 7) * 32;
    int tid = threadIdx.x;
    for (int i = tid; i < 32 * 260 / 4; i += 256)
        ((float4*)as_)[i] = make_float4(0.f, 0.f, 0.f, 0.f);
    __syncthreads();
    int ebase = b * EPG;
#pragma unroll
    for (int j = 0; j < 8; ++j) {
        int e = ebase + tid + j * 256;
        int sv = esrc[e] & 255;
        int nr = sv - nt0;
        if ((unsigned)nr < 32u)
            atomicAdd(&as_[nr * 260 + (edst[e] & 255)], 1.0f);
    }
    __syncthreads();
    int n = tid >> 3, l0 = (tid & 7) * 8;
    float acc[8];
#pragma unroll
    for (int j = 0; j < 8; ++j) acc[j] = 0.f;
    float rs = 0.f;
    for (int m0 = 0; m0 < 256; m0 += 64) {
        for (int i = tid; i < 64 * 64 / 4; i += 256)
            ((float4*)ps)[i] = ((const float4*)(p + ((size_t)b * 256 + m0) * 64))[i];
        __syncthreads();
#pragma unroll 4
        for (int m = 0; m < 64; ++m) {
            float av = as_[n * 260 + m0 + m];
            rs += av;
            float4 p0 = *(const float4*)&ps[m * 64 + l0];
            float4 p1v = *(const float4*)&ps[m * 64 + l0 + 4];
            acc[0] += av * p0.x; acc[1] += av * p0.y; acc[2] += av * p0.z; acc[3] += av * p0.w;
            acc[4] += av * p1v.x; acc[5] += av * p1v.y; acc[6] += av * p1v.z; acc[7] += av * p1v.w;
        }
        __syncthreads();
    }
#pragma unroll
    for (int j = 0; j < 8; ++j)
        tmp[((size_t)b * 256 + nt0 + n) * 64 + l0 + j] = acc[j];
    if ((tid & 7) == 0) dflat[(size_t)b * 256 + nt0 + n] = rs;
}

template<int NC, int KC, int NSPLIT, int KT, int LT>
__global__ void k_ssgp(const float* __restrict__ p, const float* __restrict__ tmp,
                       const float* __restrict__ dflat, float* __restrict__ G,
                       float* __restrict__ Gden) {
    constexpr int NCH = NC / NSPLIT;
    constexpr int LC = 2 * KC;
    constexpr int KQ = KC / 4;
    __shared__ __align__(16) float ab[NCH * LC];
    __shared__ float rbuf[4];
    int b = blockIdx.x / NSPLIT;
    int split = blockIdx.x % NSPLIT;
    int n0 = split * NCH;
    int tid = threadIdx.x;
    const float* pb = p + ((size_t)b * NC + n0) * KC;
    const float* tb = tmp + ((size_t)b * NC + n0) * KC;
    const float* db = dflat + (size_t)b * NC + n0;
    for (int i = tid; i < NCH * KQ; i += 256) {
        int r = i / KQ, c = i % KQ;
        *(float4*)(ab + r * LC + c * 4) = ((const float4*)pb)[i];
        *(float4*)(ab + r * LC + KC + c * 4) = ((const float4*)tb)[i];
    }
    __syncthreads();
    float den = 0.f;
    for (int i = tid; i < NCH * KQ; i += 256) {
        int r = i / KQ, c = i % KQ;
        float4 v = *(const float4*)(ab + r * LC + c * 4);
        den += (v.x * v.x + v.y * v.y + v.z * v.z + v.w * v.w) * db[r];
    }
    int kt = tid >> 4, lt = tid & 15;
    int k0 = kt * KT, l0 = lt * LT;
    float acc[KT][LT];
#pragma unroll
    for (int r = 0; r < KT; ++r)
#pragma unroll
        for (int c = 0; c < LT; ++c) acc[r][c] = 0.f;
#pragma unroll 4
    for (int n = 0; n < NCH; ++n) {
        float kv[KT], lv[LT];
#pragma unroll
        for (int r = 0; r < KT; ++r) kv[r] = ab[n * LC + k0 + r];
#pragma unroll
        for (int c = 0; c < LT; ++c) lv[c] = ab[n * LC + l0 + c];
#pragma unroll
        for (int r = 0; r < KT; ++r)
#pragma unroll
            for (int c = 0; c < LT; ++c) acc[r][c] += kv[r] * lv[c];
    }
    float* Gb = G + ((size_t)split * NB + b) * (KC * LC);
#pragma unroll
    for (int r = 0; r < KT; ++r)
#pragma unroll
        for (int c = 0; c < LT; ++c)
            Gb[(k0 + r) * LC + l0 + c] = acc[r][c];
    float dt = blk_sum256(den, rbuf);
    if (tid == 0) Gden[(size_t)split * NB + b] = dt;
}

template<int KC, int NSPLIT, bool DFN>
__global__ void k_finish(const float* __restrict__ G, const float* __restrict__ Gden,
                         float* __restrict__ oadj_out, float* __restrict__ dfn_out,
                         float* __restrict__ mc_out, float* __restrict__ or_out) {
    constexpr int LK = Log2<KC>::v;
    constexpr int KCP = KC + 1;
    constexpr int LC = 2 * KC;
    __shared__ float sss[KC * KCP];
    __shared__ float oss[KC * KCP];
    __shared__ float dvv[KC];
    __shared__ float rbuf[4];
    int b = blockIdx.x, tid = threadIdx.x;
    for (int i = tid; i < KC * KC; i += 256) {
        int k = i >> LK, l = i & (KC - 1);
        float sv = 0.f, ov = 0.f;
#pragma unroll
        for (int s = 0; s < NSPLIT; ++s) {
            const float* Gb = G + ((size_t)s * NB + b) * KC * LC;
            sv += Gb[k * LC + l];
            ov += Gb[k * LC + KC + l];
        }
        sss[k * KCP + l] = sv;
        oss[k * KCP + l] = ov;
    }
    __syncthreads();
    float ssn2 = 0.f;
    for (int i = tid; i < KC * KC; i += 256) {
        int k = i >> LK, l = i & (KC - 1);
        float v = sss[k * KCP + l];
        ssn2 += v * v;
    }
    float num = 0.f;
    for (int k = tid; k < KC; k += 256) num += oss[k * KCP + k];
    float ssn2_t = blk_sum256(ssn2, rbuf);
    float num_t = blk_sum256(num, rbuf);
    float den_t = 0.f;
#pragma unroll
    for (int s = 0; s < NSPLIT; ++s) den_t += Gden[(size_t)s * NB + b];
    float inv = 1.0f / sqrtf(ssn2_t);
    float dk = rsqrtf((float)KC);
    float o2 = 0.f;
    for (int i = tid; i < KC * KC; i += 256) {
        int k = i >> LK, l = i & (KC - 1);
        float v = sss[k * KCP + l] * inv - ((k == l) ? dk : 0.f);
        o2 += v * v;
    }
    float o2_t = blk_sum256(o2, rbuf);
    if (tid == 0) {
        atomicAdd(mc_out, -(num_t / den_t) * (1.0f / NB));
        atomicAdd(or_out, sqrtf(o2_t) * (1.0f / NB));
    }
    if (tid < KC) {
        float rs = 0.f;
        for (int l = 0; l < KC; ++l) rs += oss[tid * KCP + l];
        rs -= oss[tid * KCP + tid];
        dvv[tid] = sqrtf(rs) + EPSV;
    }
    __syncthreads();
    for (int i = tid; i < KC * KC; i += 256) {
        int k = i >> LK, l = i & (KC - 1);
        float v = (k == l) ? 0.f : oss[k * KCP + l] / (dvv[k] * dvv[l]);
        oadj_out[(size_t)b * KC * KC + i] = v;
    }
    if (DFN && tid < KC) {
        float s = 0.f;
        for (int l = 0; l < KC; ++l)
            if (l != tid) s += oss[tid * KCP + l] / (dvv[tid] * dvv[l]);
        dfn_out[(size_t)b * KC + tid] = s;
    }
}

// ---------------- tail A: per-batch planning ----------------
__global__ __launch_bounds__(256) void k_tail_a(
        const float* __restrict__ X1A, const float* __restrict__ oadj1,
        const float* __restrict__ dflat2, const float* __restrict__ p1,
        const float* __restrict__ Wrel2, const float* __restrict__ brel2,
        const float* __restrict__ Wroot2,
        const float* __restrict__ Wp2, const float* __restrict__ bp2,
        const float* __restrict__ Wrel3, const float* __restrict__ brel3,
        const float* __restrict__ Wroot3,
        const float* __restrict__ Wp3, const float* __restrict__ bp3,
        float* __restrict__ P2G, float* __restrict__ OADJ2G,
        float* __restrict__ P3G, float* __restrict__ OADJ3G,
        float* __restrict__ outagg,
        float* __restrict__ mc_out, float* __restrict__ or_out) {
    __shared__ float lds[16160];
    float* P2     = lds;            // 64x36 (phase1c temp: Wrel2s/Wroot2s)
    float* XM2    = lds + 2304;     // 64x36
    float* OADJ2L = lds + 4608;     // 32x36
    float* P3L    = lds + 5760;     // 32x8
    float* OADJ3L = lds + 6016;     // 8x8
    float* DF3    = lds + 6080;     // 32
    float* DVV    = lds + 6112;     // 40
    float* RBUF   = lds + 6152;     // 8
    float* OADJ1s = lds + 6160;     // 64x68
    float* S      = lds + 10512;    // 5648 scratch

    int b = blockIdx.x, tid = threadIdx.x;

    // Phase 0: XM1A = mean_t X1A  (at S, stride 36)
    float* XM1A = S;
    for (int i = tid; i < 2048; i += 256) {
        float s = 0.f;
        for (int t = 0; t < 16; ++t) s += X1A[((size_t)b * 16 + t) * 2048 + i];
        XM1A[(i >> 5) * 36 + (i & 31)] = s * (1.0f / 16.0f);
    }
    for (int i = tid; i < 4096; i += 256)
        OADJ1s[(i >> 6) * 68 + (i & 63)] = oadj1[(size_t)b * 4096 + i];
    {
        float* WR = P2;          // temp
        float* WO = P2 + 1024;
        for (int i = tid; i < 1024; i += 256) { WR[i] = Wrel2[i]; WO[i] = Wroot2[i]; }
        __syncthreads();
        float* C1 = S + 2304;
        int n = tid >> 2, j0 = (tid & 3) * 8;
        float a8[8];
#pragma unroll
        for (int j = 0; j < 8; ++j) a8[j] = 0.f;
        for (int m = 0; m < 64; ++m) {
            float av = OADJ1s[n * 68 + m];
            float4 x1 = *(const float4*)&XM1A[m * 36 + j0];
            float4 x2 = *(const float4*)&XM1A[m * 36 + j0 + 4];
            a8[0] += av * x1.x; a8[1] += av * x1.y; a8[2] += av * x1.z; a8[3] += av * x1.w;
            a8[4] += av * x2.x; a8[5] += av * x2.y; a8[6] += av * x2.z; a8[7] += av * x2.w;
        }
        __syncthreads();
#pragma unroll
        for (int j = 0; j < 8; ++j) C1[n * 36 + j0 + j] = a8[j];
        __syncthreads();
        float o8[8];
#pragma unroll
        for (int j = 0; j < 8; ++j) o8[j] = brel2[j0 + j];
        for (int h = 0; h < 32; ++h) {
            float c1v = C1[n * 36 + h];
            float xav = XM1A[n * 36 + h];
            float4 wr1 = *(const float4*)&WR[h * 32 + j0];
            float4 wr2 = *(const float4*)&WR[h * 32 + j0 + 4];
            float4 wo1 = *(const float4*)&WO[h * 32 + j0];
            float4 wo2 = *(const float4*)&WO[h * 32 + j0 + 4];
            o8[0] += c1v * wr1.x + xav * wo1.x; o8[1] += c1v * wr1.y + xav * wo1.y;
            o8[2] += c1v * wr1.z + xav * wo1.z; o8[3] += c1v * wr1.w + xav * wo1.w;
            o8[4] += c1v * wr2.x + xav * wo2.x; o8[5] += c1v * wr2.y + xav * wo2.y;
            o8[6] += c1v * wr2.z + xav * wo2.z; o8[7] += c1v * wr2.w + xav * wo2.w;
        }
#pragma unroll
        for (int j = 0; j < 8; ++j) XM2[n * 36 + j0 + j] = o8[j];
        __syncthreads();
    }
    // Phase 2: P2 = softmax(tanh(XM2@Wp2+bp2))
    {
        float* S2 = S;             // 2048 (stride 32)
        float* WP2s = S + 2048;    // 1024
        for (int i = tid; i < 1024; i += 256) WP2s[i] = Wp2[i];
        __syncthreads();
        for (int i = tid; i < 2048; i += 256) {
            int n = i >> 5, k = i & 31;
            float a = bp2[k];
            for (int h = 0; h < 32; ++h) a += XM2[n * 36 + h] * WP2s[h * 32 + k];
            S2[i] = tanhf(a);
        }
        __syncthreads();
        int lane = tid & 31, rr = tid >> 5;
        for (int r0 = 0; r0 < 64; r0 += 8) {
            int row = r0 + rr;
            float v = S2[row * 32 + lane];
            float m = v;
            for (int o = 16; o > 0; o >>= 1) m = fmaxf(m, __shfl_xor(m, o, 32));
            float e = expf(v - m);
            float s = e;
            for (int o = 16; o > 0; o >>= 1) s += __shfl_xor(s, o, 32);
            P2[row * 36 + lane] = e / s;
        }
        __syncthreads();
        for (int i = tid; i < 2048; i += 256)
            P2G[(size_t)b * 2048 + i] = P2[(i >> 5) * 36 + (i & 31)];
    }
    // Phase 3: TMP2 = OADJ1 @ P2
    float* TMP2 = S;
    {
        int n = tid >> 2, l0 = (tid & 3) * 8;
        float a8[8];
#pragma unroll
        for (int j = 0; j < 8; ++j) a8[j] = 0.f;
        for (int m = 0; m < 64; ++m) {
            float av = OADJ1s[n * 68 + m];
            float4 pa = *(const float4*)&P2[m * 36 + l0];
            float4 pb = *(const float4*)&P2[m * 36 + l0 + 4];
            a8[0] += av * pa.x; a8[1] += av * pa.y; a8[2] += av * pa.z; a8[3] += av * pa.w;
            a8[4] += av * pb.x; a8[5] += av * pb.y; a8[6] += av * pb.z; a8[7] += av * pb.w;
        }
        __syncthreads();
#pragma unroll
        for (int j = 0; j < 8; ++j) TMP2[n * 36 + l0 + j] = a8[j];
        __syncthreads();
    }
    // Phase 4: GS/GO, losses L2, OADJ2L, DF3
    {
        float* GS = S + 2304;
        float* GO = S + 3360;
        int k = tid >> 3, l0 = (tid & 7) * 4;
        float as4[4] = {0, 0, 0, 0}, ao4[4] = {0, 0, 0, 0};
        for (int n = 0; n < 64; ++n) {
            float pv = P2[n * 36 + k];
            float4 lp = *(const float4*)&P2[n * 36 + l0];
            float4 lt = *(const float4*)&TMP2[n * 36 + l0];
            as4[0] += pv * lp.x; as4[1] += pv * lp.y; as4[2] += pv * lp.z; as4[3] += pv * lp.w;
            ao4[0] += pv * lt.x; ao4[1] += pv * lt.y; ao4[2] += pv * lt.z; ao4[3] += pv * lt.w;
        }
#pragma unroll
        for (int j = 0; j < 4; ++j) {
            GS[k * 33 + l0 + j] = as4[j];
            GO[k * 33 + l0 + j] = ao4[j];
        }
        __syncthreads();
        const float* df2 = dflat2 + (size_t)b * 64;
        float den = 0.f;
        for (int i = tid; i < 2048; i += 256) {
            float pv = P2[(i >> 5) * 36 + (i & 31)];
            den += pv * pv * df2[i >> 5];
        }
        float ssn2 = 0.f;
        for (int i = tid; i < 1024; i += 256) {
            float v = GS[(i >> 5) * 33 + (i & 31)];
            ssn2 += v * v;
        }
        float num = 0.f;
        for (int kk = tid; kk < 32; kk += 256) num += GO[kk * 33 + kk];
        float den_t = blk_sum256(den, RBUF);
        float ssn2_t = blk_sum256(ssn2, RBUF);
        float num_t = blk_sum256(num, RBUF);
        float inv = 1.0f / sqrtf(ssn2_t);
        float dk = rsqrtf(32.0f);
        float o2 = 0.f;
        for (int i = tid; i < 1024; i += 256) {
            int kk = i >> 5, ll = i & 31;
            float v = GS[kk * 33 + ll] * inv - ((kk == ll) ? dk : 0.f);
            o2 += v * v;
        }
        float o2_t = blk_sum256(o2, RBUF);
        if (tid == 0) {
            atomicAdd(mc_out, -(num_t / den_t) * (1.0f / NB));
            atomicAdd(or_out, sqrtf(o2_t) * (1.0f / NB));
        }
        if (tid < 32) {
            float rs = 0.f;
            for (int l = 0; l < 32; ++l) rs += GO[tid * 33 + l];
            rs -= GO[tid * 33 + tid];
            DVV[tid] = sqrtf(rs) + EPSV;
        }
        __syncthreads();
        for (int i = tid; i < 1024; i += 256) {
            int kk = i >> 5, ll = i & 31;
            float v = (kk == ll) ? 0.f : GO[kk * 33 + ll] / (DVV[kk] * DVV[ll]);
            OADJ2L[kk * 36 + ll] = v;
            OADJ2G[(size_t)b * 1024 + i] = v;
        }
        __syncthreads();
        if (tid < 32) {
            float s = 0.f;
            for (int l = 0; l < 32; ++l) s += OADJ2L[tid * 36 + l];
            DF3[tid] = s;
        }
        __syncthreads();
    }
    // Phase 5: XM2A = P2^T @ XM2
    float* XM2A = S;
    {
        int k = tid >> 3, h0 = (tid & 7) * 4;
        float a4[4] = {0, 0, 0, 0};
        for (int n = 0; n < 64; ++n) {
            float pv = P2[n * 36 + k];
            float4 xv = *(const float4*)&XM2[n * 36 + h0];
            a4[0] += pv * xv.x; a4[1] += pv * xv.y; a4[2] += pv * xv.z; a4[3] += pv * xv.w;
        }
        __syncthreads();
        *(float4*)&XM2A[k * 36 + h0] = make_float4(a4[0], a4[1], a4[2], a4[3]);
        __syncthreads();
    }
    // Phase 6: XM2B = graphconv3(XM2A)
    float* XM2B = S + 4352;
    {
        float* WREL3s = S + 1152;
        float* WROOT3s = S + 2176;
        float* C1 = S + 3200;
        for (int i = tid; i < 1024; i += 256) {
            WREL3s[i] = Wrel3[i];
            WROOT3s[i] = Wroot3[i];
        }
        __syncthreads();
        int n = tid >> 3, j0 = (tid & 7) * 4;
        float a4[4] = {0, 0, 0, 0};
        for (int m = 0; m < 32; ++m) {
            float av = OADJ2L[n * 36 + m];
            float4 xv = *(const float4*)&XM2A[m * 36 + j0];
            a4[0] += av * xv.x; a4[1] += av * xv.y; a4[2] += av * xv.z; a4[3] += av * xv.w;
        }
        __syncthreads();
        *(float4*)&C1[n * 36 + j0] = make_float4(a4[0], a4[1], a4[2], a4[3]);
        __syncthreads();
        float o4[4];
#pragma unroll
        for (int j = 0; j < 4; ++j) o4[j] = brel3[j0 + j];
        for (int h = 0; h < 32; ++h) {
            float c1v = C1[n * 36 + h];
            float xav = XM2A[n * 36 + h];
            float4 wr = *(const float4*)&WREL3s[h * 32 + j0];
            float4 wo = *(const float4*)&WROOT3s[h * 32 + j0];
            o4[0] += c1v * wr.x + xav * wo.x;
            o4[1] += c1v * wr.y + xav * wo.y;
            o4[2] += c1v * wr.z + xav * wo.z;
            o4[3] += c1v * wr.w + xav * wo.w;
        }
        __syncthreads();
        *(float4*)&XM2B[n * 36 + j0] = make_float4(o4[0], o4[1], o4[2], o4[3]);
        __syncthreads();
    }
    // Phase 7: P3 = softmax(tanh(XM2B@Wp3+bp3))
    {
        float* WP3s = S;
        for (int i = tid; i < 256; i += 256) WP3s[i] = Wp3[i];
        __syncthreads();
        int n = tid >> 3, kk = tid & 7;
        float a = bp3[kk];
        for (int h = 0; h < 32; ++h) a += XM2B[n * 36 + h] * WP3s[h * 8 + kk];
        float v = tanhf(a);
        float m = v;
        for (int o = 4; o > 0; o >>= 1) m = fmaxf(m, __shfl_xor(m, o, 8));
        float e = expf(v - m);
        float s = e;
        for (int o = 4; o > 0; o >>= 1) s += __shfl_xor(s, o, 8);
        P3L[n * 8 + kk] = e / s;
        __syncthreads();
        P3G[(size_t)b * 256 + tid] = P3L[tid];
        __syncthreads();
    }
    // Phase 8: L3 losses + OADJ3
    {
        float* TMP3 = S;
        float* GS3 = S + 256;
        float* GO3 = S + 336;
        int n = tid >> 3, l = tid & 7;
        float a = 0.f;
        for (int m = 0; m < 32; ++m) a += OADJ2L[n * 36 + m] * P3L[m * 8 + l];
        TMP3[n * 8 + l] = a;
        __syncthreads();
        if (tid < 64) {
            int k = tid >> 3, ll = tid & 7;
            float accs = 0.f, acco = 0.f;
            for (int nn = 0; nn < 32; ++nn) {
                float pv = P3L[nn * 8 + k];
                accs += pv * P3L[nn * 8 + ll];
                acco += pv * TMP3[nn * 8 + ll];
            }
            GS3[k * 9 + ll] = accs;
            GO3[k * 9 + ll] = acco;
        }
        __syncthreads();
        float den;
        {
            float pv = P3L[tid];
            den = pv * pv * DF3[tid >> 3];
        }
        float ssn2 = 0.f;
        if (tid < 64) {
            float v = GS3[(tid >> 3) * 9 + (tid & 7)];
            ssn2 = v * v;
        }
        float num = 0.f;
        if (tid < 8) num = GO3[tid * 9 + tid];
        float den_t = blk_sum256(den, RBUF);
        float ssn2_t = blk_sum256(ssn2, RBUF);
        float num_t = blk_sum256(num, RBUF);
        float inv = 1.0f / sqrtf(ssn2_t);
        float dk = rsqrtf(8.0f);
        float o2 = 0.f;
        if (tid < 64) {
            int k = tid >> 3, ll = tid & 7;
            float v = GS3[k * 9 + ll] * inv - ((k == ll) ? dk : 0.f);
            o2 = v * v;
        }
        float o2_t = blk_sum256(o2, RBUF);
        if (tid == 0) {
            atomicAdd(mc_out, -(num_t / den_t) * (1.0f / NB));
            atomicAdd(or_out, sqrtf(o2_t) * (1.0f / NB));
        }
        if (tid < 8) {
            float rs = 0.f;
            for (int ll = 0; ll < 8; ++ll) rs += GO3[tid * 9 + ll];
            rs -= GO3[tid * 9 + tid];
            DVV[32 + tid] = sqrtf(rs) + EPSV;
        }
        __syncthreads();
        if (tid < 64) {
            int k = tid >> 3, ll = tid & 7;
            float v = (k == ll) ? 0.f : GO3[k * 9 + ll] / (DVV[32 + k] * DVV[32 + ll]);
            OADJ3L[tid] = v;
            OADJ3G[(size_t)b * 64 + tid] = v;
        }
        __syncthreads();
    }
    // Phase 9: agg = p1 @ (P2 @ P3)
    {
        float* Q = S;
        for (int i = tid; i < 512; i += 256) {
            int k = i >> 3, m = i & 7;
            float a = 0.f;
            for (int l = 0; l < 32; ++l) a += P2[k * 36 + l] * P3L[l * 8 + m];
            Q[i] = a;
        }
        __syncthreads();
        const float* p1r = p1 + ((size_t)b * 256 + tid) * 64;
        float a8[8];
#pragma unroll
        for (int m = 0; m < 8; ++m) a8[m] = 0.f;
        for (int k = 0; k < 64; ++k) {
            float pv = p1r[k];
#pragma unroll
            for (int m = 0; m < 8; ++m) a8[m] += pv * Q[k * 8 + m];
        }
#pragma unroll
        for (int m = 0; m < 8; ++m)
            outagg[((size_t)b * 256 + tid) * 8 + m] = a8[m];
    }
}

// ---------------- tail B: per-(b,t) heavy path, gc2 fused, fully LDS-resident ----------------
__global__ __launch_bounds__(256) void k_tail_b(
        const float* __restrict__ X1A, const float* __restrict__ oadj1,
        const float* __restrict__ P2G, const float* __restrict__ OADJ2G,
        const float* __restrict__ P3G, const float* __restrict__ OADJ3G,
        const float* __restrict__ Wrel2, const float* __restrict__ brel2,
        const float* __restrict__ Wroot2,
        const float* __restrict__ Wrel3, const float* __restrict__ brel3,
        const float* __restrict__ Wroot3,
        const float* __restrict__ Wrel4, const float* __restrict__ brel4,
        const float* __restrict__ Wroot4,
        float* __restrict__ outx) {
    __shared__ float A[13408];
    float* X1AT = A;               // 64x36
    float* OADJ1s = A + 2304;      // 64x68
    float* WrelS = A + 6656;       // 1024
    float* WrootS = A + 7680;      // 1024
    float* C1a = A + 8704;         // 64x36
    float* X1B = A + 11008;        // 64x36
    int bt = blockIdx.x;
    int b = bt >> 4;
    int tid = threadIdx.x;
    // Phase 0: X1B = graphconv2(X1A_t)
    for (int i = tid; i < 2048; i += 256)
        X1AT[(i >> 5) * 36 + (i & 31)] = X1A[(size_t)bt * 2048 + i];
    for (int i = tid; i < 4096; i += 256)
        OADJ1s[(i >> 6) * 68 + (i & 63)] = oadj1[(size_t)b * 4096 + i];
    for (int i = tid; i < 1024; i += 256) {
        WrelS[i] = Wrel2[i];
        WrootS[i] = Wroot2[i];
    }
    __syncthreads();
    {
        int n = tid >> 2, j0 = (tid & 3) * 8;
        float a8[8];
#pragma unroll
        for (int j = 0; j < 8; ++j) a8[j] = 0.f;
        for (int m = 0; m < 64; ++m) {
            float av = OADJ1s[n * 68 + m];
            float4 x1 = *(const float4*)&X1AT[m * 36 + j0];
            float4 x2 = *(const float4*)&X1AT[m * 36 + j0 + 4];
            a8[0] += av * x1.x; a8[1] += av * x1.y; a8[2] += av * x1.z; a8[3] += av * x1.w;
            a8[4] += av * x2.x; a8[5] += av * x2.y; a8[6] += av * x2.z; a8[7] += av * x2.w;
        }
        __syncthreads();
#pragma unroll
        for (int j = 0; j < 8; ++j) C1a[n * 36 + j0 + j] = a8[j];
        __syncthreads();
        float o8[8];
#pragma unroll
        for (int j = 0; j < 8; ++j) o8[j] = brel2[j0 + j];
        for (int h = 0; h < 32; ++h) {
            float c1v = C1a[n * 36 + h];
            float xav = X1AT[n * 36 + h];
            float4 wr1 = *(const float4*)&WrelS[h * 32 + j0];
            float4 wr2 = *(const float4*)&WrelS[h * 32 + j0 + 4];
            float4 wo1 = *(const float4*)&WrootS[h * 32 + j0];
            float4 wo2 = *(const float4*)&WrootS[h * 32 + j0 + 4];
            o8[0] += c1v * wr1.x + xav * wo1.x; o8[1] += c1v * wr1.y + xav * wo1.y;
            o8[2] += c1v * wr1.z + xav * wo1.z; o8[3] += c1v * wr1.w + xav * wo1.w;
            o8[4] += c1v * wr2.x + xav * wo2.x; o8[5] += c1v * wr2.y + xav * wo2.y;
            o8[6] += c1v * wr2.z + xav * wo2.z; o8[7] += c1v * wr2.w + xav * wo2.w;
        }
        __syncthreads();
#pragma unroll
        for (int j = 0; j < 8; ++j) X1B[n * 36 + j0 + j] = o8[j];
        __syncthreads();
    }
    // Phase 1: X2A = P2^T @ X1B
    float* P2s = A;                // 64x36
    float* X2A = A + 2304;         // 32x36
    for (int i = tid; i < 2048; i += 256)
        P2s[(i >> 5) * 36 + (i & 31)] = P2G[(size_t)b * 2048 + i];
    __syncthreads();
    {
        int k = tid >> 3, h0 = (tid & 7) * 4;
        float a4[4] = {0, 0, 0, 0};
        for (int n = 0; n < 64; ++n) {
            float pv = P2s[n * 36 + k];
            float4 xv = *(const float4*)&X1B[n * 36 + h0];
            a4[0] += pv * xv.x; a4[1] += pv * xv.y; a4[2] += pv * xv.z; a4[3] += pv * xv.w;
        }
        __syncthreads();
        *(float4*)&X2A[k * 36 + h0] = make_float4(a4[0], a4[1], a4[2], a4[3]);
        __syncthreads();
    }
    // Phase 2: X2B = graphconv3(X2A)
    float* OADJ2s = A + 3456;      // 32x36
    float* Wrel3s = A + 4608;      // 1024
    float* Wroot3s = A + 5632;     // 1024
    float* C1b = A + 6656;         // 32x36
    float* X2B = A + 7808;         // 32x36
    for (int i = tid; i < 1024; i += 256) {
        OADJ2s[(i >> 5) * 36 + (i & 31)] = OADJ2G[(size_t)b * 1024 + i];
        Wrel3s[i] = Wrel3[i];
        Wroot3s[i] = Wroot3[i];
    }
    __syncthreads();
    {
        int n = tid >> 3, j0 = (tid & 7) * 4;
        float a4[4] = {0, 0, 0, 0};
        for (int m = 0; m < 32; ++m) {
            float av = OADJ2s[n * 36 + m];
            float4 xv = *(const float4*)&X2A[m * 36 + j0];
            a4[0] += av * xv.x; a4[1] += av * xv.y; a4[2] += av * xv.z; a4[3] += av * xv.w;
        }
        __syncthreads();
        *(float4*)&C1b[n * 36 + j0] = make_float4(a4[0], a4[1], a4[2], a4[3]);
        __syncthreads();
        float o4[4];
#pragma unroll
        for (int j = 0; j < 4; ++j) o4[j] = brel3[j0 + j];
        for (int h = 0; h < 32; ++h) {
            float c1v = C1b[n * 36 + h];
            float xav = X2A[n * 36 + h];
            float4 wr = *(const float4*)&Wrel3s[h * 32 + j0];
            float4 wo = *(const float4*)&Wroot3s[h * 32 + j0];
            o4[0] += c1v * wr.x + xav * wo.x;
            o4[1] += c1v * wr.y + xav * wo.y;
            o4[2] += c1v * wr.z + xav * wo.z;
            o4[3] += c1v * wr.w + xav * wo.w;
        }
        __syncthreads();
        *(float4*)&X2B[n * 36 + j0] = make_float4(o4[0], o4[1], o4[2], o4[3]);
        __syncthreads();
    }
    // Phase 3: X3A = P3^T @ X2B
    float* P3s = A;                // 256
    float* X3A = A + 8960;         // 8x36
    P3s[tid] = P3G[(size_t)b * 256 + tid];
    __syncthreads();
    {
        int k = tid >> 5, h = tid & 31;
        float a = 0.f;
        for (int n = 0; n < 32; ++n) a += P3s[n * 8 + k] * X2B[n * 36 + h];
        __syncthreads();
        X3A[k * 36 + h] = a;
        __syncthreads();
    }
    // Phase 4: out_t = graphconv4(X3A)
    {
        float* OADJ3s = A + 256;   // 64
        float* C3 = A + 320;       // 8x36
        float* Wrel4s = A + 9248;  // 2048
        float* Wroot4s = A + 11296;// 2048
        if (tid < 64) OADJ3s[tid] = OADJ3G[(size_t)b * 64 + tid];
        for (int i = tid; i < 2048; i += 256) {
            Wrel4s[i] = Wrel4[i];
            Wroot4s[i] = Wroot4[i];
        }
        __syncthreads();
        int n = tid >> 5, h = tid & 31;
        float a = 0.f;
#pragma unroll
        for (int m = 0; m < 8; ++m) a += OADJ3s[n * 8 + m] * X3A[m * 36 + h];
        C3[n * 36 + h] = a;
        __syncthreads();
        int o0 = (tid & 31) * 2;
        float a0 = brel4[o0], a1 = brel4[o0 + 1];
        for (int hh = 0; hh < 32; ++hh) {
            float c3v = C3[n * 36 + hh];
            float x3v = X3A[n * 36 + hh];
            a0 += c3v * Wrel4s[hh * 64 + o0] + x3v * Wroot4s[hh * 64 + o0];
            a1 += c3v * Wrel4s[hh * 64 + o0 + 1] + x3v * Wroot4s[hh * 64 + o0 + 1];
        }
        float* ob = outx + ((size_t)bt * 8 + n) * 64 + o0;
        ob[0] = a0;
        ob[1] = a1;
    }
}

// ---------------- host launch ----------------

extern "C" void kernel_launch(void* const* d_in, const int* in_sizes, int n_in,
                              void* d_out, int out_size, void* d_ws, size_t ws_size,
                              hipStream_t stream) {
    const float* pos    = (const float*)d_in[0];
    const float* ea     = (const float*)d_in[1];
    const int*   esrc   = (const int*)d_in[2];
    const int*   edst   = (const int*)d_in[3];
    const float* W1     = (const float*)d_in[4];
    const float* b1     = (const float*)d_in[5];
    const float* Wp1    = (const float*)d_in[6];
    const float* bp1    = (const float*)d_in[7];
    const float* Wrel2  = (const float*)d_in[8];
    const float* brel2  = (const float*)d_in[9];
    const float* Wroot2 = (const float*)d_in[10];
    const float* Wp2    = (const float*)d_in[11];
    const float* bp2    = (const float*)d_in[12];
    const float* Wrel3  = (const float*)d_in[13];
    const float* brel3  = (const float*)d_in[14];
    const float* Wroot3 = (const float*)d_in[15];
    const float* Wp3    = (const float*)d_in[16];
    const float* bp3    = (const float*)d_in[17];
    const float* Wrel4  = (const float*)d_in[18];
    const float* brel4  = (const float*)d_in[19];
    const float* Wroot4 = (const float*)d_in[20];
    float* out = (float*)d_out;

    char* w = (char*)d_ws;
    float* TMP    = (float*)(w);                        // 4 MB
    float* GBUF1  = (float*)(w + 4194304);              // 8 MB
    float* X1A    = (float*)(w + 12582912);             // 8 MB
    float* Z      = (float*)(w + 20971520);             // 3 MB
    float* P1     = (float*)(w + 25165824);             // 4 MB
    float* DINV   = (float*)(w + 29360128);             // 64 KB
    float* DFLAT  = (float*)(w + 29425664);             // 64 KB
    float* DFLAT2 = (float*)(w + 29491200);             // 16 KB
    float* GDEN1  = (float*)(w + 29507584);             // 1 KB
    float* OADJ1  = (float*)(w + 29622272);             // 1 MB
    float* P2G    = (float*)(w + 30670848);             // 512 KB
    float* OADJ2G = (float*)(w + 31195136);             // 256 KB
    float* P3G    = (float*)(w + 31457280);             // 64 KB
    float* OADJ3G = (float*)(w + 31522816);             // 16 KB
    float* MC     = out + 524288;                       // [mincut, ortho]

    // 1. front: z, dinv, p1 (MC zeroed inside); 32-row tiles, 2 blocks/CU
    k_front<<<NB * 8, 256, 0, stream>>>(esrc, edst, ea, pos, W1, b1, Wp1, bp1,
                                        Z, DINV, P1, MC);
    // 2. pool L1 (y recomputed in LDS, never materialized)
    k_pool1f<<<NB * 8, 256, 0, stream>>>(Z, pos, DINV, P1, W1, b1, X1A);
    // 3-5. L1 mincut chain
    k_adjp2<<<NB * 8, 256, 0, stream>>>(esrc, edst, P1, TMP, DFLAT);
    k_ssgp<256, 64, 4, 4, 8><<<NB * 4, 256, 0, stream>>>(P1, TMP, DFLAT, GBUF1, GDEN1);
    k_finish<64, 4, true><<<NB, 256, 0, stream>>>(GBUF1, GDEN1, OADJ1, DFLAT2, MC, MC + 1);
    // 6. per-batch planning (gc2 on mean via linearity)
    k_tail_a<<<NB, 256, 0, stream>>>(X1A, OADJ1, DFLAT2, P1,
                                     Wrel2, brel2, Wroot2, Wp2, bp2,
                                     Wrel3, brel3, Wroot3, Wp3, bp3,
                                     P2G, OADJ2G, P3G, OADJ3G,
                                     out + 524290, MC, MC + 1);
    // 7. per-(b,t) heavy path with gc2 fused
    k_tail_b<<<NB * TC, 256, 0, stream>>>(X1A, OADJ1, P2G, OADJ2G, P3G, OADJ3G,
                                          Wrel2, brel2, Wroot2,
                                          Wrel3, brel3, Wroot3,
                                          Wrel4, brel4, Wroot4, out);
}

// Round 13
// 163.538 us; speedup vs baseline: 2.0977x; 1.1881x over previous
//
#include <hip/hip_runtime.h>
#include <math.h>

#define NB 64
#define TC 16
#define HC 32
#define NNODES 16384
#define NEDGES 131072
#define EPG 2048
#define EPSV 1e-15f

static inline int GRID(int n) { return (n + 255) / 256; }

template<int V> struct Log2 { static constexpr int v = 1 + Log2<V/2>::v; };
template<> struct Log2<1> { static constexpr int v = 0; };

__device__ inline float blk_sum256(float v, float* rbuf) {
    for (int o = 32; o > 0; o >>= 1) v += __shfl_xor(v, o);
    __syncthreads();
    if ((threadIdx.x & 63) == 0) rbuf[threadIdx.x >> 6] = v;
    __syncthreads();
    return rbuf[0] + rbuf[1] + rbuf[2] + rbuf[3];
}

__device__ inline float blk_sum512(float v, float* rbuf) {
    for (int o = 32; o > 0; o >>= 1) v += __shfl_xor(v, o);
    __syncthreads();
    if ((threadIdx.x & 63) == 0) rbuf[threadIdx.x >> 6] = v;
    __syncthreads();
    float s = 0.f;
#pragma unroll
    for (int i = 0; i < 8; ++i) s += rbuf[i];
    return s;
}

// ---------------- front: edge-LDS adjacency GEMM + fused xm/p1 ----------------
// grid NB*8; XCD-swizzled: all 8 dtiles of graph b on one XCD (b = (bid&7)*8 + bid>>6)
__global__ __launch_bounds__(256) void k_front(
        const int* __restrict__ esrc, const int* __restrict__ edst,
        const float* __restrict__ ea, const float* __restrict__ pos,
        const float* __restrict__ W1, const float* __restrict__ b1,
        const float* __restrict__ Wp1, const float* __restrict__ bp1,
        float* __restrict__ z, float* __restrict__ dinv_g,
        float* __restrict__ p1, float* __restrict__ mc) {
    __shared__ float L[9280];
    float* dinvs = L;             // 256
    float* as_   = L + 256;       // 32x36
    float* bs    = L + 1408;      // 32x48
    float* s1    = L + 256;       // 32x64 (reuse after GEMM)
    float* zs    = L + 2944;      // 32x48
    float* poss  = L + 4480;      // 32x48 -> a3 in place
    float* xm    = L + 6016;      // 32x32
    float* wp    = L + 7040;      // 32x64
    float* W1s   = L + 9088;      // 96
    float* b1s   = L + 9184;      // 32
    float* bp1s  = L + 9216;      // 64
    int bid = blockIdx.x;
    int b = (bid & 7) * 8 + (bid >> 6);
    int dtile = ((bid >> 3) & 7) * 32;
    int tid = threadIdx.x;
    if (bid == 0 && tid < 2) mc[tid] = 0.f;
    for (int i = tid; i < 512; i += 256) ((float4*)wp)[i] = ((const float4*)Wp1)[i];
    if (tid < 96) W1s[tid] = W1[tid];
    if (tid < 32) b1s[tid] = b1[tid];
    if (tid < 64) bp1s[tid] = bp1[tid];
    for (int i = tid; i < 384; i += 256)
        ((float4*)poss)[i] = ((const float4*)(pos + ((size_t)b * 256 + dtile) * 48))[i];
    int ebase = b * EPG;
    int svr[8], dvr[8];
    float evr[8];
#pragma unroll
    for (int j = 0; j < 8; ++j) {
        int e = ebase + tid + j * 256;
        svr[j] = esrc[e] & 255;
        dvr[j] = edst[e] & 255;
        evr[j] = ea[e];
    }
    dinvs[tid] = 1.0f;
    __syncthreads();
#pragma unroll
    for (int j = 0; j < 8; ++j) atomicAdd(&dinvs[dvr[j]], evr[j]);
    __syncthreads();
    float dg = dinvs[tid];
    float dvv = (dg > 0.f) ? rsqrtf(dg) : 0.f;
    __syncthreads();
    dinvs[tid] = dvv;
    __syncthreads();
    if (dtile == 0) dinv_g[b * 256 + tid] = dinvs[tid];
    int d = tid >> 3, q = tid & 7;
    float acc[6];
#pragma unroll
    for (int j = 0; j < 6; ++j) acc[j] = 0.f;
    const float* pbase = pos + (size_t)b * 256 * 48;
    for (int s0 = 0; s0 < 256; s0 += 32) {
        for (int i = tid; i < 288; i += 256)
            ((float4*)as_)[i] = make_float4(0.f, 0.f, 0.f, 0.f);
        __syncthreads();
#pragma unroll
        for (int j = 0; j < 8; ++j) {
            int dr = dvr[j] - dtile, sc = svr[j] - s0;
            if ((unsigned)dr < 32u && (unsigned)sc < 32u)
                atomicAdd(&as_[dr * 36 + sc], evr[j]);
        }
        for (int i = tid; i < 384; i += 256) {
            int r = i / 12, c = i % 12;
            float4 v = *(const float4*)(pbase + (size_t)(s0 + r) * 48 + c * 4);
            float dd = dinvs[s0 + r];
            v.x *= dd; v.y *= dd; v.z *= dd; v.w *= dd;
            *(float4*)(bs + r * 48 + c * 4) = v;
        }
        __syncthreads();
#pragma unroll 8
        for (int sp = 0; sp < 32; ++sp) {
            float a = as_[d * 36 + sp];
            const float* bp = &bs[sp * 48 + q * 6];
#pragma unroll
            for (int j = 0; j < 6; ++j) acc[j] += a * bp[j];
        }
        __syncthreads();
    }
    float dd = dinvs[dtile + d];
    float* zr = z + (size_t)(b * 256 + dtile + d) * 48 + q * 6;
#pragma unroll
    for (int j = 0; j < 6; ++j) {
        float v = acc[j] * dd;
        zr[j] = v;
        zs[d * 48 + q * 6 + j] = v;
    }
    __syncthreads();
    for (int i = tid; i < 1536; i += 256) {
        int nn = i / 48;
        float d2 = dinvs[dtile + nn];
        d2 *= d2;
        poss[i] = zs[i] + poss[i] * d2;
    }
    __syncthreads();
    {
        int h = tid & 31, ng = tid >> 5;
        float w0 = W1s[h], w1 = W1s[32 + h], w2 = W1s[64 + h], bb = b1s[h];
#pragma unroll
        for (int j = 0; j < 4; ++j) {
            int nn = ng + 8 * j;
            float a = 0.f;
#pragma unroll
            for (int t = 0; t < 16; ++t) {
                const float* ap = &poss[nn * 48 + t * 3];
                float y = fmaxf(ap[0] * w0 + ap[1] * w1 + ap[2] * w2 + bb, 0.f);
                a += y;
            }
            xm[nn * 32 + h] = a * (1.0f / 16.0f);
        }
    }
    __syncthreads();
    for (int i = tid; i < 2048; i += 256) {
        int n = i >> 6, k = i & 63;
        float a = bp1s[k];
#pragma unroll 8
        for (int h2 = 0; h2 < 32; ++h2) a += xm[n * 32 + h2] * wp[h2 * 64 + k];
        s1[i] = tanhf(a);
    }
    __syncthreads();
    {
        int wid = tid >> 6, lane = tid & 63;
        for (int r0 = wid; r0 < 32; r0 += 4) {
            float v = s1[r0 * 64 + lane];
            float m = v;
            for (int o = 32; o > 0; o >>= 1) m = fmaxf(m, __shfl_xor(m, o));
            float e = expf(v - m);
            float s = e;
            for (int o = 32; o > 0; o >>= 1) s += __shfl_xor(s, o);
            p1[((size_t)b * 256 + dtile + r0) * 64 + lane] = e / s;
        }
    }
}

// ---------------- pool1 fused: recompute y from z, pool in LDS ----------------
__global__ __launch_bounds__(256) void k_pool1f(
        const float* __restrict__ z, const float* __restrict__ pos,
        const float* __restrict__ dinv, const float* __restrict__ p1,
        const float* __restrict__ W1, const float* __restrict__ b1,
        float* __restrict__ X1A) {
    __shared__ __align__(16) float ps[4096];
    __shared__ __align__(16) float ys[4096];
    __shared__ float zc[384];
    __shared__ float pc[384];
    __shared__ float dv[64];
    __shared__ float W1s[96];
    __shared__ float b1s[32];
    int bid = blockIdx.x;
    int b = (bid & 7) * 8 + (bid >> 6);
    int t0 = ((bid >> 3) & 7) * 2;
    int tid = threadIdx.x;
    if (tid < 96) W1s[tid] = W1[tid];
    if (tid < 32) b1s[tid] = b1[tid];
    __syncthreads();
    int hh = tid & 31;
    float w0 = W1s[hh], w1 = W1s[32 + hh], w2 = W1s[64 + hh], bb = b1s[hh];
    int th = tid >> 7, r = tid & 127;
    int k0 = (r >> 3) * 4, h0 = (r & 7) * 4;
    float acc[4][4];
#pragma unroll
    for (int a = 0; a < 4; ++a)
#pragma unroll
        for (int c = 0; c < 4; ++c) acc[a][c] = 0.f;
    for (int n0 = 0; n0 < 256; n0 += 64) {
        for (int i = tid; i < 1024; i += 256)
            ((float4*)ps)[i] = ((const float4*)(p1 + ((size_t)b * 256 + n0) * 64))[i];
        if (tid < 192) {
            int n = tid / 3, c = tid % 3;
            size_t off = ((size_t)(b * 256 + n0 + n)) * 48 + t0 * 3 + c * 2;
            *(float2*)&zc[n * 6 + c * 2] = *(const float2*)(z + off);
            *(float2*)&pc[n * 6 + c * 2] = *(const float2*)(pos + off);
        }
        if (tid < 64) dv[tid] = dinv[b * 256 + n0 + tid];
        __syncthreads();
        int g = tid >> 5;
#pragma unroll
        for (int j = 0; j < 16; ++j) {
            int pidx = g * 16 + j;
            int t = pidx >> 6, nn = pidx & 63;
            float d2 = dv[nn] * dv[nn];
            const float* zp = &zc[nn * 6 + t * 3];
            const float* pp = &pc[nn * 6 + t * 3];
            float a0 = zp[0] + pp[0] * d2;
            float a1 = zp[1] + pp[1] * d2;
            float a2 = zp[2] + pp[2] * d2;
            ys[t * 2048 + nn * 32 + hh] = fmaxf(a0 * w0 + a1 * w1 + a2 * w2 + bb, 0.f);
        }
        __syncthreads();
#pragma unroll 4
        for (int n = 0; n < 64; ++n) {
            float4 kv4 = *(const float4*)&ps[n * 64 + k0];
            float4 xv4 = *(const float4*)&ys[th * 2048 + n * 32 + h0];
            float kv[4] = {kv4.x, kv4.y, kv4.z, kv4.w};
            float xv[4] = {xv4.x, xv4.y, xv4.z, xv4.w};
#pragma unroll
            for (int a = 0; a < 4; ++a)
#pragma unroll
                for (int c = 0; c < 4; ++c) acc[a][c] += kv[a] * xv[c];
        }
        __syncthreads();
    }
    float* ob = X1A + (((size_t)(b * 16 + t0 + th) * 64 + k0) * 32 + h0);
#pragma unroll
    for (int a = 0; a < 4; ++a) {
        float4 v = {acc[a][0], acc[a][1], acc[a][2], acc[a][3]};
        *(float4*)(ob + (size_t)a * 32) = v;
    }
}

// ---------------- L1: adjacency-apply + dflat ----------------
__global__ void k_adjp2(const int* __restrict__ esrc, const int* __restrict__ edst,
                        const float* __restrict__ p, float* __restrict__ tmp,
                        float* __restrict__ dflat) {
    __shared__ __align__(16) float as_[32 * 260];
    __shared__ __align__(16) float ps[64 * 64];
    int bid = blockIdx.x;
    int b = (bid & 7) * 8 + (bid >> 6);
    int nt0 = ((bid >> 3) & 7) * 32;
    int tid = threadIdx.x;
    for (int i = tid; i < 32 * 260 / 4; i += 256)
        ((float4*)as_)[i] = make_float4(0.f, 0.f, 0.f, 0.f);
    __syncthreads();
    int ebase = b * EPG;
#pragma unroll
    for (int j = 0; j < 8; ++j) {
        int e = ebase + tid + j * 256;
        int sv = esrc[e] & 255;
        int nr = sv - nt0;
        if ((unsigned)nr < 32u)
            atomicAdd(&as_[nr * 260 + (edst[e] & 255)], 1.0f);
    }
    __syncthreads();
    int n = tid >> 3, l0 = (tid & 7) * 8;
    float acc[8];
#pragma unroll
    for (int j = 0; j < 8; ++j) acc[j] = 0.f;
    float rs = 0.f;
    for (int m0 = 0; m0 < 256; m0 += 64) {
        for (int i = tid; i < 64 * 64 / 4; i += 256)
            ((float4*)ps)[i] = ((const float4*)(p + ((size_t)b * 256 + m0) * 64))[i];
        __syncthreads();
#pragma unroll 4
        for (int m = 0; m < 64; ++m) {
            float av = as_[n * 260 + m0 + m];
            rs += av;
            float4 p0 = *(const float4*)&ps[m * 64 + l0];
            float4 p1v = *(const float4*)&ps[m * 64 + l0 + 4];
            acc[0] += av * p0.x; acc[1] += av * p0.y; acc[2] += av * p0.z; acc[3] += av * p0.w;
            acc[4] += av * p1v.x; acc[5] += av * p1v.y; acc[6] += av * p1v.z; acc[7] += av * p1v.w;
        }
        __syncthreads();
    }
#pragma unroll
    for (int j = 0; j < 8; ++j)
        tmp[((size_t)b * 256 + nt0 + n) * 64 + l0 + j] = acc[j];
    if ((tid & 7) == 0) dflat[(size_t)b * 256 + nt0 + n] = rs;
}

template<int NC, int KC, int NSPLIT, int KT, int LT>
__global__ void k_ssgp(const float* __restrict__ p, const float* __restrict__ tmp,
                       const float* __restrict__ dflat, float* __restrict__ G,
                       float* __restrict__ Gden) {
    constexpr int NCH = NC / NSPLIT;
    constexpr int LC = 2 * KC;
    constexpr int KQ = KC / 4;
    __shared__ __align__(16) float ab[NCH * LC];
    __shared__ float rbuf[4];
    int bid = blockIdx.x;
    int idx = bid >> 3;
    int b = (bid & 7) * 8 + idx / NSPLIT;
    int split = idx % NSPLIT;
    int n0 = split * NCH;
    int tid = threadIdx.x;
    const float* pb = p + ((size_t)b * NC + n0) * KC;
    const float* tb = tmp + ((size_t)b * NC + n0) * KC;
    const float* db = dflat + (size_t)b * NC + n0;
    for (int i = tid; i < NCH * KQ; i += 256) {
        int r = i / KQ, c = i % KQ;
        *(float4*)(ab + r * LC + c * 4) = ((const float4*)pb)[i];
        *(float4*)(ab + r * LC + KC + c * 4) = ((const float4*)tb)[i];
    }
    __syncthreads();
    float den = 0.f;
    for (int i = tid; i < NCH * KQ; i += 256) {
        int r = i / KQ, c = i % KQ;
        float4 v = *(const float4*)(ab + r * LC + c * 4);
        den += (v.x * v.x + v.y * v.y + v.z * v.z + v.w * v.w) * db[r];
    }
    int kt = tid >> 4, lt = tid & 15;
    int k0 = kt * KT, l0 = lt * LT;
    float acc[KT][LT];
#pragma unroll
    for (int r = 0; r < KT; ++r)
#pragma unroll
        for (int c = 0; c < LT; ++c) acc[r][c] = 0.f;
#pragma unroll 4
    for (int n = 0; n < NCH; ++n) {
        float kv[KT], lv[LT];
#pragma unroll
        for (int r = 0; r < KT; ++r) kv[r] = ab[n * LC + k0 + r];
#pragma unroll
        for (int c = 0; c < LT; ++c) lv[c] = ab[n * LC + l0 + c];
#pragma unroll
        for (int r = 0; r < KT; ++r)
#pragma unroll
            for (int c = 0; c < LT; ++c) acc[r][c] += kv[r] * lv[c];
    }
    float* Gb = G + ((size_t)split * NB + b) * (KC * LC);
#pragma unroll
    for (int r = 0; r < KT; ++r)
#pragma unroll
        for (int c = 0; c < LT; ++c)
            Gb[(k0 + r) * LC + l0 + c] = acc[r][c];
    float dt = blk_sum256(den, rbuf);
    if (tid == 0) Gden[(size_t)split * NB + b] = dt;
}

template<int KC, int NSPLIT, bool DFN>
__global__ void k_finish(const float* __restrict__ G, const float* __restrict__ Gden,
                         float* __restrict__ oadj_out, float* __restrict__ dfn_out,
                         float* __restrict__ mc_out, float* __restrict__ or_out) {
    constexpr int LK = Log2<KC>::v;
    constexpr int KCP = KC + 1;
    constexpr int LC = 2 * KC;
    __shared__ float sss[KC * KCP];
    __shared__ float oss[KC * KCP];
    __shared__ float dvv[KC];
    __shared__ float rbuf[4];
    int bid = blockIdx.x;
    int b = ((bid & 7) << 3) | (bid >> 3);
    int tid = threadIdx.x;
    for (int i = tid; i < KC * KC; i += 256) {
        int k = i >> LK, l = i & (KC - 1);
        float sv = 0.f, ov = 0.f;
#pragma unroll
        for (int s = 0; s < NSPLIT; ++s) {
            const float* Gb = G + ((size_t)s * NB + b) * KC * LC;
            sv += Gb[k * LC + l];
            ov += Gb[k * LC + KC + l];
        }
        sss[k * KCP + l] = sv;
        oss[k * KCP + l] = ov;
    }
    __syncthreads();
    float ssn2 = 0.f;
    for (int i = tid; i < KC * KC; i += 256) {
        int k = i >> LK, l = i & (KC - 1);
        float v = sss[k * KCP + l];
        ssn2 += v * v;
    }
    float num = 0.f;
    for (int k = tid; k < KC; k += 256) num += oss[k * KCP + k];
    float ssn2_t = blk_sum256(ssn2, rbuf);
    float num_t = blk_sum256(num, rbuf);
    float den_t = 0.f;
#pragma unroll
    for (int s = 0; s < NSPLIT; ++s) den_t += Gden[(size_t)s * NB + b];
    float inv = 1.0f / sqrtf(ssn2_t);
    float dk = rsqrtf((float)KC);
    float o2 = 0.f;
    for (int i = tid; i < KC * KC; i += 256) {
        int k = i >> LK, l = i & (KC - 1);
        float v = sss[k * KCP + l] * inv - ((k == l) ? dk : 0.f);
        o2 += v * v;
    }
    float o2_t = blk_sum256(o2, rbuf);
    if (tid == 0) {
        atomicAdd(mc_out, -(num_t / den_t) * (1.0f / NB));
        atomicAdd(or_out, sqrtf(o2_t) * (1.0f / NB));
    }
    if (tid < KC) {
        float rs = 0.f;
        for (int l = 0; l < KC; ++l) rs += oss[tid * KCP + l];
        rs -= oss[tid * KCP + tid];
        dvv[tid] = sqrtf(rs) + EPSV;
    }
    __syncthreads();
    for (int i = tid; i < KC * KC; i += 256) {
        int k = i >> LK, l = i & (KC - 1);
        float v = (k == l) ? 0.f : oss[k * KCP + l] / (dvv[k] * dvv[l]);
        oadj_out[(size_t)b * KC * KC + i] = v;
    }
    if (DFN && tid < KC) {
        float s = 0.f;
        for (int l = 0; l < KC; ++l)
            if (l != tid) s += oss[tid * KCP + l] / (dvv[tid] * dvv[l]);
        dfn_out[(size_t)b * KC + tid] = s;
    }
}

// ---------------- tail A: per-batch planning, 512 threads ----------------
__global__ __launch_bounds__(512) void k_tail_a(
        const float* __restrict__ X1A, const float* __restrict__ oadj1,
        const float* __restrict__ dflat2, const float* __restrict__ p1,
        const float* __restrict__ Wrel2, const float* __restrict__ brel2,
        const float* __restrict__ Wroot2,
        const float* __restrict__ Wp2, const float* __restrict__ bp2,
        const float* __restrict__ Wrel3, const float* __restrict__ brel3,
        const float* __restrict__ Wroot3,
        const float* __restrict__ Wp3, const float* __restrict__ bp3,
        float* __restrict__ P2G, float* __restrict__ OADJ2G,
        float* __restrict__ P3G, float* __restrict__ OADJ3G,
        float* __restrict__ outagg,
        float* __restrict__ mc_out, float* __restrict__ or_out) {
    __shared__ __align__(16) float lds[16160];
    float* P2     = lds;            // 64x36
    float* XM2    = lds + 2304;     // 64x36
    float* OADJ2L = lds + 4608;     // 32x36
    float* P3L    = lds + 5760;     // 32x8
    float* OADJ3L = lds + 6016;     // 8x8
    float* DF3    = lds + 6080;     // 32
    float* DVV    = lds + 6112;     // 40
    float* RBUF   = lds + 6152;     // 8
    float* OADJ1s = lds + 6160;     // 64x68
    float* S      = lds + 10512;    // 5648 scratch

    int bid = blockIdx.x;
    int b = ((bid & 7) << 3) | (bid >> 3);
    int tid = threadIdx.x;

    // Phase 0: XM1A = mean_t X1A; XM2 = graphconv2(XM1A)
    float* XM1A = S;
    for (int i = tid; i < 2048; i += 512) {
        float s = 0.f;
        for (int t = 0; t < 16; ++t) s += X1A[((size_t)b * 16 + t) * 2048 + i];
        XM1A[(i >> 5) * 36 + (i & 31)] = s * (1.0f / 16.0f);
    }
    for (int i = tid; i < 4096; i += 512)
        OADJ1s[(i >> 6) * 68 + (i & 63)] = oadj1[(size_t)b * 4096 + i];
    {
        float* WR = P2;          // temp
        float* WO = P2 + 1024;
        for (int i = tid; i < 1024; i += 512) { WR[i] = Wrel2[i]; WO[i] = Wroot2[i]; }
        __syncthreads();
        float* C1 = S + 2304;
        int n = tid >> 3, j0 = (tid & 7) * 4;
        float a4[4] = {0, 0, 0, 0};
        for (int m = 0; m < 64; ++m) {
            float av = OADJ1s[n * 68 + m];
            float4 xv = *(const float4*)&XM1A[m * 36 + j0];
            a4[0] += av * xv.x; a4[1] += av * xv.y; a4[2] += av * xv.z; a4[3] += av * xv.w;
        }
        __syncthreads();
#pragma unroll
        for (int j = 0; j < 4; ++j) C1[n * 36 + j0 + j] = a4[j];
        __syncthreads();
        float o4[4];
#pragma unroll
        for (int j = 0; j < 4; ++j) o4[j] = brel2[j0 + j];
        for (int h = 0; h < 32; ++h) {
            float c1v = C1[n * 36 + h];
            float xav = XM1A[n * 36 + h];
            float4 wr = *(const float4*)&WR[h * 32 + j0];
            float4 wo = *(const float4*)&WO[h * 32 + j0];
            o4[0] += c1v * wr.x + xav * wo.x;
            o4[1] += c1v * wr.y + xav * wo.y;
            o4[2] += c1v * wr.z + xav * wo.z;
            o4[3] += c1v * wr.w + xav * wo.w;
        }
        __syncthreads();
#pragma unroll
        for (int j = 0; j < 4; ++j) XM2[n * 36 + j0 + j] = o4[j];
        __syncthreads();
    }
    // Phase 2: P2 = softmax(tanh(XM2@Wp2+bp2))
    {
        float* S2 = S;
        float* WP2s = S + 2048;
        for (int i = tid; i < 1024; i += 512) WP2s[i] = Wp2[i];
        __syncthreads();
        for (int i = tid; i < 2048; i += 512) {
            int n = i >> 5, k = i & 31;
            float a = bp2[k];
            for (int h = 0; h < 32; ++h) a += XM2[n * 36 + h] * WP2s[h * 32 + k];
            S2[i] = tanhf(a);
        }
        __syncthreads();
        int lane = tid & 31, rr = tid >> 5;
        for (int r0 = 0; r0 < 64; r0 += 16) {
            int row = r0 + rr;
            float v = S2[row * 32 + lane];
            float m = v;
            for (int o = 16; o > 0; o >>= 1) m = fmaxf(m, __shfl_xor(m, o, 32));
            float e = expf(v - m);
            float s = e;
            for (int o = 16; o > 0; o >>= 1) s += __shfl_xor(s, o, 32);
            P2[row * 36 + lane] = e / s;
        }
        __syncthreads();
        for (int i = tid; i < 2048; i += 512)
            P2G[(size_t)b * 2048 + i] = P2[(i >> 5) * 36 + (i & 31)];
    }
    // Phase 3: TMP2 = OADJ1 @ P2
    float* TMP2 = S;
    {
        int n = tid >> 3, l0 = (tid & 7) * 4;
        float a4[4] = {0, 0, 0, 0};
        for (int m = 0; m < 64; ++m) {
            float av = OADJ1s[n * 68 + m];
            float4 pv = *(const float4*)&P2[m * 36 + l0];
            a4[0] += av * pv.x; a4[1] += av * pv.y; a4[2] += av * pv.z; a4[3] += av * pv.w;
        }
        __syncthreads();
#pragma unroll
        for (int j = 0; j < 4; ++j) TMP2[n * 36 + l0 + j] = a4[j];
        __syncthreads();
    }
    // Phase 4: GS/GO, losses L2, OADJ2L, DF3
    {
        float* GS = S + 2304;
        float* GO = S + 3360;
        int k = tid >> 4, l0 = (tid & 15) * 2;
        float as2[2] = {0, 0}, ao2[2] = {0, 0};
        for (int n = 0; n < 64; ++n) {
            float pv = P2[n * 36 + k];
            float2 lp = *(const float2*)&P2[n * 36 + l0];
            float2 lt = *(const float2*)&TMP2[n * 36 + l0];
            as2[0] += pv * lp.x; as2[1] += pv * lp.y;
            ao2[0] += pv * lt.x; ao2[1] += pv * lt.y;
        }
        GS[k * 33 + l0] = as2[0]; GS[k * 33 + l0 + 1] = as2[1];
        GO[k * 33 + l0] = ao2[0]; GO[k * 33 + l0 + 1] = ao2[1];
        __syncthreads();
        const float* df2 = dflat2 + (size_t)b * 64;
        float den = 0.f;
        for (int i = tid; i < 2048; i += 512) {
            float pv = P2[(i >> 5) * 36 + (i & 31)];
            den += pv * pv * df2[i >> 5];
        }
        float ssn2 = 0.f;
        for (int i = tid; i < 1024; i += 512) {
            float v = GS[(i >> 5) * 33 + (i & 31)];
            ssn2 += v * v;
        }
        float num = 0.f;
        if (tid < 32) num = GO[tid * 33 + tid];
        float den_t = blk_sum512(den, RBUF);
        float ssn2_t = blk_sum512(ssn2, RBUF);
        float num_t = blk_sum512(num, RBUF);
        float inv = 1.0f / sqrtf(ssn2_t);
        float dk = rsqrtf(32.0f);
        float o2 = 0.f;
        for (int i = tid; i < 1024; i += 512) {
            int kk = i >> 5, ll = i & 31;
            float v = GS[kk * 33 + ll] * inv - ((kk == ll) ? dk : 0.f);
            o2 += v * v;
        }
        float o2_t = blk_sum512(o2, RBUF);
        if (tid == 0) {
            atomicAdd(mc_out, -(num_t / den_t) * (1.0f / NB));
            atomicAdd(or_out, sqrtf(o2_t) * (1.0f / NB));
        }
        if (tid < 32) {
            float rs = 0.f;
            for (int l = 0; l < 32; ++l) rs += GO[tid * 33 + l];
            rs -= GO[tid * 33 + tid];
            DVV[tid] = sqrtf(rs) + EPSV;
        }
        __syncthreads();
        for (int i = tid; i < 1024; i += 512) {
            int kk = i >> 5, ll = i & 31;
            float v = (kk == ll) ? 0.f : GO[kk * 33 + ll] / (DVV[kk] * DVV[ll]);
            OADJ2L[kk * 36 + ll] = v;
            OADJ2G[(size_t)b * 1024 + i] = v;
        }
        __syncthreads();
        if (tid < 32) {
            float s = 0.f;
            for (int l = 0; l < 32; ++l) s += OADJ2L[tid * 36 + l];
            DF3[tid] = s;
        }
        __syncthreads();
    }
    // Phase 5: XM2A = P2^T @ XM2
    float* XM2A = S;
    {
        int k = tid >> 4, h0 = (tid & 15) * 2;
        float a2[2] = {0, 0};
        for (int n = 0; n < 64; ++n) {
            float pv = P2[n * 36 + k];
            float2 xv = *(const float2*)&XM2[n * 36 + h0];
            a2[0] += pv * xv.x; a2[1] += pv * xv.y;
        }
        __syncthreads();
        XM2A[k * 36 + h0] = a2[0];
        XM2A[k * 36 + h0 + 1] = a2[1];
        __syncthreads();
    }
    // Phase 6: XM2B = graphconv3(XM2A)
    float* XM2B = S + 4352;
    {
        float* WREL3s = S + 1152;
        float* WROOT3s = S + 2176;
        float* C1 = S + 3200;
        for (int i = tid; i < 1024; i += 512) {
            WREL3s[i] = Wrel3[i];
            WROOT3s[i] = Wroot3[i];
        }
        __syncthreads();
        int n = tid >> 4, j0 = (tid & 15) * 2;
        float a2[2] = {0, 0};
        for (int m = 0; m < 32; ++m) {
            float av = OADJ2L[n * 36 + m];
            float2 xv = *(const float2*)&XM2A[m * 36 + j0];
            a2[0] += av * xv.x; a2[1] += av * xv.y;
        }
        __syncthreads();
        C1[n * 36 + j0] = a2[0];
        C1[n * 36 + j0 + 1] = a2[1];
        __syncthreads();
        float o2v[2];
        o2v[0] = brel3[j0]; o2v[1] = brel3[j0 + 1];
        for (int h = 0; h < 32; ++h) {
            float c1v = C1[n * 36 + h];
            float xav = XM2A[n * 36 + h];
            float2 wr = *(const float2*)&WREL3s[h * 32 + j0];
            float2 wo = *(const float2*)&WROOT3s[h * 32 + j0];
            o2v[0] += c1v * wr.x + xav * wo.x;
            o2v[1] += c1v * wr.y + xav * wo.y;
        }
        __syncthreads();
        XM2B[n * 36 + j0] = o2v[0];
        XM2B[n * 36 + j0 + 1] = o2v[1];
        __syncthreads();
    }
    // Phase 7: P3 = softmax(tanh(XM2B@Wp3+bp3))
    {
        float* WP3s = S;
        for (int i = tid; i < 256; i += 512) WP3s[i] = Wp3[i];
        __syncthreads();
        if (tid < 256) {
            int n = tid >> 3, kk = tid & 7;
            float a = bp3[kk];
            for (int h = 0; h < 32; ++h) a += XM2B[n * 36 + h] * WP3s[h * 8 + kk];
            float v = tanhf(a);
            float m = v;
            for (int o = 4; o > 0; o >>= 1) m = fmaxf(m, __shfl_xor(m, o, 8));
            float e = expf(v - m);
            float s = e;
            for (int o = 4; o > 0; o >>= 1) s += __shfl_xor(s, o, 8);
            P3L[n * 8 + kk] = e / s;
        }
        __syncthreads();
        if (tid < 256) P3G[(size_t)b * 256 + tid] = P3L[tid];
        __syncthreads();
    }
    // Phase 8: L3 losses + OADJ3
    {
        float* TMP3 = S;
        float* GS3 = S + 256;
        float* GO3 = S + 336;
        if (tid < 256) {
            int n = tid >> 3, l = tid & 7;
            float a = 0.f;
            for (int m = 0; m < 32; ++m) a += OADJ2L[n * 36 + m] * P3L[m * 8 + l];
            TMP3[n * 8 + l] = a;
        }
        __syncthreads();
        if (tid < 64) {
            int k = tid >> 3, ll = tid & 7;
            float accs = 0.f, acco = 0.f;
            for (int nn = 0; nn < 32; ++nn) {
                float pv = P3L[nn * 8 + k];
                accs += pv * P3L[nn * 8 + ll];
                acco += pv * TMP3[nn * 8 + ll];
            }
            GS3[k * 9 + ll] = accs;
            GO3[k * 9 + ll] = acco;
        }
        __syncthreads();
        float den = 0.f;
        if (tid < 256) {
            float pv = P3L[tid];
            den = pv * pv * DF3[tid >> 3];
        }
        float ssn2 = 0.f;
        if (tid < 64) {
            float v = GS3[(tid >> 3) * 9 + (tid & 7)];
            ssn2 = v * v;
        }
        float num = 0.f;
        if (tid < 8) num = GO3[tid * 9 + tid];
        float den_t = blk_sum512(den, RBUF);
        float ssn2_t = blk_sum512(ssn2, RBUF);
        float num_t = blk_sum512(num, RBUF);
        float inv = 1.0f / sqrtf(ssn2_t);
        float dk = rsqrtf(8.0f);
        float o2 = 0.f;
        if (tid < 64) {
            int k = tid >> 3, ll = tid & 7;
            float v = GS3[k * 9 + ll] * inv - ((k == ll) ? dk : 0.f);
            o2 = v * v;
        }
        float o2_t = blk_sum512(o2, RBUF);
        if (tid == 0) {
            atomicAdd(mc_out, -(num_t / den_t) * (1.0f / NB));
            atomicAdd(or_out, sqrtf(o2_t) * (1.0f / NB));
        }
        if (tid < 8) {
            float rs = 0.f;
            for (int ll = 0; ll < 8; ++ll) rs += GO3[tid * 9 + ll];
            rs -= GO3[tid * 9 + tid];
            DVV[32 + tid] = sqrtf(rs) + EPSV;
        }
        __syncthreads();
        if (tid < 64) {
            int k = tid >> 3, ll = tid & 7;
            float v = (k == ll) ? 0.f : GO3[k * 9 + ll] / (DVV[32 + k] * DVV[32 + ll]);
            OADJ3L[tid] = v;
            OADJ3G[(size_t)b * 64 + tid] = v;
        }
        __syncthreads();
    }
    // Phase 9: agg = p1 @ (P2 @ P3)
    {
        float* Q = S;
        {
            int i = tid;
            if (i < 512) {
                int k = i >> 3, m = i & 7;
                float a = 0.f;
                for (int l = 0; l < 32; ++l) a += P2[k * 36 + l] * P3L[l * 8 + m];
                Q[i] = a;
            }
        }
        __syncthreads();
        int row = tid >> 1, m0 = (tid & 1) * 4;
        const float* p1r = p1 + ((size_t)b * 256 + row) * 64;
        float a4[4] = {0, 0, 0, 0};
        for (int k = 0; k < 64; ++k) {
            float pv = p1r[k];
#pragma unroll
            for (int m = 0; m < 4; ++m) a4[m] += pv * Q[k * 8 + m0 + m];
        }
#pragma unroll
        for (int m = 0; m < 4; ++m)
            outagg[((size_t)b * 256 + row) * 8 + m0 + m] = a4[m];
    }
}

// ---------------- tail B: per-(b,t) heavy path, gc2 fused, fully LDS-resident ----------------
__global__ __launch_bounds__(256) void k_tail_b(
        const float* __restrict__ X1A, const float* __restrict__ oadj1,
        const float* __restrict__ P2G, const float* __restrict__ OADJ2G,
        const float* __restrict__ P3G, const float* __restrict__ OADJ3G,
        const float* __restrict__ Wrel2, const float* __restrict__ brel2,
        const float* __restrict__ Wroot2,
        const float* __restrict__ Wrel3, const float* __restrict__ brel3,
        const float* __restrict__ Wroot3,
        const float* __restrict__ Wrel4, const float* __restrict__ brel4,
        const float* __restrict__ Wroot4,
        float* __restrict__ outx) {
    __shared__ float A[13408];
    float* X1AT = A;               // 64x36
    float* OADJ1s = A + 2304;      // 64x68
    float* WrelS = A + 6656;       // 1024
    float* WrootS = A + 7680;      // 1024
    float* C1a = A + 8704;         // 64x36
    float* X1B = A + 11008;        // 64x36
    int bid = blockIdx.x;
    int idxg = bid >> 3;
    int t = idxg & 15;
    int b = (bid & 7) * 8 + (idxg >> 4);
    int bt = b * 16 + t;
    int tid = threadIdx.x;
    // Phase 0: X1B = graphconv2(X1A_t)
    for (int i = tid; i < 2048; i += 256)
        X1AT[(i >> 5) * 36 + (i & 31)] = X1A[(size_t)bt * 2048 + i];
    for (int i = tid; i < 4096; i += 256)
        OADJ1s[(i >> 6) * 68 + (i & 63)] = oadj1[(size_t)b * 4096 + i];
    for (int i = tid; i < 1024; i += 256) {
        WrelS[i] = Wrel2[i];
        WrootS[i] = Wroot2[i];
    }
    __syncthreads();
    {
        int n = tid >> 2, j0 = (tid & 3) * 8;
        float a8[8];
#pragma unroll
        for (int j = 0; j < 8; ++j) a8[j] = 0.f;
        for (int m = 0; m < 64; ++m) {
            float av = OADJ1s[n * 68 + m];
            float4 x1 = *(const float4*)&X1AT[m * 36 + j0];
            float4 x2 = *(const float4*)&X1AT[m * 36 + j0 + 4];
            a8[0] += av * x1.x; a8[1] += av * x1.y; a8[2] += av * x1.z; a8[3] += av * x1.w;
            a8[4] += av * x2.x; a8[5] += av * x2.y; a8[6] += av * x2.z; a8[7] += av * x2.w;
        }
        __syncthreads();
#pragma unroll
        for (int j = 0; j < 8; ++j) C1a[n * 36 + j0 + j] = a8[j];
        __syncthreads();
        float o8[8];
#pragma unroll
        for (int j = 0; j < 8; ++j) o8[j] = brel2[j0 + j];
        for (int h = 0; h < 32; ++h) {
            float c1v = C1a[n * 36 + h];
            float xav = X1AT[n * 36 + h];
            float4 wr1 = *(const float4*)&WrelS[h * 32 + j0];
            float4 wr2 = *(const float4*)&WrelS[h * 32 + j0 + 4];
            float4 wo1 = *(const float4*)&WrootS[h * 32 + j0];
            float4 wo2 = *(const float4*)&WrootS[h * 32 + j0 + 4];
            o8[0] += c1v * wr1.x + xav * wo1.x; o8[1] += c1v * wr1.y + xav * wo1.y;
            o8[2] += c1v * wr1.z + xav * wo1.z; o8[3] += c1v * wr1.w + xav * wo1.w;
            o8[4] += c1v * wr2.x + xav * wo2.x; o8[5] += c1v * wr2.y + xav * wo2.y;
            o8[6] += c1v * wr2.z + xav * wo2.z; o8[7] += c1v * wr2.w + xav * wo2.w;
        }
        __syncthreads();
#pragma unroll
        for (int j = 0; j < 8; ++j) X1B[n * 36 + j0 + j] = o8[j];
        __syncthreads();
    }
    // Phase 1: X2A = P2^T @ X1B
    float* P2s = A;                // 64x36
    float* X2A = A + 2304;         // 32x36
    for (int i = tid; i < 2048; i += 256)
        P2s[(i >> 5) * 36 + (i & 31)] = P2G[(size_t)b * 2048 + i];
    __syncthreads();
    {
        int k = tid >> 3, h0 = (tid & 7) * 4;
        float a4[4] = {0, 0, 0, 0};
        for (int n = 0; n < 64; ++n) {
            float pv = P2s[n * 36 + k];
            float4 xv = *(const float4*)&X1B[n * 36 + h0];
            a4[0] += pv * xv.x; a4[1] += pv * xv.y; a4[2] += pv * xv.z; a4[3] += pv * xv.w;
        }
        __syncthreads();
        *(float4*)&X2A[k * 36 + h0] = make_float4(a4[0], a4[1], a4[2], a4[3]);
        __syncthreads();
    }
    // Phase 2: X2B = graphconv3(X2A)
    float* OADJ2s = A + 3456;      // 32x36
    float* Wrel3s = A + 4608;      // 1024
    float* Wroot3s = A + 5632;     // 1024
    float* C1b = A + 6656;         // 32x36
    float* X2B = A + 7808;         // 32x36
    for (int i = tid; i < 1024; i += 256) {
        OADJ2s[(i >> 5) * 36 + (i & 31)] = OADJ2G[(size_t)b * 1024 + i];
        Wrel3s[i] = Wrel3[i];
        Wroot3s[i] = Wroot3[i];
    }
    __syncthreads();
    {
        int n = tid >> 3, j0 = (tid & 7) * 4;
        float a4[4] = {0, 0, 0, 0};
        for (int m = 0; m < 32; ++m) {
            float av = OADJ2s[n * 36 + m];
            float4 xv = *(const float4*)&X2A[m * 36 + j0];
            a4[0] += av * xv.x; a4[1] += av * xv.y; a4[2] += av * xv.z; a4[3] += av * xv.w;
        }
        __syncthreads();
        *(float4*)&C1b[n * 36 + j0] = make_float4(a4[0], a4[1], a4[2], a4[3]);
        __syncthreads();
        float o4[4];
#pragma unroll
        for (int j = 0; j < 4; ++j) o4[j] = brel3[j0 + j];
        for (int h = 0; h < 32; ++h) {
            float c1v = C1b[n * 36 + h];
            float xav = X2A[n * 36 + h];
            float4 wr = *(const float4*)&Wrel3s[h * 32 + j0];
            float4 wo = *(const float4*)&Wroot3s[h * 32 + j0];
            o4[0] += c1v * wr.x + xav * wo.x;
            o4[1] += c1v * wr.y + xav * wo.y;
            o4[2] += c1v * wr.z + xav * wo.z;
            o4[3] += c1v * wr.w + xav * wo.w;
        }
        __syncthreads();
        *(float4*)&X2B[n * 36 + j0] = make_float4(o4[0], o4[1], o4[2], o4[3]);
        __syncthreads();
    }
    // Phase 3: X3A = P3^T @ X2B
    float* P3s = A;                // 256
    float* X3A = A + 8960;         // 8x36
    P3s[tid] = P3G[(size_t)b * 256 + tid];
    __syncthreads();
    {
        int k = tid >> 5, h = tid & 31;
        float a = 0.f;
        for (int n = 0; n < 32; ++n) a += P3s[n * 8 + k] * X2B[n * 36 + h];
        __syncthreads();
        X3A[k * 36 + h] = a;
        __syncthreads();
    }
    // Phase 4: out_t = graphconv4(X3A)
    {
        float* OADJ3s = A + 256;   // 64
        float* C3 = A + 320;       // 8x36
        float* Wrel4s = A + 9248;  // 2048
        float* Wroot4s = A + 11296;// 2048
        if (tid < 64) OADJ3s[tid] = OADJ3G[(size_t)b * 64 + tid];
        for (int i = tid; i < 2048; i += 256) {
            Wrel4s[i] = Wrel4[i];
            Wroot4s[i] = Wroot4[i];
        }
        __syncthreads();
        int n = tid >> 5, h = tid & 31;
        float a = 0.f;
#pragma unroll
        for (int m = 0; m < 8; ++m) a += OADJ3s[n * 8 + m] * X3A[m * 36 + h];
        C3[n * 36 + h] = a;
        __syncthreads();
        int o0 = (tid & 31) * 2;
        float a0 = brel4[o0], a1 = brel4[o0 + 1];
        for (int hh = 0; hh < 32; ++hh) {
            float c3v = C3[n * 36 + hh];
            float x3v = X3A[n * 36 + hh];
            a0 += c3v * Wrel4s[hh * 64 + o0] + x3v * Wroot4s[hh * 64 + o0];
            a1 += c3v * Wrel4s[hh * 64 + o0 + 1] + x3v * Wroot4s[hh * 64 + o0 + 1];
        }
        float* ob = outx + ((size_t)bt * 8 + n) * 64 + o0;
        ob[0] = a0;
        ob[1] = a1;
    }
}

// ---------------- host launch ----------------

extern "C" void kernel_launch(void* const* d_in, const int* in_sizes, int n_in,
                              void* d_out, int out_size, void* d_ws, size_t ws_size,
                              hipStream_t stream) {
    const float* pos    = (const float*)d_in[0];
    const float* ea     = (const float*)d_in[1];
    const int*   esrc   = (const int*)d_in[2];
    const int*   edst   = (const int*)d_in[3];
    const float* W1     = (const float*)d_in[4];
    const float* b1     = (const float*)d_in[5];
    const float* Wp1    = (const float*)d_in[6];
    const float* bp1    = (const float*)d_in[7];
    const float* Wrel2  = (const float*)d_in[8];
    const float* brel2  = (const float*)d_in[9];
    const float* Wroot2 = (const float*)d_in[10];
    const float* Wp2    = (const float*)d_in[11];
    const float* bp2    = (const float*)d_in[12];
    const float* Wrel3  = (const float*)d_in[13];
    const float* brel3  = (const float*)d_in[14];
    const float* Wroot3 = (const float*)d_in[15];
    const float* Wp3    = (const float*)d_in[16];
    const float* bp3    = (const float*)d_in[17];
    const float* Wrel4  = (const float*)d_in[18];
    const float* brel4  = (const float*)d_in[19];
    const float* Wroot4 = (const float*)d_in[20];
    float* out = (float*)d_out;

    char* w = (char*)d_ws;
    float* TMP    = (float*)(w);                        // 4 MB
    float* GBUF1  = (float*)(w + 4194304);              // 8 MB
    float* X1A    = (float*)(w + 12582912);             // 8 MB
    float* Z      = (float*)(w + 20971520);             // 3 MB
    float* P1     = (float*)(w + 25165824);             // 4 MB
    float* DINV   = (float*)(w + 29360128);             // 64 KB
    float* DFLAT  = (float*)(w + 29425664);             // 64 KB
    float* DFLAT2 = (float*)(w + 29491200);             // 16 KB
    float* GDEN1  = (float*)(w + 29507584);             // 1 KB
    float* OADJ1  = (float*)(w + 29622272);             // 1 MB
    float* P2G    = (float*)(w + 30670848);             // 512 KB
    float* OADJ2G = (float*)(w + 31195136);             // 256 KB
    float* P3G    = (float*)(w + 31457280);             // 64 KB
    float* OADJ3G = (float*)(w + 31522816);             // 16 KB
    float* MC     = out + 524288;                       // [mincut, ortho]

    // 1. front (XCD-swizzled): z, dinv, p1 (MC zeroed inside)
    k_front<<<NB * 8, 256, 0, stream>>>(esrc, edst, ea, pos, W1, b1, Wp1, bp1,
                                        Z, DINV, P1, MC);
    // 2. pool L1 (XCD-swizzled)
    k_pool1f<<<NB * 8, 256, 0, stream>>>(Z, pos, DINV, P1, W1, b1, X1A);
    // 3-5. L1 mincut chain (XCD-swizzled)
    k_adjp2<<<NB * 8, 256, 0, stream>>>(esrc, edst, P1, TMP, DFLAT);
    k_ssgp<256, 64, 4, 4, 8><<<NB * 4, 256, 0, stream>>>(P1, TMP, DFLAT, GBUF1, GDEN1);
    k_finish<64, 4, true><<<NB, 256, 0, stream>>>(GBUF1, GDEN1, OADJ1, DFLAT2, MC, MC + 1);
    // 6. per-batch planning (512 threads for latency hiding)
    k_tail_a<<<NB, 512, 0, stream>>>(X1A, OADJ1, DFLAT2, P1,
                                     Wrel2, brel2, Wroot2, Wp2, bp2,
                                     Wrel3, brel3, Wroot3, Wp3, bp3,
                                     P2G, OADJ2G, P3G, OADJ3G,
                                     out + 524290, MC, MC + 1);
    // 7. per-(b,t) heavy path (XCD-swizzled)
    k_tail_b<<<NB * TC, 256, 0, stream>>>(X1A, OADJ1, P2G, OADJ2G, P3G, OADJ3G,
                                          Wrel2, brel2, Wroot2,
                                          Wrel3, brel3, Wroot3,
                                          Wrel4, brel4, Wroot4, out);
}